// Round 2
// baseline (710.888 us; speedup 1.0000x reference)
//
#include <hip/hip_runtime.h>
#include <math.h>

// ---------------- conv0: (B,1,15360) -> (B,16,7680), k=5 p=2, BN+ReLU+maxpool2
__global__ __launch_bounds__(256) void conv0_kernel(
    const float* __restrict__ x, const float* __restrict__ w,
    const float* __restrict__ cb, const float* __restrict__ bg,
    const float* __restrict__ bb, const float* __restrict__ bm,
    const float* __restrict__ bv, float* __restrict__ out)
{
    const int L = 15360, LO = 7680;
    int b = blockIdx.y;
    int j = blockIdx.x * 256 + threadIdx.x;
    const float* xb = x + (size_t)b * L;
    int base = 2 * j - 2;
    float xv[6];
#pragma unroll
    for (int t = 0; t < 6; ++t) {
        int p = base + t;
        xv[t] = (p >= 0 && p < L) ? xb[p] : 0.f;
    }
#pragma unroll
    for (int c = 0; c < 16; ++c) {
        float s = bg[c] * rsqrtf(bv[c] + 1e-5f);
        float bias = (cb[c] - bm[c]) * s + bb[c];
        float a0 = 0.f, a1 = 0.f;
#pragma unroll
        for (int t = 0; t < 5; ++t) {
            float wc = w[c * 5 + t];
            a0 = fmaf(wc, xv[t], a0);
            a1 = fmaf(wc, xv[t + 1], a1);
        }
        float v = fmaxf(fmaf(a0, s, bias), fmaf(a1, s, bias));
        out[((size_t)b * 16 + c) * LO + j] = fmaxf(v, 0.f);
    }
}

// ---------------- conv mid: (B,CI,LI) -> (B,CO,LO), k=5 p=2, BN+ReLU+maxpool2
template <int CI, int CO, int LI, int LO, int TJ>
__global__ __launch_bounds__(256) void convmid_kernel(
    const float* __restrict__ in, const float* __restrict__ w,
    const float* __restrict__ cb, const float* __restrict__ bg,
    const float* __restrict__ bb, const float* __restrict__ bm,
    const float* __restrict__ bv, float* __restrict__ out)
{
    const int XW = 2 * TJ + 4;
    __shared__ float xt[CI][XW];
    __shared__ float ws[CI * 5 * CO];   // [ci][t][co]
    __shared__ float sc[CO], bs[CO];
    int b = blockIdx.y;
    int j0 = blockIdx.x * TJ;
    int tid = threadIdx.x;
    for (int i = tid; i < CI * 5 * CO; i += 256) {
        int co = i % CO; int r = i / CO; int t = r % 5; int ci = r / 5;
        ws[i] = w[(co * CI + ci) * 5 + t];
    }
    if (tid < CO) {
        float s = bg[tid] * rsqrtf(bv[tid] + 1e-5f);
        sc[tid] = s;
        bs[tid] = (cb[tid] - bm[tid]) * s + bb[tid];
    }
    for (int i = tid; i < CI * XW; i += 256) {
        int ci = i / XW, p = i % XW;
        int gp = 2 * j0 - 2 + p;
        xt[ci][p] = (gp >= 0 && gp < LI) ? in[((size_t)b * CI + ci) * LI + gp] : 0.f;
    }
    __syncthreads();
    int jj = tid % TJ;
    int cg = tid / TJ;
    float a0[16], a1[16];
#pragma unroll
    for (int q = 0; q < 16; ++q) { a0[q] = 0.f; a1[q] = 0.f; }
    for (int ci = 0; ci < CI; ++ci) {
        float xv[6];
#pragma unroll
        for (int t = 0; t < 6; ++t) xv[t] = xt[ci][2 * jj + t];
#pragma unroll
        for (int t = 0; t < 5; ++t) {
            const float4* wp = reinterpret_cast<const float4*>(&ws[(ci * 5 + t) * CO + cg * 16]);
#pragma unroll
            for (int q4 = 0; q4 < 4; ++q4) {
                float4 wv = wp[q4];
                a0[q4 * 4 + 0] = fmaf(wv.x, xv[t], a0[q4 * 4 + 0]);
                a0[q4 * 4 + 1] = fmaf(wv.y, xv[t], a0[q4 * 4 + 1]);
                a0[q4 * 4 + 2] = fmaf(wv.z, xv[t], a0[q4 * 4 + 2]);
                a0[q4 * 4 + 3] = fmaf(wv.w, xv[t], a0[q4 * 4 + 3]);
                a1[q4 * 4 + 0] = fmaf(wv.x, xv[t + 1], a1[q4 * 4 + 0]);
                a1[q4 * 4 + 1] = fmaf(wv.y, xv[t + 1], a1[q4 * 4 + 1]);
                a1[q4 * 4 + 2] = fmaf(wv.z, xv[t + 1], a1[q4 * 4 + 2]);
                a1[q4 * 4 + 3] = fmaf(wv.w, xv[t + 1], a1[q4 * 4 + 3]);
            }
        }
    }
#pragma unroll
    for (int q = 0; q < 16; ++q) {
        int co = cg * 16 + q;
        float v = fmaxf(fmaf(a0[q], sc[co], bs[co]), fmaf(a1[q], sc[co], bs[co]));
        out[((size_t)b * CO + co) * LO + j0 + jj] = fmaxf(v, 0.f);
    }
}

// ---------------- avgpool: (B,64,1920) -> (B, T=64, C=64) (transposed for LSTM)
__global__ __launch_bounds__(256) void avgpool_kernel(
    const float* __restrict__ a2, float* __restrict__ xseq)
{
    int b = blockIdx.x, tid = threadIdx.x;
    for (int i = tid; i < 4096; i += 256) {
        int c = i >> 6, t = i & 63;
        const float* p = a2 + ((size_t)b * 64 + c) * 1920 + t * 30;
        float s = 0.f;
#pragma unroll
        for (int k = 0; k < 30; ++k) s += p[k];
        xseq[((size_t)b * 64 + t) * 64 + c] = s * (1.f / 30.f);
    }
}

// ---------------- LSTM: 2 layers fused, one block per batch element.
__global__ __launch_bounds__(256) void lstm_kernel(
    const float* __restrict__ xseq,
    const float* __restrict__ wih0, const float* __restrict__ whh0,
    const float* __restrict__ bih0, const float* __restrict__ bhh0,
    const float* __restrict__ wih1, const float* __restrict__ whh1,
    const float* __restrict__ bih1, const float* __restrict__ bhh1,
    float* __restrict__ hseq)
{
    __shared__ float xb[64][64];    // layer input (overwritten by layer0 output)
    __shared__ float xg[64][256];   // precomputed input-gate contributions
    __shared__ float gb4[4][64];
    __shared__ float hb[64];
    int b = blockIdx.x;
    int tid = threadIdx.x;
    int wv = tid >> 6, ln = tid & 63;
    for (int i = tid; i < 4096; i += 256) xb[i >> 6][i & 63] = xseq[(size_t)b * 4096 + i];
    __syncthreads();
    float wr[64];
    for (int layer = 0; layer < 2; ++layer) {
        const float* wih = layer ? wih1 : wih0;
        const float* whh = layer ? whh1 : whh0;
        float bias = layer ? (bih1[tid] + bhh1[tid]) : (bih0[tid] + bhh0[tid]);
        // phase A: xg[t][r] = bias + x_t . wih_row(r)
#pragma unroll
        for (int k4 = 0; k4 < 16; ++k4) {
            float4 v = reinterpret_cast<const float4*>(wih + (size_t)tid * 64)[k4];
            wr[k4 * 4 + 0] = v.x; wr[k4 * 4 + 1] = v.y;
            wr[k4 * 4 + 2] = v.z; wr[k4 * 4 + 3] = v.w;
        }
        for (int t = 0; t < 64; ++t) {
            float s0 = bias, s1 = 0.f, s2 = 0.f, s3 = 0.f;
#pragma unroll
            for (int k = 0; k < 64; k += 4) {
                s0 = fmaf(wr[k + 0], xb[t][k + 0], s0);
                s1 = fmaf(wr[k + 1], xb[t][k + 1], s1);
                s2 = fmaf(wr[k + 2], xb[t][k + 2], s2);
                s3 = fmaf(wr[k + 3], xb[t][k + 3], s3);
            }
            xg[t][tid] = (s0 + s1) + (s2 + s3);
        }
        // phase B: recurrence
#pragma unroll
        for (int k4 = 0; k4 < 16; ++k4) {
            float4 v = reinterpret_cast<const float4*>(whh + (size_t)tid * 64)[k4];
            wr[k4 * 4 + 0] = v.x; wr[k4 * 4 + 1] = v.y;
            wr[k4 * 4 + 2] = v.z; wr[k4 * 4 + 3] = v.w;
        }
        if (tid < 64) hb[tid] = 0.f;
        float c = 0.f;
        __syncthreads();
        for (int t = 0; t < 64; ++t) {
            float s0 = xg[t][tid], s1 = 0.f, s2 = 0.f, s3 = 0.f;
#pragma unroll
            for (int k = 0; k < 64; k += 4) {
                s0 = fmaf(wr[k + 0], hb[k + 0], s0);
                s1 = fmaf(wr[k + 1], hb[k + 1], s1);
                s2 = fmaf(wr[k + 2], hb[k + 2], s2);
                s3 = fmaf(wr[k + 3], hb[k + 3], s3);
            }
            float acc = (s0 + s1) + (s2 + s3);
            float a;
            if (wv == 2) a = tanhf(acc);
            else         a = 1.f / (1.f + __expf(-acc));
            gb4[wv][ln] = a;
            __syncthreads();
            float gi = gb4[0][ln], gf = gb4[1][ln], gg = gb4[2][ln], go = gb4[3][ln];
            c = fmaf(gf, c, gi * gg);   // identical in all 4 waves
            float h = go * tanhf(c);
            if (wv == 0) {
                hb[ln] = h;
                if (layer == 0) xb[t][ln] = h;
                else hseq[((size_t)b * 64 + t) * 64 + ln] = h;
            }
            __syncthreads();
        }
    }
}

// ---------------- graph: correlation + kthvalue(192) + adjacency + 3x GCN + classifier
__global__ __launch_bounds__(256) void graph_kernel(
    const float* __restrict__ hseq,
    const float* __restrict__ gw0, const float* __restrict__ gb0,
    const float* __restrict__ gw1, const float* __restrict__ gb1,
    const float* __restrict__ gw2, const float* __restrict__ gb2,
    const float* __restrict__ clw, const float* __restrict__ clb,
    float* __restrict__ out)
{
    __shared__ float nf[16][257];   // ORIGINAL node features (GCN input!)
    __shared__ float sb[16][257];   // normalized copy, then GCN L0 aggregation
    __shared__ float red[16][17];
    __shared__ float mean[16], rstd[16];
    __shared__ float C[256];
    __shared__ float adj[16][16];
    __shared__ float thrv;
    __shared__ float bufA[16][65], bufB[16][65], bufC[16][65];
    __shared__ float emb[64];
    int b = blockIdx.x, tid = threadIdx.x;
    for (int i = tid; i < 4096; i += 256) nf[i >> 8][i & 255] = hseq[(size_t)b * 4096 + i];
    __syncthreads();
    int nd = tid >> 4, sub = tid & 15;
    {   // mean
        float s = 0.f;
        for (int f = sub; f < 256; f += 16) s += nf[nd][f];
        red[nd][sub] = s;
    }
    __syncthreads();
    if (tid < 16) {
        float m = 0.f;
        for (int i = 0; i < 16; ++i) m += red[tid][i];
        mean[tid] = m * (1.f / 256.f);
    }
    __syncthreads();
    {   // centered sumsq (ddof=1)
        float mu = mean[nd];
        float ss = 0.f;
        for (int f = sub; f < 256; f += 16) { float d = nf[nd][f] - mu; ss = fmaf(d, d, ss); }
        red[nd][sub] = ss;
    }
    __syncthreads();
    if (tid < 16) {
        float m = 0.f;
        for (int i = 0; i < 16; ++i) m += red[tid][i];
        rstd[tid] = 1.f / (sqrtf(m * (1.f / 255.f)) + 1e-8f);
    }
    __syncthreads();
    // normalized copy into sb -- nf stays ORIGINAL for the GCN
    for (int i = tid; i < 4096; i += 256) {
        int n = i >> 8, f = i & 255;
        sb[n][f] = (nf[n][f] - mean[n]) * rstd[n];
    }
    __syncthreads();
    {   // C[n][m] = nrm_n . nrm_m / 256
        int n = tid >> 4, m = tid & 15;
        float a0 = 0, a1 = 0, a2 = 0, a3 = 0;
        for (int f = 0; f < 256; f += 4) {
            a0 = fmaf(sb[n][f + 0], sb[m][f + 0], a0);
            a1 = fmaf(sb[n][f + 1], sb[m][f + 1], a1);
            a2 = fmaf(sb[n][f + 2], sb[m][f + 2], a2);
            a3 = fmaf(sb[n][f + 3], sb[m][f + 3], a3);
        }
        C[tid] = ((a0 + a1) + (a2 + a3)) * (1.f / 256.f);
    }
    __syncthreads();
    {   // kthvalue: sorted[191] via rank counting (exact, handles duplicates)
        float v = C[tid];
        int cnt = 0, eq = 0;
        for (int j2 = 0; j2 < 256; ++j2) {
            float vj = C[j2];
            cnt += (vj < v);
            eq  += (vj == v);
        }
        if (cnt <= 191 && 191 < cnt + eq) thrv = v;  // identical bits from all writers
    }
    __syncthreads();
    {
        int n = tid >> 4, m = tid & 15;
        adj[n][m] = (C[tid] > thrv && n != m) ? 1.f : 0.f;
    }
    __syncthreads();
    // GCN L0: s = nf + adj@nf (16x256), into sb (normalized copy now dead)
    for (int i = tid; i < 4096; i += 256) {
        int n = i >> 8, f = i & 255;
        float acc = nf[n][f];
#pragma unroll
        for (int m = 0; m < 16; ++m) acc = fmaf(adj[n][m], nf[m][f], acc);
        sb[n][f] = acc;
    }
    __syncthreads();
    for (int i = tid; i < 1024; i += 256) {   // g1 = relu(s@gw0^T + gb0)
        int n = i >> 6, o = i & 63;
        const float4* wr4 = reinterpret_cast<const float4*>(gw0 + (size_t)o * 256);
        float acc = gb0[o];
        for (int f4 = 0; f4 < 64; ++f4) {
            float4 wv = wr4[f4];
            int f = f4 * 4;
            acc = fmaf(sb[n][f + 0], wv.x, acc);
            acc = fmaf(sb[n][f + 1], wv.y, acc);
            acc = fmaf(sb[n][f + 2], wv.z, acc);
            acc = fmaf(sb[n][f + 3], wv.w, acc);
        }
        bufA[n][o] = fmaxf(acc, 0.f);
    }
    __syncthreads();
    // L1
    for (int i = tid; i < 1024; i += 256) {
        int n = i >> 6, f = i & 63;
        float acc = bufA[n][f];
#pragma unroll
        for (int m = 0; m < 16; ++m) acc = fmaf(adj[n][m], bufA[m][f], acc);
        bufB[n][f] = acc;
    }
    __syncthreads();
    for (int i = tid; i < 1024; i += 256) {
        int n = i >> 6, o = i & 63;
        const float4* wr4 = reinterpret_cast<const float4*>(gw1 + (size_t)o * 64);
        float acc = gb1[o];
        for (int f4 = 0; f4 < 16; ++f4) {
            float4 wv = wr4[f4];
            int f = f4 * 4;
            acc = fmaf(bufB[n][f + 0], wv.x, acc);
            acc = fmaf(bufB[n][f + 1], wv.y, acc);
            acc = fmaf(bufB[n][f + 2], wv.z, acc);
            acc = fmaf(bufB[n][f + 3], wv.w, acc);
        }
        bufC[n][o] = fmaxf(acc, 0.f);
    }
    __syncthreads();
    // L2
    for (int i = tid; i < 1024; i += 256) {
        int n = i >> 6, f = i & 63;
        float acc = bufC[n][f];
#pragma unroll
        for (int m = 0; m < 16; ++m) acc = fmaf(adj[n][m], bufC[m][f], acc);
        bufA[n][f] = acc;
    }
    __syncthreads();
    for (int i = tid; i < 1024; i += 256) {
        int n = i >> 6, o = i & 63;
        const float4* wr4 = reinterpret_cast<const float4*>(gw2 + (size_t)o * 64);
        float acc = gb2[o];
        for (int f4 = 0; f4 < 16; ++f4) {
            float4 wv = wr4[f4];
            int f = f4 * 4;
            acc = fmaf(bufA[n][f + 0], wv.x, acc);
            acc = fmaf(bufA[n][f + 1], wv.y, acc);
            acc = fmaf(bufA[n][f + 2], wv.z, acc);
            acc = fmaf(bufA[n][f + 3], wv.w, acc);
        }
        bufB[n][o] = fmaxf(acc, 0.f);
    }
    __syncthreads();
    if (tid < 64) {   // emb = max over nodes
        float mx = bufB[0][tid];
#pragma unroll
        for (int n = 1; n < 16; ++n) mx = fmaxf(mx, bufB[n][tid]);
        emb[tid] = mx;
    }
    __syncthreads();
    if (tid < 5) {
        float acc = clb[tid];
#pragma unroll
        for (int o = 0; o < 64; ++o) acc = fmaf(emb[o], clw[tid * 64 + o], acc);
        out[(size_t)b * 5 + tid] = acc;
    }
}

extern "C" void kernel_launch(void* const* d_in, const int* in_sizes, int n_in,
                              void* d_out, int out_size, void* d_ws, size_t ws_size,
                              hipStream_t stream)
{
    const float* x    = (const float*)d_in[0];
    const float* cw0  = (const float*)d_in[1];
    const float* cb0  = (const float*)d_in[2];
    const float* bng0 = (const float*)d_in[3];
    const float* bnb0 = (const float*)d_in[4];
    const float* bnm0 = (const float*)d_in[5];
    const float* bnv0 = (const float*)d_in[6];
    const float* cw1  = (const float*)d_in[7];
    const float* cb1  = (const float*)d_in[8];
    const float* bng1 = (const float*)d_in[9];
    const float* bnb1 = (const float*)d_in[10];
    const float* bnm1 = (const float*)d_in[11];
    const float* bnv1 = (const float*)d_in[12];
    const float* cw2  = (const float*)d_in[13];
    const float* cb2  = (const float*)d_in[14];
    const float* bng2 = (const float*)d_in[15];
    const float* bnb2 = (const float*)d_in[16];
    const float* bnm2 = (const float*)d_in[17];
    const float* bnv2 = (const float*)d_in[18];
    const float* wih0 = (const float*)d_in[19];
    const float* whh0 = (const float*)d_in[20];
    const float* bih0 = (const float*)d_in[21];
    const float* bhh0 = (const float*)d_in[22];
    const float* wih1 = (const float*)d_in[23];
    const float* whh1 = (const float*)d_in[24];
    const float* bih1 = (const float*)d_in[25];
    const float* bhh1 = (const float*)d_in[26];
    const float* gw0  = (const float*)d_in[27];
    const float* gb0  = (const float*)d_in[28];
    const float* gw1  = (const float*)d_in[29];
    const float* gb1  = (const float*)d_in[30];
    const float* gw2  = (const float*)d_in[31];
    const float* gb2  = (const float*)d_in[32];
    const float* clw  = (const float*)d_in[33];
    const float* clb  = (const float*)d_in[34];

    // workspace layout (floats): two 31.46M-float ping-pong buffers
    const size_t BUF = 31457280;            // 256*16*7680 == 256*32*3840 == 256*64*1920
    float* f0 = (float*)d_ws;               // a0, then a2
    float* f1 = f0 + BUF;                   // a1, then xseq (+4MB for hseq)
    float* xs = f1;                         // (B,64,64) = 1,048,576 floats
    float* hs = f1 + 1048576;               // (B,64,64)

    conv0_kernel<<<dim3(30, 256), 256, 0, stream>>>(x, cw0, cb0, bng0, bnb0, bnm0, bnv0, f0);
    convmid_kernel<16, 32, 7680, 3840, 128><<<dim3(30, 256), 256, 0, stream>>>(
        f0, cw1, cb1, bng1, bnb1, bnm1, bnv1, f1);
    convmid_kernel<32, 64, 3840, 1920, 64><<<dim3(30, 256), 256, 0, stream>>>(
        f1, cw2, cb2, bng2, bnb2, bnm2, bnv2, f0);
    avgpool_kernel<<<256, 256, 0, stream>>>(f0, xs);
    lstm_kernel<<<256, 256, 0, stream>>>(xs, wih0, whh0, bih0, bhh0,
                                         wih1, whh1, bih1, bhh1, hs);
    graph_kernel<<<256, 256, 0, stream>>>(hs, gw0, gb0, gw1, gb1, gw2, gb2,
                                          clw, clb, (float*)d_out);
}

// Round 3
// 498.599 us; speedup vs baseline: 1.4258x; 1.4258x over previous
//
#include <hip/hip_runtime.h>
#include <math.h>

// ---------------- prep: transpose + BN-fold conv weights into [ci][t][co] layout
__global__ __launch_bounds__(256) void prep_weights_kernel(
    const float* __restrict__ cw0, const float* __restrict__ cb0,
    const float* __restrict__ bng0, const float* __restrict__ bnb0,
    const float* __restrict__ bnm0, const float* __restrict__ bnv0,
    const float* __restrict__ cw1, const float* __restrict__ cb1,
    const float* __restrict__ bng1, const float* __restrict__ bnb1,
    const float* __restrict__ bnm1, const float* __restrict__ bnv1,
    const float* __restrict__ cw2, const float* __restrict__ cb2,
    const float* __restrict__ bng2, const float* __restrict__ bnb2,
    const float* __restrict__ bnm2, const float* __restrict__ bnv2,
    float* __restrict__ wt1, float* __restrict__ b1,
    float* __restrict__ wt2, float* __restrict__ b2,
    float* __restrict__ w0f, float* __restrict__ b0f)
{
    int tid = threadIdx.x;
    // wt1[(ci*5+t)*32+co] = cw1[(co*16+ci)*5+t] * s1[co]
    for (int i = tid; i < 2560; i += 256) {
        int co = i & 31, r = i >> 5, t = r % 5, ci = r / 5;
        float s = bng1[co] * rsqrtf(bnv1[co] + 1e-5f);
        wt1[i] = cw1[(co * 16 + ci) * 5 + t] * s;
    }
    if (tid < 32) {
        float s = bng1[tid] * rsqrtf(bnv1[tid] + 1e-5f);
        b1[tid] = (cb1[tid] - bnm1[tid]) * s + bnb1[tid];
    }
    // wt2[(ci*5+t)*64+co] = cw2[(co*32+ci)*5+t] * s2[co]
    for (int i = tid; i < 10240; i += 256) {
        int co = i & 63, r = i >> 6, t = r % 5, ci = r / 5;
        float s = bng2[co] * rsqrtf(bnv2[co] + 1e-5f);
        wt2[i] = cw2[(co * 32 + ci) * 5 + t] * s;
    }
    if (tid < 64) {
        float s = bng2[tid] * rsqrtf(bnv2[tid] + 1e-5f);
        b2[tid] = (cb2[tid] - bnm2[tid]) * s + bnb2[tid];
    }
    // conv0: w0f[co*5+t] = cw0[co*5+t]*s0[co]
    if (tid < 80) {
        int co = tid / 5;
        float s = bng0[co] * rsqrtf(bnv0[co] + 1e-5f);
        w0f[tid] = cw0[tid] * s;
    }
    if (tid < 16) {
        float s = bng0[tid] * rsqrtf(bnv0[tid] + 1e-5f);
        b0f[tid] = (cb0[tid] - bnm0[tid]) * s + bnb0[tid];
    }
}

// ---------------- fused conv0 + conv1: x (B,1,15360) -> (B,32,3840)
// conv0 tile computed in-block; conv1 weights via wave-uniform scalar loads.
__global__ __launch_bounds__(256) void conv01_kernel(
    const float* __restrict__ x, const float* __restrict__ wt1,
    const float* __restrict__ b1, const float* __restrict__ w0f,
    const float* __restrict__ b0f, float* __restrict__ out)
{
    __shared__ float raw[528];
    __shared__ float xt0[16][260];   // row = 1040 B (16B-aligned)
    __shared__ float w0l[80];
    __shared__ float b0l[16];
    int b = blockIdx.y, tid = threadIdx.x;
    int j0 = blockIdx.x * 128;       // output position base in 3840-space
    const float* xb = x + (size_t)b * 15360;
    for (int p = tid; p < 524; p += 256) {
        int g = 4 * j0 - 6 + p;
        raw[p] = (g >= 0 && g < 15360) ? xb[g] : 0.f;
    }
    if (tid < 80) w0l[tid] = w0f[tid];
    if (tid < 16) b0l[tid] = b0f[tid];
    __syncthreads();
    // conv0: xt0[ci0][p] for positions q = 2*j0-2+p in 7680-space
#pragma unroll 1
    for (int ci0 = 0; ci0 < 16; ++ci0) {
        float w0 = w0l[ci0 * 5 + 0], w1 = w0l[ci0 * 5 + 1], w2 = w0l[ci0 * 5 + 2],
              w3 = w0l[ci0 * 5 + 3], w4 = w0l[ci0 * 5 + 4];
        float bb = b0l[ci0];
        for (int p = tid; p < 260; p += 256) {
            int q = 2 * j0 - 2 + p;
            float v = 0.f;
            if (q >= 0 && q < 7680) {
                float r0 = raw[2*p], r1 = raw[2*p+1], r2 = raw[2*p+2],
                      r3 = raw[2*p+3], r4 = raw[2*p+4], r5 = raw[2*p+5];
                float s0 = fmaf(w0, r0, fmaf(w1, r1, fmaf(w2, r2, fmaf(w3, r3, w4 * r4))));
                float s1 = fmaf(w0, r1, fmaf(w1, r2, fmaf(w2, r3, fmaf(w3, r4, w4 * r5))));
                v = fmaxf(fmaxf(s0, s1) + bb, 0.f);
            }
            xt0[ci0][p] = v;
        }
    }
    __syncthreads();
    // conv1: CG=2 groups of 16 couts, 128 positions each, 1 output/thread
    int cg = tid >> 7, jj = tid & 127;
    int cgu = __builtin_amdgcn_readfirstlane(cg);
    const float* wb = wt1 + cgu * 16;
    float a0[16], a1[16];
#pragma unroll
    for (int q = 0; q < 16; ++q) { a0[q] = 0.f; a1[q] = 0.f; }
#pragma unroll 1
    for (int ci = 0; ci < 16; ++ci) {
        const float2* xr = reinterpret_cast<const float2*>(&xt0[ci][0]);
        float2 xA = xr[jj], xB = xr[jj + 1], xC = xr[jj + 2];
        float xv[6] = { xA.x, xA.y, xB.x, xB.y, xC.x, xC.y };
#pragma unroll
        for (int t = 0; t < 5; ++t) {
            const float4* wp = reinterpret_cast<const float4*>(wb + (ci * 5 + t) * 32);
            float xa = xv[t], xc = xv[t + 1];
#pragma unroll
            for (int q4 = 0; q4 < 4; ++q4) {
                float4 w = wp[q4];
                int q = q4 * 4;
                a0[q+0] = fmaf(w.x, xa, a0[q+0]); a0[q+1] = fmaf(w.y, xa, a0[q+1]);
                a0[q+2] = fmaf(w.z, xa, a0[q+2]); a0[q+3] = fmaf(w.w, xa, a0[q+3]);
                a1[q+0] = fmaf(w.x, xc, a1[q+0]); a1[q+1] = fmaf(w.y, xc, a1[q+1]);
                a1[q+2] = fmaf(w.z, xc, a1[q+2]); a1[q+3] = fmaf(w.w, xc, a1[q+3]);
            }
        }
    }
    int j = j0 + jj;
    size_t obase = ((size_t)b * 32 + cgu * 16) * 3840 + j;
#pragma unroll
    for (int q = 0; q < 16; ++q) {
        float vb = b1[cgu * 16 + q];
        out[obase + (size_t)q * 3840] = fmaxf(fmaxf(a0[q], a1[q]) + vb, 0.f);
    }
}

// ---------------- fused conv2 + adaptive avgpool: (B,32,3840) -> xseq (B,64,64)
// block = 60 output positions = exactly 2 avgpool bins
__global__ __launch_bounds__(256) void conv2p_kernel(
    const float* __restrict__ in, const float* __restrict__ wt2,
    const float* __restrict__ b2, float* __restrict__ xs)
{
    __shared__ float xt[32 * 132];   // rows padded to 132 (8B-aligned, OOB-safe)
    int b = blockIdx.y, tid = threadIdx.x;
    int j0 = blockIdx.x * 60;
    for (int i = tid; i < 32 * 132; i += 256) {
        int ci = i / 132, p = i % 132;
        int gp = 2 * j0 - 2 + p;
        xt[i] = (gp >= 0 && gp < 3840) ? in[((size_t)b * 32 + ci) * 3840 + gp] : 0.f;
    }
    __syncthreads();
    int cg = tid >> 6, jj = tid & 63;     // 4 groups x 64 lanes (jj<60 active)
    int cgu = __builtin_amdgcn_readfirstlane(cg);
    const float* wb = wt2 + cgu * 16;
    float a0[16], a1[16];
#pragma unroll
    for (int q = 0; q < 16; ++q) { a0[q] = 0.f; a1[q] = 0.f; }
#pragma unroll 1
    for (int ci = 0; ci < 32; ++ci) {
        const float2* xr = reinterpret_cast<const float2*>(xt + ci * 132);
        float2 xA = xr[jj], xB = xr[jj + 1], xC = xr[jj + 2];
        float xv[6] = { xA.x, xA.y, xB.x, xB.y, xC.x, xC.y };
#pragma unroll
        for (int t = 0; t < 5; ++t) {
            const float4* wp = reinterpret_cast<const float4*>(wb + (ci * 5 + t) * 64);
            float xa = xv[t], xc = xv[t + 1];
#pragma unroll
            for (int q4 = 0; q4 < 4; ++q4) {
                float4 w = wp[q4];
                int q = q4 * 4;
                a0[q+0] = fmaf(w.x, xa, a0[q+0]); a0[q+1] = fmaf(w.y, xa, a0[q+1]);
                a0[q+2] = fmaf(w.z, xa, a0[q+2]); a0[q+3] = fmaf(w.w, xa, a0[q+3]);
                a1[q+0] = fmaf(w.x, xc, a1[q+0]); a1[q+1] = fmaf(w.y, xc, a1[q+1]);
                a1[q+2] = fmaf(w.z, xc, a1[q+2]); a1[q+3] = fmaf(w.w, xc, a1[q+3]);
            }
        }
    }
    __syncthreads();
    float* outt = xt;                 // reuse: [64 co][stride 61] = 3904 <= 4224
    if (jj < 60) {
#pragma unroll
        for (int q = 0; q < 16; ++q) {
            float vb = b2[cgu * 16 + q];
            outt[(cgu * 16 + q) * 61 + jj] = fmaxf(fmaxf(a0[q], a1[q]) + vb, 0.f);
        }
    }
    __syncthreads();
    if (tid < 128) {
        int co = tid & 63, bin = tid >> 6;
        const float* r = outt + co * 61 + bin * 30;
        float s = 0.f;
#pragma unroll
        for (int k = 0; k < 30; ++k) s += r[k];
        xs[((size_t)b * 64 + (blockIdx.x * 2 + bin)) * 64 + co] = s * (1.f / 30.f);
    }
}

// ---------------- LSTM: 2 layers fused, one block per batch element.
__global__ __launch_bounds__(256) void lstm_kernel(
    const float* __restrict__ xseq,
    const float* __restrict__ wih0, const float* __restrict__ whh0,
    const float* __restrict__ bih0, const float* __restrict__ bhh0,
    const float* __restrict__ wih1, const float* __restrict__ whh1,
    const float* __restrict__ bih1, const float* __restrict__ bhh1,
    float* __restrict__ hseq)
{
    __shared__ float xb[64][64];
    __shared__ float xg[64][256];
    __shared__ float gb4[4][64];
    __shared__ float hb[64];
    int b = blockIdx.x;
    int tid = threadIdx.x;
    int wv = tid >> 6, ln = tid & 63;
    for (int i = tid; i < 4096; i += 256) xb[i >> 6][i & 63] = xseq[(size_t)b * 4096 + i];
    __syncthreads();
    float wr[64];
    for (int layer = 0; layer < 2; ++layer) {
        const float* wih = layer ? wih1 : wih0;
        const float* whh = layer ? whh1 : whh0;
        float bias = layer ? (bih1[tid] + bhh1[tid]) : (bih0[tid] + bhh0[tid]);
#pragma unroll
        for (int k4 = 0; k4 < 16; ++k4) {
            float4 v = reinterpret_cast<const float4*>(wih + (size_t)tid * 64)[k4];
            wr[k4 * 4 + 0] = v.x; wr[k4 * 4 + 1] = v.y;
            wr[k4 * 4 + 2] = v.z; wr[k4 * 4 + 3] = v.w;
        }
        for (int t = 0; t < 64; ++t) {
            float s0 = bias, s1 = 0.f, s2 = 0.f, s3 = 0.f;
#pragma unroll
            for (int k = 0; k < 64; k += 4) {
                s0 = fmaf(wr[k + 0], xb[t][k + 0], s0);
                s1 = fmaf(wr[k + 1], xb[t][k + 1], s1);
                s2 = fmaf(wr[k + 2], xb[t][k + 2], s2);
                s3 = fmaf(wr[k + 3], xb[t][k + 3], s3);
            }
            xg[t][tid] = (s0 + s1) + (s2 + s3);
        }
#pragma unroll
        for (int k4 = 0; k4 < 16; ++k4) {
            float4 v = reinterpret_cast<const float4*>(whh + (size_t)tid * 64)[k4];
            wr[k4 * 4 + 0] = v.x; wr[k4 * 4 + 1] = v.y;
            wr[k4 * 4 + 2] = v.z; wr[k4 * 4 + 3] = v.w;
        }
        if (tid < 64) hb[tid] = 0.f;
        float c = 0.f;
        __syncthreads();
        for (int t = 0; t < 64; ++t) {
            float s0 = xg[t][tid], s1 = 0.f, s2 = 0.f, s3 = 0.f;
#pragma unroll
            for (int k = 0; k < 64; k += 4) {
                s0 = fmaf(wr[k + 0], hb[k + 0], s0);
                s1 = fmaf(wr[k + 1], hb[k + 1], s1);
                s2 = fmaf(wr[k + 2], hb[k + 2], s2);
                s3 = fmaf(wr[k + 3], hb[k + 3], s3);
            }
            float acc = (s0 + s1) + (s2 + s3);
            float a;
            if (wv == 2) a = tanhf(acc);
            else         a = 1.f / (1.f + __expf(-acc));
            gb4[wv][ln] = a;
            __syncthreads();
            float gi = gb4[0][ln], gf = gb4[1][ln], gg = gb4[2][ln], go = gb4[3][ln];
            c = fmaf(gf, c, gi * gg);
            float h = go * tanhf(c);
            if (wv == 0) {
                hb[ln] = h;
                if (layer == 0) xb[t][ln] = h;
                else hseq[((size_t)b * 64 + t) * 64 + ln] = h;
            }
            __syncthreads();
        }
    }
}

// ---------------- graph: correlation + kthvalue(192) + adjacency + 3x GCN + classifier
__global__ __launch_bounds__(256) void graph_kernel(
    const float* __restrict__ hseq,
    const float* __restrict__ gw0, const float* __restrict__ gb0,
    const float* __restrict__ gw1, const float* __restrict__ gb1,
    const float* __restrict__ gw2, const float* __restrict__ gb2,
    const float* __restrict__ clw, const float* __restrict__ clb,
    float* __restrict__ out)
{
    __shared__ float nf[16][257];   // ORIGINAL node features (GCN input!)
    __shared__ float sb[16][257];   // normalized copy, then GCN L0 aggregation
    __shared__ float red[16][17];
    __shared__ float mean[16], rstd[16];
    __shared__ float C[256];
    __shared__ float adj[16][16];
    __shared__ float thrv;
    __shared__ float bufA[16][65], bufB[16][65], bufC[16][65];
    __shared__ float emb[64];
    int b = blockIdx.x, tid = threadIdx.x;
    for (int i = tid; i < 4096; i += 256) nf[i >> 8][i & 255] = hseq[(size_t)b * 4096 + i];
    __syncthreads();
    int nd = tid >> 4, sub = tid & 15;
    {
        float s = 0.f;
        for (int f = sub; f < 256; f += 16) s += nf[nd][f];
        red[nd][sub] = s;
    }
    __syncthreads();
    if (tid < 16) {
        float m = 0.f;
        for (int i = 0; i < 16; ++i) m += red[tid][i];
        mean[tid] = m * (1.f / 256.f);
    }
    __syncthreads();
    {
        float mu = mean[nd];
        float ss = 0.f;
        for (int f = sub; f < 256; f += 16) { float d = nf[nd][f] - mu; ss = fmaf(d, d, ss); }
        red[nd][sub] = ss;
    }
    __syncthreads();
    if (tid < 16) {
        float m = 0.f;
        for (int i = 0; i < 16; ++i) m += red[tid][i];
        rstd[tid] = 1.f / (sqrtf(m * (1.f / 255.f)) + 1e-8f);
    }
    __syncthreads();
    for (int i = tid; i < 4096; i += 256) {
        int n = i >> 8, f = i & 255;
        sb[n][f] = (nf[n][f] - mean[n]) * rstd[n];
    }
    __syncthreads();
    {
        int n = tid >> 4, m = tid & 15;
        float a0 = 0, a1 = 0, a2 = 0, a3 = 0;
        for (int f = 0; f < 256; f += 4) {
            a0 = fmaf(sb[n][f + 0], sb[m][f + 0], a0);
            a1 = fmaf(sb[n][f + 1], sb[m][f + 1], a1);
            a2 = fmaf(sb[n][f + 2], sb[m][f + 2], a2);
            a3 = fmaf(sb[n][f + 3], sb[m][f + 3], a3);
        }
        C[tid] = ((a0 + a1) + (a2 + a3)) * (1.f / 256.f);
    }
    __syncthreads();
    {
        float v = C[tid];
        int cnt = 0, eq = 0;
        for (int j2 = 0; j2 < 256; ++j2) {
            float vj = C[j2];
            cnt += (vj < v);
            eq  += (vj == v);
        }
        if (cnt <= 191 && 191 < cnt + eq) thrv = v;
    }
    __syncthreads();
    {
        int n = tid >> 4, m = tid & 15;
        adj[n][m] = (C[tid] > thrv && n != m) ? 1.f : 0.f;
    }
    __syncthreads();
    for (int i = tid; i < 4096; i += 256) {
        int n = i >> 8, f = i & 255;
        float acc = nf[n][f];
#pragma unroll
        for (int m = 0; m < 16; ++m) acc = fmaf(adj[n][m], nf[m][f], acc);
        sb[n][f] = acc;
    }
    __syncthreads();
    for (int i = tid; i < 1024; i += 256) {
        int n = i >> 6, o = i & 63;
        const float4* wr4 = reinterpret_cast<const float4*>(gw0 + (size_t)o * 256);
        float acc = gb0[o];
        for (int f4 = 0; f4 < 64; ++f4) {
            float4 wv = wr4[f4];
            int f = f4 * 4;
            acc = fmaf(sb[n][f + 0], wv.x, acc);
            acc = fmaf(sb[n][f + 1], wv.y, acc);
            acc = fmaf(sb[n][f + 2], wv.z, acc);
            acc = fmaf(sb[n][f + 3], wv.w, acc);
        }
        bufA[n][o] = fmaxf(acc, 0.f);
    }
    __syncthreads();
    for (int i = tid; i < 1024; i += 256) {
        int n = i >> 6, f = i & 63;
        float acc = bufA[n][f];
#pragma unroll
        for (int m = 0; m < 16; ++m) acc = fmaf(adj[n][m], bufA[m][f], acc);
        bufB[n][f] = acc;
    }
    __syncthreads();
    for (int i = tid; i < 1024; i += 256) {
        int n = i >> 6, o = i & 63;
        const float4* wr4 = reinterpret_cast<const float4*>(gw1 + (size_t)o * 64);
        float acc = gb1[o];
        for (int f4 = 0; f4 < 16; ++f4) {
            float4 wv = wr4[f4];
            int f = f4 * 4;
            acc = fmaf(bufB[n][f + 0], wv.x, acc);
            acc = fmaf(bufB[n][f + 1], wv.y, acc);
            acc = fmaf(bufB[n][f + 2], wv.z, acc);
            acc = fmaf(bufB[n][f + 3], wv.w, acc);
        }
        bufC[n][o] = fmaxf(acc, 0.f);
    }
    __syncthreads();
    for (int i = tid; i < 1024; i += 256) {
        int n = i >> 6, f = i & 63;
        float acc = bufC[n][f];
#pragma unroll
        for (int m = 0; m < 16; ++m) acc = fmaf(adj[n][m], bufC[m][f], acc);
        bufA[n][f] = acc;
    }
    __syncthreads();
    for (int i = tid; i < 1024; i += 256) {
        int n = i >> 6, o = i & 63;
        const float4* wr4 = reinterpret_cast<const float4*>(gw2 + (size_t)o * 64);
        float acc = gb2[o];
        for (int f4 = 0; f4 < 16; ++f4) {
            float4 wv = wr4[f4];
            int f = f4 * 4;
            acc = fmaf(bufA[n][f + 0], wv.x, acc);
            acc = fmaf(bufA[n][f + 1], wv.y, acc);
            acc = fmaf(bufA[n][f + 2], wv.z, acc);
            acc = fmaf(bufA[n][f + 3], wv.w, acc);
        }
        bufB[n][o] = fmaxf(acc, 0.f);
    }
    __syncthreads();
    if (tid < 64) {
        float mx = bufB[0][tid];
#pragma unroll
        for (int n = 1; n < 16; ++n) mx = fmaxf(mx, bufB[n][tid]);
        emb[tid] = mx;
    }
    __syncthreads();
    if (tid < 5) {
        float acc = clb[tid];
#pragma unroll
        for (int o = 0; o < 64; ++o) acc = fmaf(emb[o], clw[tid * 64 + o], acc);
        out[(size_t)b * 5 + tid] = acc;
    }
}

extern "C" void kernel_launch(void* const* d_in, const int* in_sizes, int n_in,
                              void* d_out, int out_size, void* d_ws, size_t ws_size,
                              hipStream_t stream)
{
    const float* x    = (const float*)d_in[0];
    const float* cw0  = (const float*)d_in[1];
    const float* cb0  = (const float*)d_in[2];
    const float* bng0 = (const float*)d_in[3];
    const float* bnb0 = (const float*)d_in[4];
    const float* bnm0 = (const float*)d_in[5];
    const float* bnv0 = (const float*)d_in[6];
    const float* cw1  = (const float*)d_in[7];
    const float* cb1  = (const float*)d_in[8];
    const float* bng1 = (const float*)d_in[9];
    const float* bnb1 = (const float*)d_in[10];
    const float* bnm1 = (const float*)d_in[11];
    const float* bnv1 = (const float*)d_in[12];
    const float* cw2  = (const float*)d_in[13];
    const float* cb2  = (const float*)d_in[14];
    const float* bng2 = (const float*)d_in[15];
    const float* bnb2 = (const float*)d_in[16];
    const float* bnm2 = (const float*)d_in[17];
    const float* bnv2 = (const float*)d_in[18];
    const float* wih0 = (const float*)d_in[19];
    const float* whh0 = (const float*)d_in[20];
    const float* bih0 = (const float*)d_in[21];
    const float* bhh0 = (const float*)d_in[22];
    const float* wih1 = (const float*)d_in[23];
    const float* whh1 = (const float*)d_in[24];
    const float* bih1 = (const float*)d_in[25];
    const float* bhh1 = (const float*)d_in[26];
    const float* gw0  = (const float*)d_in[27];
    const float* gb0  = (const float*)d_in[28];
    const float* gw1  = (const float*)d_in[29];
    const float* gb1  = (const float*)d_in[30];
    const float* gw2  = (const float*)d_in[31];
    const float* gb2  = (const float*)d_in[32];
    const float* clw  = (const float*)d_in[33];
    const float* clb  = (const float*)d_in[34];

    // ws layout (floats)
    float* f0  = (float*)d_ws;            // conv1 out: 256*32*3840 = 31457280
    float* xs  = f0 + 31457280;           // (B,64,64) = 1048576
    float* hs  = xs + 1048576;            // (B,64,64) = 1048576
    float* wt1 = hs + 1048576;            // 2560
    float* b1  = wt1 + 2560;              // 32
    float* wt2 = b1 + 32;                 // 10240
    float* b2  = wt2 + 10240;             // 64
    float* w0f = b2 + 64;                 // 80
    float* b0f = w0f + 80;                // 16

    prep_weights_kernel<<<1, 256, 0, stream>>>(
        cw0, cb0, bng0, bnb0, bnm0, bnv0,
        cw1, cb1, bng1, bnb1, bnm1, bnv1,
        cw2, cb2, bng2, bnb2, bnm2, bnv2,
        wt1, b1, wt2, b2, w0f, b0f);
    conv01_kernel<<<dim3(30, 256), 256, 0, stream>>>(x, wt1, b1, w0f, b0f, f0);
    conv2p_kernel<<<dim3(32, 256), 256, 0, stream>>>(f0, wt2, b2, xs);
    lstm_kernel<<<256, 256, 0, stream>>>(xs, wih0, whh0, bih0, bhh0,
                                         wih1, whh1, bih1, bhh1, hs);
    graph_kernel<<<256, 256, 0, stream>>>(hs, gw0, gb0, gw1, gb1, gw2, gb2,
                                          clw, clb, (float*)d_out);
}

// Round 6
// 497.398 us; speedup vs baseline: 1.4292x; 1.0024x over previous
//
#include <hip/hip_runtime.h>
#include <math.h>

typedef __attribute__((ext_vector_type(2))) float v2f;

// ---------------- prep: transpose + BN-fold conv weights into [ci][t][co] layout
__global__ __launch_bounds__(256) void prep_weights_kernel(
    const float* __restrict__ cw0, const float* __restrict__ cb0,
    const float* __restrict__ bng0, const float* __restrict__ bnb0,
    const float* __restrict__ bnm0, const float* __restrict__ bnv0,
    const float* __restrict__ cw1, const float* __restrict__ cb1,
    const float* __restrict__ bng1, const float* __restrict__ bnb1,
    const float* __restrict__ bnm1, const float* __restrict__ bnv1,
    const float* __restrict__ cw2, const float* __restrict__ cb2,
    const float* __restrict__ bng2, const float* __restrict__ bnb2,
    const float* __restrict__ bnm2, const float* __restrict__ bnv2,
    float* __restrict__ wt1, float* __restrict__ b1,
    float* __restrict__ wt2, float* __restrict__ b2,
    float* __restrict__ w0f, float* __restrict__ b0f)
{
    int tid = threadIdx.x;
    // wt1[(ci*5+t)*32+co] = cw1[(co*16+ci)*5+t] * s1[co]
    for (int i = tid; i < 2560; i += 256) {
        int co = i & 31, r = i >> 5, t = r % 5, ci = r / 5;
        float s = bng1[co] * rsqrtf(bnv1[co] + 1e-5f);
        wt1[i] = cw1[(co * 16 + ci) * 5 + t] * s;
    }
    if (tid < 32) {
        float s = bng1[tid] * rsqrtf(bnv1[tid] + 1e-5f);
        b1[tid] = (cb1[tid] - bnm1[tid]) * s + bnb1[tid];
    }
    // wt2[(ci*5+t)*64+co] = cw2[(co*32+ci)*5+t] * s2[co]
    for (int i = tid; i < 10240; i += 256) {
        int co = i & 63, r = i >> 6, t = r % 5, ci = r / 5;
        float s = bng2[co] * rsqrtf(bnv2[co] + 1e-5f);
        wt2[i] = cw2[(co * 32 + ci) * 5 + t] * s;
    }
    if (tid < 64) {
        float s = bng2[tid] * rsqrtf(bnv2[tid] + 1e-5f);
        b2[tid] = (cb2[tid] - bnm2[tid]) * s + bnb2[tid];
    }
    if (tid < 80) {
        int co = tid / 5;
        float s = bng0[co] * rsqrtf(bnv0[co] + 1e-5f);
        w0f[tid] = cw0[tid] * s;
    }
    if (tid < 16) {
        float s = bng0[tid] * rsqrtf(bnv0[tid] + 1e-5f);
        b0f[tid] = (cb0[tid] - bnm0[tid]) * s + bnb0[tid];
    }
}

// ---------------- fused conv0 + conv1: x (B,1,15360) -> (B,32,3840)
// conv1 inner loop uses packed-fp32 candidates (v2f + elementwise_fma).
// Pairing is across OUTPUT channels; each cout's accumulation chain keeps the
// exact (ci,t) order of the scalar version -> bit-identical results.
__global__ __launch_bounds__(256) void conv01_kernel(
    const float* __restrict__ x, const float* __restrict__ wt1,
    const float* __restrict__ b1, const float* __restrict__ w0f,
    const float* __restrict__ b0f, float* __restrict__ out)
{
    __shared__ float raw[528];
    __shared__ float xt0[16][260];
    __shared__ float w0l[80];
    __shared__ float b0l[16];
    int b = blockIdx.y, tid = threadIdx.x;
    int j0 = blockIdx.x * 128;
    const float* xb = x + (size_t)b * 15360;
    for (int p = tid; p < 524; p += 256) {
        int g = 4 * j0 - 6 + p;
        raw[p] = (g >= 0 && g < 15360) ? xb[g] : 0.f;
    }
    if (tid < 80) w0l[tid] = w0f[tid];
    if (tid < 16) b0l[tid] = b0f[tid];
    __syncthreads();
#pragma unroll 1
    for (int ci0 = 0; ci0 < 16; ++ci0) {
        float w0 = w0l[ci0 * 5 + 0], w1 = w0l[ci0 * 5 + 1], w2 = w0l[ci0 * 5 + 2],
              w3 = w0l[ci0 * 5 + 3], w4 = w0l[ci0 * 5 + 4];
        float bb = b0l[ci0];
        for (int p = tid; p < 260; p += 256) {
            int q = 2 * j0 - 2 + p;
            float v = 0.f;
            if (q >= 0 && q < 7680) {
                float r0 = raw[2*p], r1 = raw[2*p+1], r2 = raw[2*p+2],
                      r3 = raw[2*p+3], r4 = raw[2*p+4], r5 = raw[2*p+5];
                float s0 = fmaf(w0, r0, fmaf(w1, r1, fmaf(w2, r2, fmaf(w3, r3, w4 * r4))));
                float s1 = fmaf(w0, r1, fmaf(w1, r2, fmaf(w2, r3, fmaf(w3, r4, w4 * r5))));
                v = fmaxf(fmaxf(s0, s1) + bb, 0.f);
            }
            xt0[ci0][p] = v;
        }
    }
    __syncthreads();
    int cg = tid >> 7, jj = tid & 127;
    int cgu = __builtin_amdgcn_readfirstlane(cg);
    const float* wb = wt1 + cgu * 16;
    v2f a0[8], a1[8];
#pragma unroll
    for (int q = 0; q < 8; ++q) { a0[q] = (v2f){0.f, 0.f}; a1[q] = (v2f){0.f, 0.f}; }
#pragma unroll 1
    for (int ci = 0; ci < 16; ++ci) {
        const float2* xr = reinterpret_cast<const float2*>(&xt0[ci][0]);
        float2 xA = xr[jj], xB = xr[jj + 1], xC = xr[jj + 2];
        float xv[6] = { xA.x, xA.y, xB.x, xB.y, xC.x, xC.y };
#pragma unroll
        for (int t = 0; t < 5; ++t) {
            const v2f* wp2 = reinterpret_cast<const v2f*>(wb + (ci * 5 + t) * 32);
            v2f va = { xv[t], xv[t] };
            v2f vc = { xv[t + 1], xv[t + 1] };
#pragma unroll
            for (int q2 = 0; q2 < 8; ++q2) {
                v2f w = wp2[q2];
                a0[q2] = __builtin_elementwise_fma(w, va, a0[q2]);
                a1[q2] = __builtin_elementwise_fma(w, vc, a1[q2]);
            }
        }
    }
    int j = j0 + jj;
    size_t obase = ((size_t)b * 32 + cgu * 16) * 3840 + j;
#pragma unroll
    for (int q2 = 0; q2 < 8; ++q2) {
#pragma unroll
        for (int cpp = 0; cpp < 2; ++cpp) {
            int q = 2 * q2 + cpp;
            float vb = b1[cgu * 16 + q];
            float m = fmaxf(a0[q2][cpp], a1[q2][cpp]) + vb;
            out[obase + (size_t)q * 3840] = fmaxf(m, 0.f);
        }
    }
}

// ---------------- fused conv2 + adaptive avgpool: (B,32,3840) -> xseq (B,64,64)
// block = 60 output positions = exactly 2 avgpool bins; packed-fp32 inner loop
__global__ __launch_bounds__(256) void conv2p_kernel(
    const float* __restrict__ in, const float* __restrict__ wt2,
    const float* __restrict__ b2, float* __restrict__ xs)
{
    __shared__ float xt[32 * 132];   // rows padded to 132
    int b = blockIdx.y, tid = threadIdx.x;
    int j0 = blockIdx.x * 60;
    for (int i = tid; i < 32 * 132; i += 256) {
        int ci = i / 132, p = i % 132;
        int gp = 2 * j0 - 2 + p;
        xt[i] = (gp >= 0 && gp < 3840) ? in[((size_t)b * 32 + ci) * 3840 + gp] : 0.f;
    }
    __syncthreads();
    int cg = tid >> 6, jj = tid & 63;     // 4 groups x 64 lanes (jj<60 active)
    int cgu = __builtin_amdgcn_readfirstlane(cg);
    const float* wb = wt2 + cgu * 16;
    v2f a0[8], a1[8];
#pragma unroll
    for (int q = 0; q < 8; ++q) { a0[q] = (v2f){0.f, 0.f}; a1[q] = (v2f){0.f, 0.f}; }
#pragma unroll 1
    for (int ci = 0; ci < 32; ++ci) {
        const float2* xr = reinterpret_cast<const float2*>(xt + ci * 132);
        float2 xA = xr[jj], xB = xr[jj + 1], xC = xr[jj + 2];
        float xv[6] = { xA.x, xA.y, xB.x, xB.y, xC.x, xC.y };
#pragma unroll
        for (int t = 0; t < 5; ++t) {
            const v2f* wp2 = reinterpret_cast<const v2f*>(wb + (ci * 5 + t) * 64);
            v2f va = { xv[t], xv[t] };
            v2f vc = { xv[t + 1], xv[t + 1] };
#pragma unroll
            for (int q2 = 0; q2 < 8; ++q2) {
                v2f w = wp2[q2];
                a0[q2] = __builtin_elementwise_fma(w, va, a0[q2]);
                a1[q2] = __builtin_elementwise_fma(w, vc, a1[q2]);
            }
        }
    }
    __syncthreads();
    float* outt = xt;                 // reuse: [64 co][stride 61] = 3904 <= 4224
    if (jj < 60) {
#pragma unroll
        for (int q2 = 0; q2 < 8; ++q2) {
#pragma unroll
            for (int cpp = 0; cpp < 2; ++cpp) {
                int q = 2 * q2 + cpp;
                int co = cgu * 16 + q;
                float m = fmaxf(a0[q2][cpp], a1[q2][cpp]) + b2[co];
                outt[co * 61 + jj] = fmaxf(m, 0.f);
            }
        }
    }
    __syncthreads();
    if (tid < 128) {
        int co = tid & 63, bin = tid >> 6;
        const float* r = outt + co * 61 + bin * 30;
        float s = 0.f;
#pragma unroll
        for (int k = 0; k < 30; ++k) s += r[k];
        xs[((size_t)b * 64 + (blockIdx.x * 2 + bin)) * 64 + co] = s * (1.f / 30.f);
    }
}

// ---------------- LSTM: 2 layers fused, one block per batch element.
__global__ __launch_bounds__(256) void lstm_kernel(
    const float* __restrict__ xseq,
    const float* __restrict__ wih0, const float* __restrict__ whh0,
    const float* __restrict__ bih0, const float* __restrict__ bhh0,
    const float* __restrict__ wih1, const float* __restrict__ whh1,
    const float* __restrict__ bih1, const float* __restrict__ bhh1,
    float* __restrict__ hseq)
{
    __shared__ float xb[64][64];
    __shared__ float xg[64][256];
    __shared__ float gb4[4][64];
    __shared__ float hb[64];
    int b = blockIdx.x;
    int tid = threadIdx.x;
    int wv = tid >> 6, ln = tid & 63;
    for (int i = tid; i < 4096; i += 256) xb[i >> 6][i & 63] = xseq[(size_t)b * 4096 + i];
    __syncthreads();
    float wr[64];
    for (int layer = 0; layer < 2; ++layer) {
        const float* wih = layer ? wih1 : wih0;
        const float* whh = layer ? whh1 : whh0;
        float bias = layer ? (bih1[tid] + bhh1[tid]) : (bih0[tid] + bhh0[tid]);
#pragma unroll
        for (int k4 = 0; k4 < 16; ++k4) {
            float4 v = reinterpret_cast<const float4*>(wih + (size_t)tid * 64)[k4];
            wr[k4 * 4 + 0] = v.x; wr[k4 * 4 + 1] = v.y;
            wr[k4 * 4 + 2] = v.z; wr[k4 * 4 + 3] = v.w;
        }
        for (int t = 0; t < 64; ++t) {
            float s0 = bias, s1 = 0.f, s2 = 0.f, s3 = 0.f;
#pragma unroll
            for (int k = 0; k < 64; k += 4) {
                s0 = fmaf(wr[k + 0], xb[t][k + 0], s0);
                s1 = fmaf(wr[k + 1], xb[t][k + 1], s1);
                s2 = fmaf(wr[k + 2], xb[t][k + 2], s2);
                s3 = fmaf(wr[k + 3], xb[t][k + 3], s3);
            }
            xg[t][tid] = (s0 + s1) + (s2 + s3);
        }
#pragma unroll
        for (int k4 = 0; k4 < 16; ++k4) {
            float4 v = reinterpret_cast<const float4*>(whh + (size_t)tid * 64)[k4];
            wr[k4 * 4 + 0] = v.x; wr[k4 * 4 + 1] = v.y;
            wr[k4 * 4 + 2] = v.z; wr[k4 * 4 + 3] = v.w;
        }
        if (tid < 64) hb[tid] = 0.f;
        float c = 0.f;
        __syncthreads();
        for (int t = 0; t < 64; ++t) {
            float s0 = xg[t][tid], s1 = 0.f, s2 = 0.f, s3 = 0.f;
#pragma unroll
            for (int k = 0; k < 64; k += 4) {
                s0 = fmaf(wr[k + 0], hb[k + 0], s0);
                s1 = fmaf(wr[k + 1], hb[k + 1], s1);
                s2 = fmaf(wr[k + 2], hb[k + 2], s2);
                s3 = fmaf(wr[k + 3], hb[k + 3], s3);
            }
            float acc = (s0 + s1) + (s2 + s3);
            float a;
            if (wv == 2) a = tanhf(acc);
            else         a = 1.f / (1.f + __expf(-acc));
            gb4[wv][ln] = a;
            __syncthreads();
            float gi = gb4[0][ln], gf = gb4[1][ln], gg = gb4[2][ln], go = gb4[3][ln];
            c = fmaf(gf, c, gi * gg);
            float h = go * tanhf(c);
            if (wv == 0) {
                hb[ln] = h;
                if (layer == 0) xb[t][ln] = h;
                else hseq[((size_t)b * 64 + t) * 64 + ln] = h;
            }
            __syncthreads();
        }
    }
}

// ---------------- graph: correlation + kthvalue(192) + adjacency + 3x GCN + classifier
__global__ __launch_bounds__(256) void graph_kernel(
    const float* __restrict__ hseq,
    const float* __restrict__ gw0, const float* __restrict__ gb0,
    const float* __restrict__ gw1, const float* __restrict__ gb1,
    const float* __restrict__ gw2, const float* __restrict__ gb2,
    const float* __restrict__ clw, const float* __restrict__ clb,
    float* __restrict__ out)
{
    __shared__ float nf[16][257];
    __shared__ float sb[16][257];
    __shared__ float red[16][17];
    __shared__ float mean[16], rstd[16];
    __shared__ float C[256];
    __shared__ float adj[16][16];
    __shared__ float thrv;
    __shared__ float bufA[16][65], bufB[16][65], bufC[16][65];
    __shared__ float emb[64];
    int b = blockIdx.x, tid = threadIdx.x;
    for (int i = tid; i < 4096; i += 256) nf[i >> 8][i & 255] = hseq[(size_t)b * 4096 + i];
    __syncthreads();
    int nd = tid >> 4, sub = tid & 15;
    {
        float s = 0.f;
        for (int f = sub; f < 256; f += 16) s += nf[nd][f];
        red[nd][sub] = s;
    }
    __syncthreads();
    if (tid < 16) {
        float m = 0.f;
        for (int i = 0; i < 16; ++i) m += red[tid][i];
        mean[tid] = m * (1.f / 256.f);
    }
    __syncthreads();
    {
        float mu = mean[nd];
        float ss = 0.f;
        for (int f = sub; f < 256; f += 16) { float d = nf[nd][f] - mu; ss = fmaf(d, d, ss); }
        red[nd][sub] = ss;
    }
    __syncthreads();
    if (tid < 16) {
        float m = 0.f;
        for (int i = 0; i < 16; ++i) m += red[tid][i];
        rstd[tid] = 1.f / (sqrtf(m * (1.f / 255.f)) + 1e-8f);
    }
    __syncthreads();
    for (int i = tid; i < 4096; i += 256) {
        int n = i >> 8, f = i & 255;
        sb[n][f] = (nf[n][f] - mean[n]) * rstd[n];
    }
    __syncthreads();
    {
        int n = tid >> 4, m = tid & 15;
        float a0 = 0, a1 = 0, a2 = 0, a3 = 0;
        for (int f = 0; f < 256; f += 4) {
            a0 = fmaf(sb[n][f + 0], sb[m][f + 0], a0);
            a1 = fmaf(sb[n][f + 1], sb[m][f + 1], a1);
            a2 = fmaf(sb[n][f + 2], sb[m][f + 2], a2);
            a3 = fmaf(sb[n][f + 3], sb[m][f + 3], a3);
        }
        C[tid] = ((a0 + a1) + (a2 + a3)) * (1.f / 256.f);
    }
    __syncthreads();
    {
        float v = C[tid];
        int cnt = 0, eq = 0;
        for (int j2 = 0; j2 < 256; ++j2) {
            float vj = C[j2];
            cnt += (vj < v);
            eq  += (vj == v);
        }
        if (cnt <= 191 && 191 < cnt + eq) thrv = v;
    }
    __syncthreads();
    {
        int n = tid >> 4, m = tid & 15;
        adj[n][m] = (C[tid] > thrv && n != m) ? 1.f : 0.f;
    }
    __syncthreads();
    for (int i = tid; i < 4096; i += 256) {
        int n = i >> 8, f = i & 255;
        float acc = nf[n][f];
#pragma unroll
        for (int m = 0; m < 16; ++m) acc = fmaf(adj[n][m], nf[m][f], acc);
        sb[n][f] = acc;
    }
    __syncthreads();
    for (int i = tid; i < 1024; i += 256) {
        int n = i >> 6, o = i & 63;
        const float4* wr4 = reinterpret_cast<const float4*>(gw0 + (size_t)o * 256);
        float acc = gb0[o];
        for (int f4 = 0; f4 < 64; ++f4) {
            float4 wv = wr4[f4];
            int f = f4 * 4;
            acc = fmaf(sb[n][f + 0], wv.x, acc);
            acc = fmaf(sb[n][f + 1], wv.y, acc);
            acc = fmaf(sb[n][f + 2], wv.z, acc);
            acc = fmaf(sb[n][f + 3], wv.w, acc);
        }
        bufA[n][o] = fmaxf(acc, 0.f);
    }
    __syncthreads();
    for (int i = tid; i < 1024; i += 256) {
        int n = i >> 6, f = i & 63;
        float acc = bufA[n][f];
#pragma unroll
        for (int m = 0; m < 16; ++m) acc = fmaf(adj[n][m], bufA[m][f], acc);
        bufB[n][f] = acc;
    }
    __syncthreads();
    for (int i = tid; i < 1024; i += 256) {
        int n = i >> 6, o = i & 63;
        const float4* wr4 = reinterpret_cast<const float4*>(gw1 + (size_t)o * 64);
        float acc = gb1[o];
        for (int f4 = 0; f4 < 16; ++f4) {
            float4 wv = wr4[f4];
            int f = f4 * 4;
            acc = fmaf(bufB[n][f + 0], wv.x, acc);
            acc = fmaf(bufB[n][f + 1], wv.y, acc);
            acc = fmaf(bufB[n][f + 2], wv.z, acc);
            acc = fmaf(bufB[n][f + 3], wv.w, acc);
        }
        bufC[n][o] = fmaxf(acc, 0.f);
    }
    __syncthreads();
    for (int i = tid; i < 1024; i += 256) {
        int n = i >> 6, f = i & 63;
        float acc = bufC[n][f];
#pragma unroll
        for (int m = 0; m < 16; ++m) acc = fmaf(adj[n][m], bufC[m][f], acc);
        bufA[n][f] = acc;
    }
    __syncthreads();
    for (int i = tid; i < 1024; i += 256) {
        int n = i >> 6, o = i & 63;
        const float4* wr4 = reinterpret_cast<const float4*>(gw2 + (size_t)o * 64);
        float acc = gb2[o];
        for (int f4 = 0; f4 < 16; ++f4) {
            float4 wv = wr4[f4];
            int f = f4 * 4;
            acc = fmaf(bufA[n][f + 0], wv.x, acc);
            acc = fmaf(bufA[n][f + 1], wv.y, acc);
            acc = fmaf(bufA[n][f + 2], wv.z, acc);
            acc = fmaf(bufA[n][f + 3], wv.w, acc);
        }
        bufB[n][o] = fmaxf(acc, 0.f);
    }
    __syncthreads();
    if (tid < 64) {
        float mx = bufB[0][tid];
#pragma unroll
        for (int n = 1; n < 16; ++n) mx = fmaxf(mx, bufB[n][tid]);
        emb[tid] = mx;
    }
    __syncthreads();
    if (tid < 5) {
        float acc = clb[tid];
#pragma unroll
        for (int o = 0; o < 64; ++o) acc = fmaf(emb[o], clw[tid * 64 + o], acc);
        out[(size_t)b * 5 + tid] = acc;
    }
}

extern "C" void kernel_launch(void* const* d_in, const int* in_sizes, int n_in,
                              void* d_out, int out_size, void* d_ws, size_t ws_size,
                              hipStream_t stream)
{
    const float* x    = (const float*)d_in[0];
    const float* cw0  = (const float*)d_in[1];
    const float* cb0  = (const float*)d_in[2];
    const float* bng0 = (const float*)d_in[3];
    const float* bnb0 = (const float*)d_in[4];
    const float* bnm0 = (const float*)d_in[5];
    const float* bnv0 = (const float*)d_in[6];
    const float* cw1  = (const float*)d_in[7];
    const float* cb1  = (const float*)d_in[8];
    const float* bng1 = (const float*)d_in[9];
    const float* bnb1 = (const float*)d_in[10];
    const float* bnm1 = (const float*)d_in[11];
    const float* bnv1 = (const float*)d_in[12];
    const float* cw2  = (const float*)d_in[13];
    const float* cb2  = (const float*)d_in[14];
    const float* bng2 = (const float*)d_in[15];
    const float* bnb2 = (const float*)d_in[16];
    const float* bnm2 = (const float*)d_in[17];
    const float* bnv2 = (const float*)d_in[18];
    const float* wih0 = (const float*)d_in[19];
    const float* whh0 = (const float*)d_in[20];
    const float* bih0 = (const float*)d_in[21];
    const float* bhh0 = (const float*)d_in[22];
    const float* wih1 = (const float*)d_in[23];
    const float* whh1 = (const float*)d_in[24];
    const float* bih1 = (const float*)d_in[25];
    const float* bhh1 = (const float*)d_in[26];
    const float* gw0  = (const float*)d_in[27];
    const float* gb0  = (const float*)d_in[28];
    const float* gw1  = (const float*)d_in[29];
    const float* gb1  = (const float*)d_in[30];
    const float* gw2  = (const float*)d_in[31];
    const float* gb2  = (const float*)d_in[32];
    const float* clw  = (const float*)d_in[33];
    const float* clb  = (const float*)d_in[34];

    // ws layout (floats)
    float* f0  = (float*)d_ws;            // conv1 out: 256*32*3840 = 31457280
    float* xs  = f0 + 31457280;           // (B,64,64)
    float* hs  = xs + 1048576;            // (B,64,64)
    float* wt1 = hs + 1048576;            // 2560
    float* b1  = wt1 + 2560;              // 32
    float* wt2 = b1 + 32;                 // 10240
    float* b2  = wt2 + 10240;             // 64
    float* w0f = b2 + 64;                 // 80
    float* b0f = w0f + 80;                // 16

    prep_weights_kernel<<<1, 256, 0, stream>>>(
        cw0, cb0, bng0, bnb0, bnm0, bnv0,
        cw1, cb1, bng1, bnb1, bnm1, bnv1,
        cw2, cb2, bng2, bnb2, bnm2, bnv2,
        wt1, b1, wt2, b2, w0f, b0f);
    conv01_kernel<<<dim3(30, 256), 256, 0, stream>>>(x, wt1, b1, w0f, b0f, f0);
    conv2p_kernel<<<dim3(32, 256), 256, 0, stream>>>(f0, wt2, b2, xs);
    lstm_kernel<<<256, 256, 0, stream>>>(xs, wih0, whh0, bih0, bhh0,
                                         wih1, whh1, bih1, bhh1, hs);
    graph_kernel<<<256, 256, 0, stream>>>(hs, gw0, gb0, gw1, gb1, gw2, gb2,
                                          clw, clb, (float*)d_out);
}

// Round 7
// 483.121 us; speedup vs baseline: 1.4715x; 1.0296x over previous
//
#include <hip/hip_runtime.h>
#include <math.h>

typedef __attribute__((ext_vector_type(2))) float v2f;

// ---------------- prep: transpose + BN-fold conv weights into [ci][t][co] layout
__global__ __launch_bounds__(256) void prep_weights_kernel(
    const float* __restrict__ cw0, const float* __restrict__ cb0,
    const float* __restrict__ bng0, const float* __restrict__ bnb0,
    const float* __restrict__ bnm0, const float* __restrict__ bnv0,
    const float* __restrict__ cw1, const float* __restrict__ cb1,
    const float* __restrict__ bng1, const float* __restrict__ bnb1,
    const float* __restrict__ bnm1, const float* __restrict__ bnv1,
    const float* __restrict__ cw2, const float* __restrict__ cb2,
    const float* __restrict__ bng2, const float* __restrict__ bnb2,
    const float* __restrict__ bnm2, const float* __restrict__ bnv2,
    float* __restrict__ wt1, float* __restrict__ b1,
    float* __restrict__ wt2, float* __restrict__ b2,
    float* __restrict__ w0f, float* __restrict__ b0f)
{
    int tid = threadIdx.x;
    // wt1[(ci*5+t)*32+co] = cw1[(co*16+ci)*5+t] * s1[co]
    for (int i = tid; i < 2560; i += 256) {
        int co = i & 31, r = i >> 5, t = r % 5, ci = r / 5;
        float s = bng1[co] * rsqrtf(bnv1[co] + 1e-5f);
        wt1[i] = cw1[(co * 16 + ci) * 5 + t] * s;
    }
    if (tid < 32) {
        float s = bng1[tid] * rsqrtf(bnv1[tid] + 1e-5f);
        b1[tid] = (cb1[tid] - bnm1[tid]) * s + bnb1[tid];
    }
    // wt2[(ci*5+t)*64+co] = cw2[(co*32+ci)*5+t] * s2[co]
    for (int i = tid; i < 10240; i += 256) {
        int co = i & 63, r = i >> 6, t = r % 5, ci = r / 5;
        float s = bng2[co] * rsqrtf(bnv2[co] + 1e-5f);
        wt2[i] = cw2[(co * 32 + ci) * 5 + t] * s;
    }
    if (tid < 64) {
        float s = bng2[tid] * rsqrtf(bnv2[tid] + 1e-5f);
        b2[tid] = (cb2[tid] - bnm2[tid]) * s + bnb2[tid];
    }
    if (tid < 80) {
        int co = tid / 5;
        float s = bng0[co] * rsqrtf(bnv0[co] + 1e-5f);
        w0f[tid] = cw0[tid] * s;
    }
    if (tid < 16) {
        float s = bng0[tid] * rsqrtf(bnv0[tid] + 1e-5f);
        b0f[tid] = (cb0[tid] - bnm0[tid]) * s + bnb0[tid];
    }
}

// ---------------- fused conv0 + conv1: x (B,1,15360) -> (B,32,3840)
__global__ __launch_bounds__(256) void conv01_kernel(
    const float* __restrict__ x, const float* __restrict__ wt1,
    const float* __restrict__ b1, const float* __restrict__ w0f,
    const float* __restrict__ b0f, float* __restrict__ out)
{
    __shared__ float raw[528];
    __shared__ float xt0[16][260];
    __shared__ float w0l[80];
    __shared__ float b0l[16];
    int b = blockIdx.y, tid = threadIdx.x;
    int j0 = blockIdx.x * 128;
    const float* xb = x + (size_t)b * 15360;
    for (int p = tid; p < 524; p += 256) {
        int g = 4 * j0 - 6 + p;
        raw[p] = (g >= 0 && g < 15360) ? xb[g] : 0.f;
    }
    if (tid < 80) w0l[tid] = w0f[tid];
    if (tid < 16) b0l[tid] = b0f[tid];
    __syncthreads();
    // conv0 stage: ci0 = tid>>4 (all 256 threads active), weights register-resident
    {
        int ci0 = tid >> 4, sub = tid & 15;
        float w0 = w0l[ci0 * 5 + 0], w1 = w0l[ci0 * 5 + 1], w2 = w0l[ci0 * 5 + 2],
              w3 = w0l[ci0 * 5 + 3], w4 = w0l[ci0 * 5 + 4];
        float bb = b0l[ci0];
        for (int p = sub; p < 260; p += 16) {
            int q = 2 * j0 - 2 + p;
            float v = 0.f;
            if (q >= 0 && q < 7680) {
                float r0 = raw[2*p], r1 = raw[2*p+1], r2 = raw[2*p+2],
                      r3 = raw[2*p+3], r4 = raw[2*p+4], r5 = raw[2*p+5];
                float s0 = fmaf(w0, r0, fmaf(w1, r1, fmaf(w2, r2, fmaf(w3, r3, w4 * r4))));
                float s1 = fmaf(w0, r1, fmaf(w1, r2, fmaf(w2, r3, fmaf(w3, r4, w4 * r5))));
                v = fmaxf(fmaxf(s0, s1) + bb, 0.f);
            }
            xt0[ci0][p] = v;
        }
    }
    __syncthreads();
    int cg = tid >> 7, jj = tid & 127;
    int cgu = __builtin_amdgcn_readfirstlane(cg);
    const float* wb = wt1 + cgu * 16;
    v2f a0[8], a1[8];
#pragma unroll
    for (int q = 0; q < 8; ++q) { a0[q] = (v2f){0.f, 0.f}; a1[q] = (v2f){0.f, 0.f}; }
#pragma unroll 4
    for (int ci = 0; ci < 16; ++ci) {
        const float2* xr = reinterpret_cast<const float2*>(&xt0[ci][0]);
        float2 xA = xr[jj], xB = xr[jj + 1], xC = xr[jj + 2];
        float xv[6] = { xA.x, xA.y, xB.x, xB.y, xC.x, xC.y };
#pragma unroll
        for (int t = 0; t < 5; ++t) {
            const v2f* wp2 = reinterpret_cast<const v2f*>(wb + (ci * 5 + t) * 32);
            v2f va = { xv[t], xv[t] };
            v2f vc = { xv[t + 1], xv[t + 1] };
#pragma unroll
            for (int q2 = 0; q2 < 8; ++q2) {
                v2f w = wp2[q2];
                a0[q2] = __builtin_elementwise_fma(w, va, a0[q2]);
                a1[q2] = __builtin_elementwise_fma(w, vc, a1[q2]);
            }
        }
    }
    int j = j0 + jj;
    size_t obase = ((size_t)b * 32 + cgu * 16) * 3840 + j;
#pragma unroll
    for (int q2 = 0; q2 < 8; ++q2) {
#pragma unroll
        for (int cpp = 0; cpp < 2; ++cpp) {
            int q = 2 * q2 + cpp;
            float vb = b1[cgu * 16 + q];
            float m = fmaxf(a0[q2][cpp], a1[q2][cpp]) + vb;
            out[obase + (size_t)q * 3840] = fmaxf(m, 0.f);
        }
    }
}

// ---------------- fused conv2 + adaptive avgpool: (B,32,3840) -> xseq (B,64,64)
__global__ __launch_bounds__(256) void conv2p_kernel(
    const float* __restrict__ in, const float* __restrict__ wt2,
    const float* __restrict__ b2, float* __restrict__ xs)
{
    __shared__ float xt[32 * 132];   // rows padded to 132
    int b = blockIdx.y, tid = threadIdx.x;
    int j0 = blockIdx.x * 60;
    // staging: div/mod-free mapping, ci = tid>>3, p strides by 8
    {
        int ci = tid >> 3, lane8 = tid & 7;
        const float* src = in + ((size_t)b * 32 + ci) * 3840;
        for (int p = lane8; p < 132; p += 8) {
            int gp = 2 * j0 - 2 + p;
            xt[ci * 132 + p] = (gp >= 0 && gp < 3840) ? src[gp] : 0.f;
        }
    }
    __syncthreads();
    int cg = tid >> 6, jj = tid & 63;     // 4 groups x 64 lanes (jj<60 active)
    int cgu = __builtin_amdgcn_readfirstlane(cg);
    const float* wb = wt2 + cgu * 16;
    v2f a0[8], a1[8];
#pragma unroll
    for (int q = 0; q < 8; ++q) { a0[q] = (v2f){0.f, 0.f}; a1[q] = (v2f){0.f, 0.f}; }
#pragma unroll 4
    for (int ci = 0; ci < 32; ++ci) {
        const float2* xr = reinterpret_cast<const float2*>(xt + ci * 132);
        float2 xA = xr[jj], xB = xr[jj + 1], xC = xr[jj + 2];
        float xv[6] = { xA.x, xA.y, xB.x, xB.y, xC.x, xC.y };
#pragma unroll
        for (int t = 0; t < 5; ++t) {
            const v2f* wp2 = reinterpret_cast<const v2f*>(wb + (ci * 5 + t) * 64);
            v2f va = { xv[t], xv[t] };
            v2f vc = { xv[t + 1], xv[t + 1] };
#pragma unroll
            for (int q2 = 0; q2 < 8; ++q2) {
                v2f w = wp2[q2];
                a0[q2] = __builtin_elementwise_fma(w, va, a0[q2]);
                a1[q2] = __builtin_elementwise_fma(w, vc, a1[q2]);
            }
        }
    }
    __syncthreads();
    float* outt = xt;                 // reuse: [64 co][stride 61] = 3904 <= 4224
    if (jj < 60) {
#pragma unroll
        for (int q2 = 0; q2 < 8; ++q2) {
#pragma unroll
            for (int cpp = 0; cpp < 2; ++cpp) {
                int q = 2 * q2 + cpp;
                int co = cgu * 16 + q;
                float m = fmaxf(a0[q2][cpp], a1[q2][cpp]) + b2[co];
                outt[co * 61 + jj] = fmaxf(m, 0.f);
            }
        }
    }
    __syncthreads();
    if (tid < 128) {
        int co = tid & 63, bin = tid >> 6;
        const float* r = outt + co * 61 + bin * 30;
        float s = 0.f;
#pragma unroll
        for (int k = 0; k < 30; ++k) s += r[k];
        xs[((size_t)b * 64 + (blockIdx.x * 2 + bin)) * 64 + co] = s * (1.f / 30.f);
    }
}

// ---------------- LSTM: 2 layers fused, one block per batch element.
__global__ __launch_bounds__(256) void lstm_kernel(
    const float* __restrict__ xseq,
    const float* __restrict__ wih0, const float* __restrict__ whh0,
    const float* __restrict__ bih0, const float* __restrict__ bhh0,
    const float* __restrict__ wih1, const float* __restrict__ whh1,
    const float* __restrict__ bih1, const float* __restrict__ bhh1,
    float* __restrict__ hseq)
{
    __shared__ float xb[64][64];
    __shared__ float xg[64][256];
    __shared__ float gb4[4][64];
    __shared__ float hb[64];
    int b = blockIdx.x;
    int tid = threadIdx.x;
    int wv = tid >> 6, ln = tid & 63;
    for (int i = tid; i < 4096; i += 256) xb[i >> 6][i & 63] = xseq[(size_t)b * 4096 + i];
    __syncthreads();
    float wr[64];
    for (int layer = 0; layer < 2; ++layer) {
        const float* wih = layer ? wih1 : wih0;
        const float* whh = layer ? whh1 : whh0;
        float bias = layer ? (bih1[tid] + bhh1[tid]) : (bih0[tid] + bhh0[tid]);
#pragma unroll
        for (int k4 = 0; k4 < 16; ++k4) {
            float4 v = reinterpret_cast<const float4*>(wih + (size_t)tid * 64)[k4];
            wr[k4 * 4 + 0] = v.x; wr[k4 * 4 + 1] = v.y;
            wr[k4 * 4 + 2] = v.z; wr[k4 * 4 + 3] = v.w;
        }
        for (int t = 0; t < 64; ++t) {
            float s0 = bias, s1 = 0.f, s2 = 0.f, s3 = 0.f;
#pragma unroll
            for (int k = 0; k < 64; k += 4) {
                s0 = fmaf(wr[k + 0], xb[t][k + 0], s0);
                s1 = fmaf(wr[k + 1], xb[t][k + 1], s1);
                s2 = fmaf(wr[k + 2], xb[t][k + 2], s2);
                s3 = fmaf(wr[k + 3], xb[t][k + 3], s3);
            }
            xg[t][tid] = (s0 + s1) + (s2 + s3);
        }
#pragma unroll
        for (int k4 = 0; k4 < 16; ++k4) {
            float4 v = reinterpret_cast<const float4*>(whh + (size_t)tid * 64)[k4];
            wr[k4 * 4 + 0] = v.x; wr[k4 * 4 + 1] = v.y;
            wr[k4 * 4 + 2] = v.z; wr[k4 * 4 + 3] = v.w;
        }
        if (tid < 64) hb[tid] = 0.f;
        float c = 0.f;
        __syncthreads();
        for (int t = 0; t < 64; ++t) {
            float s0 = xg[t][tid], s1 = 0.f, s2 = 0.f, s3 = 0.f;
#pragma unroll
            for (int k = 0; k < 64; k += 4) {
                s0 = fmaf(wr[k + 0], hb[k + 0], s0);
                s1 = fmaf(wr[k + 1], hb[k + 1], s1);
                s2 = fmaf(wr[k + 2], hb[k + 2], s2);
                s3 = fmaf(wr[k + 3], hb[k + 3], s3);
            }
            float acc = (s0 + s1) + (s2 + s3);
            float a;
            if (wv == 2) a = tanhf(acc);
            else         a = 1.f / (1.f + __expf(-acc));
            gb4[wv][ln] = a;
            __syncthreads();
            float gi = gb4[0][ln], gf = gb4[1][ln], gg = gb4[2][ln], go = gb4[3][ln];
            c = fmaf(gf, c, gi * gg);
            float h = go * tanhf(c);
            if (wv == 0) {
                hb[ln] = h;
                if (layer == 0) xb[t][ln] = h;
                else hseq[((size_t)b * 64 + t) * 64 + ln] = h;
            }
            __syncthreads();
        }
    }
}

// ---------------- graph: correlation + kthvalue(192) + adjacency + 3x GCN + classifier
__global__ __launch_bounds__(256) void graph_kernel(
    const float* __restrict__ hseq,
    const float* __restrict__ gw0, const float* __restrict__ gb0,
    const float* __restrict__ gw1, const float* __restrict__ gb1,
    const float* __restrict__ gw2, const float* __restrict__ gb2,
    const float* __restrict__ clw, const float* __restrict__ clb,
    float* __restrict__ out)
{
    __shared__ float nf[16][257];
    __shared__ float sb[16][257];
    __shared__ float red[16][17];
    __shared__ float mean[16], rstd[16];
    __shared__ float C[256];
    __shared__ float adj[16][16];
    __shared__ float thrv;
    __shared__ float bufA[16][65], bufB[16][65], bufC[16][65];
    __shared__ float emb[64];
    int b = blockIdx.x, tid = threadIdx.x;
    for (int i = tid; i < 4096; i += 256) nf[i >> 8][i & 255] = hseq[(size_t)b * 4096 + i];
    __syncthreads();
    int nd = tid >> 4, sub = tid & 15;
    {
        float s = 0.f;
        for (int f = sub; f < 256; f += 16) s += nf[nd][f];
        red[nd][sub] = s;
    }
    __syncthreads();
    if (tid < 16) {
        float m = 0.f;
        for (int i = 0; i < 16; ++i) m += red[tid][i];
        mean[tid] = m * (1.f / 256.f);
    }
    __syncthreads();
    {
        float mu = mean[nd];
        float ss = 0.f;
        for (int f = sub; f < 256; f += 16) { float d = nf[nd][f] - mu; ss = fmaf(d, d, ss); }
        red[nd][sub] = ss;
    }
    __syncthreads();
    if (tid < 16) {
        float m = 0.f;
        for (int i = 0; i < 16; ++i) m += red[tid][i];
        rstd[tid] = 1.f / (sqrtf(m * (1.f / 255.f)) + 1e-8f);
    }
    __syncthreads();
    for (int i = tid; i < 4096; i += 256) {
        int n = i >> 8, f = i & 255;
        sb[n][f] = (nf[n][f] - mean[n]) * rstd[n];
    }
    __syncthreads();
    {
        int n = tid >> 4, m = tid & 15;
        float a0 = 0, a1 = 0, a2 = 0, a3 = 0;
        for (int f = 0; f < 256; f += 4) {
            a0 = fmaf(sb[n][f + 0], sb[m][f + 0], a0);
            a1 = fmaf(sb[n][f + 1], sb[m][f + 1], a1);
            a2 = fmaf(sb[n][f + 2], sb[m][f + 2], a2);
            a3 = fmaf(sb[n][f + 3], sb[m][f + 3], a3);
        }
        C[tid] = ((a0 + a1) + (a2 + a3)) * (1.f / 256.f);
    }
    __syncthreads();
    {
        float v = C[tid];
        int cnt = 0, eq = 0;
        for (int j2 = 0; j2 < 256; ++j2) {
            float vj = C[j2];
            cnt += (vj < v);
            eq  += (vj == v);
        }
        if (cnt <= 191 && 191 < cnt + eq) thrv = v;
    }
    __syncthreads();
    {
        int n = tid >> 4, m = tid & 15;
        adj[n][m] = (C[tid] > thrv && n != m) ? 1.f : 0.f;
    }
    __syncthreads();
    for (int i = tid; i < 4096; i += 256) {
        int n = i >> 8, f = i & 255;
        float acc = nf[n][f];
#pragma unroll
        for (int m = 0; m < 16; ++m) acc = fmaf(adj[n][m], nf[m][f], acc);
        sb[n][f] = acc;
    }
    __syncthreads();
    for (int i = tid; i < 1024; i += 256) {
        int n = i >> 6, o = i & 63;
        const float4* wr4 = reinterpret_cast<const float4*>(gw0 + (size_t)o * 256);
        float acc = gb0[o];
        for (int f4 = 0; f4 < 64; ++f4) {
            float4 wv = wr4[f4];
            int f = f4 * 4;
            acc = fmaf(sb[n][f + 0], wv.x, acc);
            acc = fmaf(sb[n][f + 1], wv.y, acc);
            acc = fmaf(sb[n][f + 2], wv.z, acc);
            acc = fmaf(sb[n][f + 3], wv.w, acc);
        }
        bufA[n][o] = fmaxf(acc, 0.f);
    }
    __syncthreads();
    for (int i = tid; i < 1024; i += 256) {
        int n = i >> 6, f = i & 63;
        float acc = bufA[n][f];
#pragma unroll
        for (int m = 0; m < 16; ++m) acc = fmaf(adj[n][m], bufA[m][f], acc);
        bufB[n][f] = acc;
    }
    __syncthreads();
    for (int i = tid; i < 1024; i += 256) {
        int n = i >> 6, o = i & 63;
        const float4* wr4 = reinterpret_cast<const float4*>(gw1 + (size_t)o * 64);
        float acc = gb1[o];
        for (int f4 = 0; f4 < 16; ++f4) {
            float4 wv = wr4[f4];
            int f = f4 * 4;
            acc = fmaf(bufB[n][f + 0], wv.x, acc);
            acc = fmaf(bufB[n][f + 1], wv.y, acc);
            acc = fmaf(bufB[n][f + 2], wv.z, acc);
            acc = fmaf(bufB[n][f + 3], wv.w, acc);
        }
        bufC[n][o] = fmaxf(acc, 0.f);
    }
    __syncthreads();
    for (int i = tid; i < 1024; i += 256) {
        int n = i >> 6, f = i & 63;
        float acc = bufC[n][f];
#pragma unroll
        for (int m = 0; m < 16; ++m) acc = fmaf(adj[n][m], bufC[m][f], acc);
        bufA[n][f] = acc;
    }
    __syncthreads();
    for (int i = tid; i < 1024; i += 256) {
        int n = i >> 6, o = i & 63;
        const float4* wr4 = reinterpret_cast<const float4*>(gw2 + (size_t)o * 64);
        float acc = gb2[o];
        for (int f4 = 0; f4 < 16; ++f4) {
            float4 wv = wr4[f4];
            int f = f4 * 4;
            acc = fmaf(bufA[n][f + 0], wv.x, acc);
            acc = fmaf(bufA[n][f + 1], wv.y, acc);
            acc = fmaf(bufA[n][f + 2], wv.z, acc);
            acc = fmaf(bufA[n][f + 3], wv.w, acc);
        }
        bufB[n][o] = fmaxf(acc, 0.f);
    }
    __syncthreads();
    if (tid < 64) {
        float mx = bufB[0][tid];
#pragma unroll
        for (int n = 1; n < 16; ++n) mx = fmaxf(mx, bufB[n][tid]);
        emb[tid] = mx;
    }
    __syncthreads();
    if (tid < 5) {
        float acc = clb[tid];
#pragma unroll
        for (int o = 0; o < 64; ++o) acc = fmaf(emb[o], clw[tid * 64 + o], acc);
        out[(size_t)b * 5 + tid] = acc;
    }
}

extern "C" void kernel_launch(void* const* d_in, const int* in_sizes, int n_in,
                              void* d_out, int out_size, void* d_ws, size_t ws_size,
                              hipStream_t stream)
{
    const float* x    = (const float*)d_in[0];
    const float* cw0  = (const float*)d_in[1];
    const float* cb0  = (const float*)d_in[2];
    const float* bng0 = (const float*)d_in[3];
    const float* bnb0 = (const float*)d_in[4];
    const float* bnm0 = (const float*)d_in[5];
    const float* bnv0 = (const float*)d_in[6];
    const float* cw1  = (const float*)d_in[7];
    const float* cb1  = (const float*)d_in[8];
    const float* bng1 = (const float*)d_in[9];
    const float* bnb1 = (const float*)d_in[10];
    const float* bnm1 = (const float*)d_in[11];
    const float* bnv1 = (const float*)d_in[12];
    const float* cw2  = (const float*)d_in[13];
    const float* cb2  = (const float*)d_in[14];
    const float* bng2 = (const float*)d_in[15];
    const float* bnb2 = (const float*)d_in[16];
    const float* bnm2 = (const float*)d_in[17];
    const float* bnv2 = (const float*)d_in[18];
    const float* wih0 = (const float*)d_in[19];
    const float* whh0 = (const float*)d_in[20];
    const float* bih0 = (const float*)d_in[21];
    const float* bhh0 = (const float*)d_in[22];
    const float* wih1 = (const float*)d_in[23];
    const float* whh1 = (const float*)d_in[24];
    const float* bih1 = (const float*)d_in[25];
    const float* bhh1 = (const float*)d_in[26];
    const float* gw0  = (const float*)d_in[27];
    const float* gb0  = (const float*)d_in[28];
    const float* gw1  = (const float*)d_in[29];
    const float* gb1  = (const float*)d_in[30];
    const float* gw2  = (const float*)d_in[31];
    const float* gb2  = (const float*)d_in[32];
    const float* clw  = (const float*)d_in[33];
    const float* clb  = (const float*)d_in[34];

    // ws layout (floats)
    float* f0  = (float*)d_ws;            // conv1 out: 256*32*3840 = 31457280
    float* xs  = f0 + 31457280;           // (B,64,64)
    float* hs  = xs + 1048576;            // (B,64,64)
    float* wt1 = hs + 1048576;            // 2560
    float* b1  = wt1 + 2560;              // 32
    float* wt2 = b1 + 32;                 // 10240
    float* b2  = wt2 + 10240;             // 64
    float* w0f = b2 + 64;                 // 80
    float* b0f = w0f + 80;                // 16

    prep_weights_kernel<<<1, 256, 0, stream>>>(
        cw0, cb0, bng0, bnb0, bnm0, bnv0,
        cw1, cb1, bng1, bnb1, bnm1, bnv1,
        cw2, cb2, bng2, bnb2, bnm2, bnv2,
        wt1, b1, wt2, b2, w0f, b0f);
    conv01_kernel<<<dim3(30, 256), 256, 0, stream>>>(x, wt1, b1, w0f, b0f, f0);
    conv2p_kernel<<<dim3(32, 256), 256, 0, stream>>>(f0, wt2, b2, xs);
    lstm_kernel<<<256, 256, 0, stream>>>(xs, wih0, whh0, bih0, bhh0,
                                         wih1, whh1, bih1, bhh1, hs);
    graph_kernel<<<256, 256, 0, stream>>>(hs, gw0, gb0, gw1, gb1, gw2, gb2,
                                          clw, clb, (float*)d_out);
}

// Round 8
// 477.976 us; speedup vs baseline: 1.4873x; 1.0108x over previous
//
#include <hip/hip_runtime.h>
#include <math.h>

typedef __attribute__((ext_vector_type(2))) float v2f;

// ---------------- prep: transpose + BN-fold conv weights into [ci][t][co] layout
__global__ __launch_bounds__(256) void prep_weights_kernel(
    const float* __restrict__ cw0, const float* __restrict__ cb0,
    const float* __restrict__ bng0, const float* __restrict__ bnb0,
    const float* __restrict__ bnm0, const float* __restrict__ bnv0,
    const float* __restrict__ cw1, const float* __restrict__ cb1,
    const float* __restrict__ bng1, const float* __restrict__ bnb1,
    const float* __restrict__ bnm1, const float* __restrict__ bnv1,
    const float* __restrict__ cw2, const float* __restrict__ cb2,
    const float* __restrict__ bng2, const float* __restrict__ bnb2,
    const float* __restrict__ bnm2, const float* __restrict__ bnv2,
    float* __restrict__ wt1, float* __restrict__ b1,
    float* __restrict__ wt2, float* __restrict__ b2,
    float* __restrict__ w0f, float* __restrict__ b0f)
{
    int tid = threadIdx.x;
    // wt1[(ci*5+t)*32+co] = cw1[(co*16+ci)*5+t] * s1[co]
    for (int i = tid; i < 2560; i += 256) {
        int co = i & 31, r = i >> 5, t = r % 5, ci = r / 5;
        float s = bng1[co] * rsqrtf(bnv1[co] + 1e-5f);
        wt1[i] = cw1[(co * 16 + ci) * 5 + t] * s;
    }
    if (tid < 32) {
        float s = bng1[tid] * rsqrtf(bnv1[tid] + 1e-5f);
        b1[tid] = (cb1[tid] - bnm1[tid]) * s + bnb1[tid];
    }
    // wt2[(ci*5+t)*64+co] = cw2[(co*32+ci)*5+t] * s2[co]
    for (int i = tid; i < 10240; i += 256) {
        int co = i & 63, r = i >> 6, t = r % 5, ci = r / 5;
        float s = bng2[co] * rsqrtf(bnv2[co] + 1e-5f);
        wt2[i] = cw2[(co * 32 + ci) * 5 + t] * s;
    }
    if (tid < 64) {
        float s = bng2[tid] * rsqrtf(bnv2[tid] + 1e-5f);
        b2[tid] = (cb2[tid] - bnm2[tid]) * s + bnb2[tid];
    }
    if (tid < 80) {
        int co = tid / 5;
        float s = bng0[co] * rsqrtf(bnv0[co] + 1e-5f);
        w0f[tid] = cw0[tid] * s;
    }
    if (tid < 16) {
        float s = bng0[tid] * rsqrtf(bnv0[tid] + 1e-5f);
        b0f[tid] = (cb0[tid] - bnm0[tid]) * s + bnb0[tid];
    }
}

// ---------------- fully fused CNN: x (B,1,15360) -> xs (B,64,64)
// One block = (batch b) x (60 conv2-pooled outputs = 2 avgpool bins).
// All intermediate tiles live in LDS; accumulation chains keep the exact
// (ci,t) order of the previous split kernels -> bit-identical results.
__global__ __launch_bounds__(256) void convall_kernel(
    const float* __restrict__ x,
    const float* __restrict__ w0f, const float* __restrict__ b0f,
    const float* __restrict__ wt1, const float* __restrict__ b1,
    const float* __restrict__ wt2, const float* __restrict__ b2,
    float* __restrict__ xs)
{
    __shared__ float raw[512];     // raw x window [480bx-14, 480bx+493]
    __shared__ float U[8320];      // xt0: [0,4096) stride 256 | xt1: [4096,8320) stride 132 | Y reuse: [0,3904) stride 61
    int b = blockIdx.y, bx = blockIdx.x, tid = threadIdx.x;
    const float* xb = x + (size_t)b * 15360;
    {
        int base = 480 * bx - 14;
        for (int i = tid; i < 508; i += 256) {
            int g = base + i;
            raw[i] = (g >= 0 && g < 15360) ? xb[g] : 0.f;
        }
    }
    __syncthreads();
    // ---- conv0 (+BN+ReLU+maxpool2): 252 pooled values per ci0, global r = 240bx-6+p
    {
        int ci0 = tid >> 4, sub = tid & 15;
        float w0 = w0f[ci0*5+0], w1 = w0f[ci0*5+1], w2 = w0f[ci0*5+2],
              w3 = w0f[ci0*5+3], w4 = w0f[ci0*5+4];
        float bb = b0f[ci0];
        int r0g = 240 * bx - 6;
        for (int p = sub; p < 252; p += 16) {
            int r = r0g + p;
            float v = 0.f;
            if (r >= 0 && r < 7680) {
                int i0 = 2 * p;
                float c0 = raw[i0],   c1 = raw[i0+1], c2 = raw[i0+2],
                      c3 = raw[i0+3], c4 = raw[i0+4], c5 = raw[i0+5];
                float s0 = fmaf(w0,c0, fmaf(w1,c1, fmaf(w2,c2, fmaf(w3,c3, w4*c4))));
                float s1 = fmaf(w0,c1, fmaf(w1,c2, fmaf(w2,c3, fmaf(w3,c4, w4*c5))));
                v = fmaxf(fmaxf(s0, s1) + bb, 0.f);
            }
            U[ci0 * 256 + p] = v;
        }
    }
    __syncthreads();
    // ---- conv1 (+BN+ReLU+maxpool2): 124 pooled values per co, global q = 120bx-2+jj
    {
        int cg = tid >> 7, jj = tid & 127;
        int cgu = __builtin_amdgcn_readfirstlane(cg);
        // deterministic zero-fill of xt1 tail cols [124,132)
        { int co = tid >> 3, c = 124 + (tid & 7); U[4096 + co * 132 + c] = 0.f; }
        if (jj < 124) {
            const float* wb = wt1 + cgu * 16;
            v2f a0[8], a1[8];
#pragma unroll
            for (int q = 0; q < 8; ++q) { a0[q] = (v2f){0.f,0.f}; a1[q] = (v2f){0.f,0.f}; }
#pragma unroll 4
            for (int ci = 0; ci < 16; ++ci) {
                const float2* xr = reinterpret_cast<const float2*>(&U[ci * 256]);
                float2 xA = xr[jj], xB = xr[jj + 1], xC = xr[jj + 2];
                float xv[6] = { xA.x, xA.y, xB.x, xB.y, xC.x, xC.y };
#pragma unroll
                for (int t = 0; t < 5; ++t) {
                    const v2f* wp2 = reinterpret_cast<const v2f*>(wb + (ci * 5 + t) * 32);
                    v2f va = { xv[t], xv[t] };
                    v2f vc = { xv[t + 1], xv[t + 1] };
#pragma unroll
                    for (int q2 = 0; q2 < 8; ++q2) {
                        v2f w = wp2[q2];
                        a0[q2] = __builtin_elementwise_fma(w, va, a0[q2]);
                        a1[q2] = __builtin_elementwise_fma(w, vc, a1[q2]);
                    }
                }
            }
            int q = 120 * bx - 2 + jj;
            bool ok = (q >= 0 && q < 3840);
#pragma unroll
            for (int q2 = 0; q2 < 8; ++q2) {
#pragma unroll
                for (int cpp = 0; cpp < 2; ++cpp) {
                    int qq = 2 * q2 + cpp;
                    int co = cgu * 16 + qq;
                    float val = 0.f;
                    if (ok) val = fmaxf(fmaxf(a0[q2][cpp], a1[q2][cpp]) + b1[co], 0.f);
                    U[4096 + co * 132 + jj] = val;
                }
            }
        }
    }
    __syncthreads();
    // ---- conv2 (+BN+ReLU+maxpool2) + avgpool epilogue
    {
        int cg = tid >> 6, jj = tid & 63;
        int cgu = __builtin_amdgcn_readfirstlane(cg);
        const float* wb = wt2 + cgu * 16;
        v2f a0[8], a1[8];
#pragma unroll
        for (int q = 0; q < 8; ++q) { a0[q] = (v2f){0.f,0.f}; a1[q] = (v2f){0.f,0.f}; }
#pragma unroll 4
        for (int ci = 0; ci < 32; ++ci) {
            const float2* xr = reinterpret_cast<const float2*>(&U[4096 + ci * 132]);
            float2 xA = xr[jj], xB = xr[jj + 1], xC = xr[jj + 2];
            float xv[6] = { xA.x, xA.y, xB.x, xB.y, xC.x, xC.y };
#pragma unroll
            for (int t = 0; t < 5; ++t) {
                const v2f* wp2 = reinterpret_cast<const v2f*>(wb + (ci * 5 + t) * 64);
                v2f va = { xv[t], xv[t] };
                v2f vc = { xv[t + 1], xv[t + 1] };
#pragma unroll
                for (int q2 = 0; q2 < 8; ++q2) {
                    v2f w = wp2[q2];
                    a0[q2] = __builtin_elementwise_fma(w, va, a0[q2]);
                    a1[q2] = __builtin_elementwise_fma(w, vc, a1[q2]);
                }
            }
        }
        __syncthreads();     // xt0/xt1 dead; U becomes Y[64 co][stride 61]
        if (jj < 60) {
#pragma unroll
            for (int q2 = 0; q2 < 8; ++q2) {
#pragma unroll
                for (int cpp = 0; cpp < 2; ++cpp) {
                    int qq = 2 * q2 + cpp;
                    int co = cgu * 16 + qq;
                    float m = fmaxf(a0[q2][cpp], a1[q2][cpp]) + b2[co];
                    U[co * 61 + jj] = fmaxf(m, 0.f);
                }
            }
        }
    }
    __syncthreads();
    if (tid < 128) {
        int co = tid & 63, bin = tid >> 6;
        const float* r = U + co * 61 + bin * 30;
        float s = 0.f;
#pragma unroll
        for (int k = 0; k < 30; ++k) s += r[k];
        xs[((size_t)b * 64 + (bx * 2 + bin)) * 64 + co] = s * (1.f / 30.f);
    }
}

// ---------------- LSTM: 2 layers fused, one block per batch element.
// LDS reads on the serial path vectorized to float4 (bit-exact chain order).
__global__ __launch_bounds__(256) void lstm_kernel(
    const float* __restrict__ xseq,
    const float* __restrict__ wih0, const float* __restrict__ whh0,
    const float* __restrict__ bih0, const float* __restrict__ bhh0,
    const float* __restrict__ wih1, const float* __restrict__ whh1,
    const float* __restrict__ bih1, const float* __restrict__ bhh1,
    float* __restrict__ hseq)
{
    __shared__ float xb[64][64];
    __shared__ float xg[64][256];
    __shared__ float gb4[4][64];
    __shared__ float hb[64];
    int b = blockIdx.x;
    int tid = threadIdx.x;
    int wv = tid >> 6, ln = tid & 63;
    for (int i = tid; i < 4096; i += 256) xb[i >> 6][i & 63] = xseq[(size_t)b * 4096 + i];
    __syncthreads();
    float wr[64];
    for (int layer = 0; layer < 2; ++layer) {
        const float* wih = layer ? wih1 : wih0;
        const float* whh = layer ? whh1 : whh0;
        float bias = layer ? (bih1[tid] + bhh1[tid]) : (bih0[tid] + bhh0[tid]);
#pragma unroll
        for (int k4 = 0; k4 < 16; ++k4) {
            float4 v = reinterpret_cast<const float4*>(wih + (size_t)tid * 64)[k4];
            wr[k4 * 4 + 0] = v.x; wr[k4 * 4 + 1] = v.y;
            wr[k4 * 4 + 2] = v.z; wr[k4 * 4 + 3] = v.w;
        }
        for (int t = 0; t < 64; ++t) {
            float s0 = bias, s1 = 0.f, s2 = 0.f, s3 = 0.f;
#pragma unroll
            for (int k4 = 0; k4 < 16; ++k4) {
                float4 xv4 = *reinterpret_cast<const float4*>(&xb[t][k4 * 4]);
                s0 = fmaf(wr[k4 * 4 + 0], xv4.x, s0);
                s1 = fmaf(wr[k4 * 4 + 1], xv4.y, s1);
                s2 = fmaf(wr[k4 * 4 + 2], xv4.z, s2);
                s3 = fmaf(wr[k4 * 4 + 3], xv4.w, s3);
            }
            xg[t][tid] = (s0 + s1) + (s2 + s3);
        }
#pragma unroll
        for (int k4 = 0; k4 < 16; ++k4) {
            float4 v = reinterpret_cast<const float4*>(whh + (size_t)tid * 64)[k4];
            wr[k4 * 4 + 0] = v.x; wr[k4 * 4 + 1] = v.y;
            wr[k4 * 4 + 2] = v.z; wr[k4 * 4 + 3] = v.w;
        }
        if (tid < 64) hb[tid] = 0.f;
        float c = 0.f;
        __syncthreads();
        for (int t = 0; t < 64; ++t) {
            float s0 = xg[t][tid], s1 = 0.f, s2 = 0.f, s3 = 0.f;
#pragma unroll
            for (int k4 = 0; k4 < 16; ++k4) {
                float4 hv4 = *reinterpret_cast<const float4*>(&hb[k4 * 4]);
                s0 = fmaf(wr[k4 * 4 + 0], hv4.x, s0);
                s1 = fmaf(wr[k4 * 4 + 1], hv4.y, s1);
                s2 = fmaf(wr[k4 * 4 + 2], hv4.z, s2);
                s3 = fmaf(wr[k4 * 4 + 3], hv4.w, s3);
            }
            float acc = (s0 + s1) + (s2 + s3);
            float a;
            if (wv == 2) a = tanhf(acc);
            else         a = 1.f / (1.f + __expf(-acc));
            gb4[wv][ln] = a;
            __syncthreads();
            float gi = gb4[0][ln], gf = gb4[1][ln], gg = gb4[2][ln], go = gb4[3][ln];
            c = fmaf(gf, c, gi * gg);
            float h = go * tanhf(c);
            if (wv == 0) {
                hb[ln] = h;
                if (layer == 0) xb[t][ln] = h;
                else hseq[((size_t)b * 64 + t) * 64 + ln] = h;
            }
            __syncthreads();
        }
    }
}

// ---------------- graph: correlation + kthvalue(192) + adjacency + 3x GCN + classifier
__global__ __launch_bounds__(256) void graph_kernel(
    const float* __restrict__ hseq,
    const float* __restrict__ gw0, const float* __restrict__ gb0,
    const float* __restrict__ gw1, const float* __restrict__ gb1,
    const float* __restrict__ gw2, const float* __restrict__ gb2,
    const float* __restrict__ clw, const float* __restrict__ clb,
    float* __restrict__ out)
{
    __shared__ float nf[16][257];
    __shared__ float sb[16][257];
    __shared__ float red[16][17];
    __shared__ float mean[16], rstd[16];
    __shared__ float C[256];
    __shared__ float adj[16][16];
    __shared__ float thrv;
    __shared__ float bufA[16][65], bufB[16][65], bufC[16][65];
    __shared__ float emb[64];
    int b = blockIdx.x, tid = threadIdx.x;
    for (int i = tid; i < 4096; i += 256) nf[i >> 8][i & 255] = hseq[(size_t)b * 4096 + i];
    __syncthreads();
    int nd = tid >> 4, sub = tid & 15;
    {
        float s = 0.f;
        for (int f = sub; f < 256; f += 16) s += nf[nd][f];
        red[nd][sub] = s;
    }
    __syncthreads();
    if (tid < 16) {
        float m = 0.f;
        for (int i = 0; i < 16; ++i) m += red[tid][i];
        mean[tid] = m * (1.f / 256.f);
    }
    __syncthreads();
    {
        float mu = mean[nd];
        float ss = 0.f;
        for (int f = sub; f < 256; f += 16) { float d = nf[nd][f] - mu; ss = fmaf(d, d, ss); }
        red[nd][sub] = ss;
    }
    __syncthreads();
    if (tid < 16) {
        float m = 0.f;
        for (int i = 0; i < 16; ++i) m += red[tid][i];
        rstd[tid] = 1.f / (sqrtf(m * (1.f / 255.f)) + 1e-8f);
    }
    __syncthreads();
    for (int i = tid; i < 4096; i += 256) {
        int n = i >> 8, f = i & 255;
        sb[n][f] = (nf[n][f] - mean[n]) * rstd[n];
    }
    __syncthreads();
    {
        int n = tid >> 4, m = tid & 15;
        float a0 = 0, a1 = 0, a2 = 0, a3 = 0;
        for (int f = 0; f < 256; f += 4) {
            a0 = fmaf(sb[n][f + 0], sb[m][f + 0], a0);
            a1 = fmaf(sb[n][f + 1], sb[m][f + 1], a1);
            a2 = fmaf(sb[n][f + 2], sb[m][f + 2], a2);
            a3 = fmaf(sb[n][f + 3], sb[m][f + 3], a3);
        }
        C[tid] = ((a0 + a1) + (a2 + a3)) * (1.f / 256.f);
    }
    __syncthreads();
    {
        float v = C[tid];
        int cnt = 0, eq = 0;
        for (int j2 = 0; j2 < 256; ++j2) {
            float vj = C[j2];
            cnt += (vj < v);
            eq  += (vj == v);
        }
        if (cnt <= 191 && 191 < cnt + eq) thrv = v;
    }
    __syncthreads();
    {
        int n = tid >> 4, m = tid & 15;
        adj[n][m] = (C[tid] > thrv && n != m) ? 1.f : 0.f;
    }
    __syncthreads();
    for (int i = tid; i < 4096; i += 256) {
        int n = i >> 8, f = i & 255;
        float acc = nf[n][f];
#pragma unroll
        for (int m = 0; m < 16; ++m) acc = fmaf(adj[n][m], nf[m][f], acc);
        sb[n][f] = acc;
    }
    __syncthreads();
    for (int i = tid; i < 1024; i += 256) {
        int n = i >> 6, o = i & 63;
        const float4* wr4 = reinterpret_cast<const float4*>(gw0 + (size_t)o * 256);
        float acc = gb0[o];
        for (int f4 = 0; f4 < 64; ++f4) {
            float4 wv = wr4[f4];
            int f = f4 * 4;
            acc = fmaf(sb[n][f + 0], wv.x, acc);
            acc = fmaf(sb[n][f + 1], wv.y, acc);
            acc = fmaf(sb[n][f + 2], wv.z, acc);
            acc = fmaf(sb[n][f + 3], wv.w, acc);
        }
        bufA[n][o] = fmaxf(acc, 0.f);
    }
    __syncthreads();
    for (int i = tid; i < 1024; i += 256) {
        int n = i >> 6, f = i & 63;
        float acc = bufA[n][f];
#pragma unroll
        for (int m = 0; m < 16; ++m) acc = fmaf(adj[n][m], bufA[m][f], acc);
        bufB[n][f] = acc;
    }
    __syncthreads();
    for (int i = tid; i < 1024; i += 256) {
        int n = i >> 6, o = i & 63;
        const float4* wr4 = reinterpret_cast<const float4*>(gw1 + (size_t)o * 64);
        float acc = gb1[o];
        for (int f4 = 0; f4 < 16; ++f4) {
            float4 wv = wr4[f4];
            int f = f4 * 4;
            acc = fmaf(bufB[n][f + 0], wv.x, acc);
            acc = fmaf(bufB[n][f + 1], wv.y, acc);
            acc = fmaf(bufB[n][f + 2], wv.z, acc);
            acc = fmaf(bufB[n][f + 3], wv.w, acc);
        }
        bufC[n][o] = fmaxf(acc, 0.f);
    }
    __syncthreads();
    for (int i = tid; i < 1024; i += 256) {
        int n = i >> 6, f = i & 63;
        float acc = bufC[n][f];
#pragma unroll
        for (int m = 0; m < 16; ++m) acc = fmaf(adj[n][m], bufC[m][f], acc);
        bufA[n][f] = acc;
    }
    __syncthreads();
    for (int i = tid; i < 1024; i += 256) {
        int n = i >> 6, o = i & 63;
        const float4* wr4 = reinterpret_cast<const float4*>(gw2 + (size_t)o * 64);
        float acc = gb2[o];
        for (int f4 = 0; f4 < 16; ++f4) {
            float4 wv = wr4[f4];
            int f = f4 * 4;
            acc = fmaf(bufA[n][f + 0], wv.x, acc);
            acc = fmaf(bufA[n][f + 1], wv.y, acc);
            acc = fmaf(bufA[n][f + 2], wv.z, acc);
            acc = fmaf(bufA[n][f + 3], wv.w, acc);
        }
        bufB[n][o] = fmaxf(acc, 0.f);
    }
    __syncthreads();
    if (tid < 64) {
        float mx = bufB[0][tid];
#pragma unroll
        for (int n = 1; n < 16; ++n) mx = fmaxf(mx, bufB[n][tid]);
        emb[tid] = mx;
    }
    __syncthreads();
    if (tid < 5) {
        float acc = clb[tid];
#pragma unroll
        for (int o = 0; o < 64; ++o) acc = fmaf(emb[o], clw[tid * 64 + o], acc);
        out[(size_t)b * 5 + tid] = acc;
    }
}

extern "C" void kernel_launch(void* const* d_in, const int* in_sizes, int n_in,
                              void* d_out, int out_size, void* d_ws, size_t ws_size,
                              hipStream_t stream)
{
    const float* x    = (const float*)d_in[0];
    const float* cw0  = (const float*)d_in[1];
    const float* cb0  = (const float*)d_in[2];
    const float* bng0 = (const float*)d_in[3];
    const float* bnb0 = (const float*)d_in[4];
    const float* bnm0 = (const float*)d_in[5];
    const float* bnv0 = (const float*)d_in[6];
    const float* cw1  = (const float*)d_in[7];
    const float* cb1  = (const float*)d_in[8];
    const float* bng1 = (const float*)d_in[9];
    const float* bnb1 = (const float*)d_in[10];
    const float* bnm1 = (const float*)d_in[11];
    const float* bnv1 = (const float*)d_in[12];
    const float* cw2  = (const float*)d_in[13];
    const float* cb2  = (const float*)d_in[14];
    const float* bng2 = (const float*)d_in[15];
    const float* bnb2 = (const float*)d_in[16];
    const float* bnm2 = (const float*)d_in[17];
    const float* bnv2 = (const float*)d_in[18];
    const float* wih0 = (const float*)d_in[19];
    const float* whh0 = (const float*)d_in[20];
    const float* bih0 = (const float*)d_in[21];
    const float* bhh0 = (const float*)d_in[22];
    const float* wih1 = (const float*)d_in[23];
    const float* whh1 = (const float*)d_in[24];
    const float* bih1 = (const float*)d_in[25];
    const float* bhh1 = (const float*)d_in[26];
    const float* gw0  = (const float*)d_in[27];
    const float* gb0  = (const float*)d_in[28];
    const float* gw1  = (const float*)d_in[29];
    const float* gb1  = (const float*)d_in[30];
    const float* gw2  = (const float*)d_in[31];
    const float* gb2  = (const float*)d_in[32];
    const float* clw  = (const float*)d_in[33];
    const float* clb  = (const float*)d_in[34];

    // ws layout (floats)
    float* xs  = (float*)d_ws;            // (B,64,64) = 1048576
    float* hs  = xs + 1048576;            // (B,64,64) = 1048576
    float* wt1 = hs + 1048576;            // 2560
    float* b1  = wt1 + 2560;              // 32
    float* wt2 = b1 + 32;                 // 10240
    float* b2  = wt2 + 10240;             // 64
    float* w0f = b2 + 64;                 // 80
    float* b0f = w0f + 80;                // 16

    prep_weights_kernel<<<1, 256, 0, stream>>>(
        cw0, cb0, bng0, bnb0, bnm0, bnv0,
        cw1, cb1, bng1, bnb1, bnm1, bnv1,
        cw2, cb2, bng2, bnb2, bnm2, bnv2,
        wt1, b1, wt2, b2, w0f, b0f);
    convall_kernel<<<dim3(32, 256), 256, 0, stream>>>(x, w0f, b0f, wt1, b1, wt2, b2, xs);
    lstm_kernel<<<256, 256, 0, stream>>>(xs, wih0, whh0, bih0, bhh0,
                                         wih1, whh1, bih1, bhh1, hs);
    graph_kernel<<<256, 256, 0, stream>>>(hs, gw0, gb0, gw1, gb1, gw2, gb2,
                                          clw, clb, (float*)d_out);
}

// Round 9
// 468.975 us; speedup vs baseline: 1.5158x; 1.0192x over previous
//
#include <hip/hip_runtime.h>
#include <math.h>

typedef __attribute__((ext_vector_type(2))) float v2f;

// ---------------- prep: transpose + BN-fold conv weights into [ci][t][co] layout
__global__ __launch_bounds__(256) void prep_weights_kernel(
    const float* __restrict__ cw0, const float* __restrict__ cb0,
    const float* __restrict__ bng0, const float* __restrict__ bnb0,
    const float* __restrict__ bnm0, const float* __restrict__ bnv0,
    const float* __restrict__ cw1, const float* __restrict__ cb1,
    const float* __restrict__ bng1, const float* __restrict__ bnb1,
    const float* __restrict__ bnm1, const float* __restrict__ bnv1,
    const float* __restrict__ cw2, const float* __restrict__ cb2,
    const float* __restrict__ bng2, const float* __restrict__ bnb2,
    const float* __restrict__ bnm2, const float* __restrict__ bnv2,
    float* __restrict__ wt1, float* __restrict__ b1,
    float* __restrict__ wt2, float* __restrict__ b2,
    float* __restrict__ w0f, float* __restrict__ b0f)
{
    int tid = threadIdx.x;
    for (int i = tid; i < 2560; i += 256) {
        int co = i & 31, r = i >> 5, t = r % 5, ci = r / 5;
        float s = bng1[co] * rsqrtf(bnv1[co] + 1e-5f);
        wt1[i] = cw1[(co * 16 + ci) * 5 + t] * s;
    }
    if (tid < 32) {
        float s = bng1[tid] * rsqrtf(bnv1[tid] + 1e-5f);
        b1[tid] = (cb1[tid] - bnm1[tid]) * s + bnb1[tid];
    }
    for (int i = tid; i < 10240; i += 256) {
        int co = i & 63, r = i >> 6, t = r % 5, ci = r / 5;
        float s = bng2[co] * rsqrtf(bnv2[co] + 1e-5f);
        wt2[i] = cw2[(co * 32 + ci) * 5 + t] * s;
    }
    if (tid < 64) {
        float s = bng2[tid] * rsqrtf(bnv2[tid] + 1e-5f);
        b2[tid] = (cb2[tid] - bnm2[tid]) * s + bnb2[tid];
    }
    if (tid < 80) {
        int co = tid / 5;
        float s = bng0[co] * rsqrtf(bnv0[co] + 1e-5f);
        w0f[tid] = cw0[tid] * s;
    }
    if (tid < 16) {
        float s = bng0[tid] * rsqrtf(bnv0[tid] + 1e-5f);
        b0f[tid] = (cb0[tid] - bnm0[tid]) * s + bnb0[tid];
    }
}

// ---------------- fully fused CNN: x (B,1,15360) -> xs (B,64,64)
// LDS diet: 8096 floats = 31.6 KB -> 5 blocks/CU. Layout:
//   xt0: U[ci0*254], 16 rows (reads to float 251)
//   xt1: U[4064 + ci*126], 32 rows (reads to float 123 via jje clamp)
//   raw: U[4064..4576) -- overlaps xt1 region, dead before conv1 writes
//   Y  : U[co*61], 64 rows -- xt0 region, dead after conv1
// Accumulation chains identical to round 8 -> bit-identical results.
__global__ __launch_bounds__(256) void convall_kernel(
    const float* __restrict__ x,
    const float* __restrict__ w0f, const float* __restrict__ b0f,
    const float* __restrict__ wt1, const float* __restrict__ b1,
    const float* __restrict__ wt2, const float* __restrict__ b2,
    float* __restrict__ xs)
{
    __shared__ float U[8096];
    float* raw = &U[4064];
    int b = blockIdx.y, bx = blockIdx.x, tid = threadIdx.x;
    const float* xb = x + (size_t)b * 15360;
    {
        int base = 480 * bx - 14;
        for (int i = tid; i < 508; i += 256) {
            int g = base + i;
            raw[i] = (g >= 0 && g < 15360) ? xb[g] : 0.f;
        }
    }
    __syncthreads();
    // ---- conv0 (+BN+ReLU+maxpool2): 252 pooled values per ci0
    {
        int ci0 = tid >> 4, sub = tid & 15;
        float w0 = w0f[ci0*5+0], w1 = w0f[ci0*5+1], w2 = w0f[ci0*5+2],
              w3 = w0f[ci0*5+3], w4 = w0f[ci0*5+4];
        float bb = b0f[ci0];
        int r0g = 240 * bx - 6;
        for (int p = sub; p < 252; p += 16) {
            int r = r0g + p;
            float v = 0.f;
            if (r >= 0 && r < 7680) {
                int i0 = 2 * p;
                float c0 = raw[i0],   c1 = raw[i0+1], c2 = raw[i0+2],
                      c3 = raw[i0+3], c4 = raw[i0+4], c5 = raw[i0+5];
                float s0 = fmaf(w0,c0, fmaf(w1,c1, fmaf(w2,c2, fmaf(w3,c3, w4*c4))));
                float s1 = fmaf(w0,c1, fmaf(w1,c2, fmaf(w2,c3, fmaf(w3,c4, w4*c5))));
                v = fmaxf(fmaxf(s0, s1) + bb, 0.f);
            }
            U[ci0 * 254 + p] = v;
        }
    }
    __syncthreads();
    // ---- conv1 (+BN+ReLU+maxpool2): 124 pooled values per co (raw now dead)
    {
        int cg = tid >> 7, jj = tid & 127;
        int cgu = __builtin_amdgcn_readfirstlane(cg);
        if (tid < 64) { int co = tid >> 1, c = 124 + (tid & 1); U[4064 + co * 126 + c] = 0.f; }
        if (jj < 124) {
            const float* wb = wt1 + cgu * 16;
            v2f a0[8], a1[8];
#pragma unroll
            for (int q = 0; q < 8; ++q) { a0[q] = (v2f){0.f,0.f}; a1[q] = (v2f){0.f,0.f}; }
#pragma unroll 4
            for (int ci = 0; ci < 16; ++ci) {
                const float2* xr = reinterpret_cast<const float2*>(&U[ci * 254]);
                float2 xA = xr[jj], xB = xr[jj + 1], xC = xr[jj + 2];
                float xv[6] = { xA.x, xA.y, xB.x, xB.y, xC.x, xC.y };
#pragma unroll
                for (int t = 0; t < 5; ++t) {
                    const v2f* wp2 = reinterpret_cast<const v2f*>(wb + (ci * 5 + t) * 32);
                    v2f va = { xv[t], xv[t] };
                    v2f vc = { xv[t + 1], xv[t + 1] };
#pragma unroll
                    for (int q2 = 0; q2 < 8; ++q2) {
                        v2f w = wp2[q2];
                        a0[q2] = __builtin_elementwise_fma(w, va, a0[q2]);
                        a1[q2] = __builtin_elementwise_fma(w, vc, a1[q2]);
                    }
                }
            }
            int q = 120 * bx - 2 + jj;
            bool ok = (q >= 0 && q < 3840);
#pragma unroll
            for (int q2 = 0; q2 < 8; ++q2) {
#pragma unroll
                for (int cpp = 0; cpp < 2; ++cpp) {
                    int qq = 2 * q2 + cpp;
                    int co = cgu * 16 + qq;
                    float val = 0.f;
                    if (ok) val = fmaxf(fmaxf(a0[q2][cpp], a1[q2][cpp]) + b1[co], 0.f);
                    U[4064 + co * 126 + jj] = val;
                }
            }
        }
    }
    __syncthreads();
    // ---- conv2 (+BN+ReLU+maxpool2) + avgpool epilogue
    {
        int cg = tid >> 6, jj = tid & 63;
        int jje = (jj < 59) ? jj : 59;    // lanes 60..63 duplicate jj=59 (discarded)
        int cgu = __builtin_amdgcn_readfirstlane(cg);
        const float* wb = wt2 + cgu * 16;
        v2f a0[8], a1[8];
#pragma unroll
        for (int q = 0; q < 8; ++q) { a0[q] = (v2f){0.f,0.f}; a1[q] = (v2f){0.f,0.f}; }
#pragma unroll 4
        for (int ci = 0; ci < 32; ++ci) {
            const float2* xr = reinterpret_cast<const float2*>(&U[4064 + ci * 126]);
            float2 xA = xr[jje], xB = xr[jje + 1], xC = xr[jje + 2];
            float xv[6] = { xA.x, xA.y, xB.x, xB.y, xC.x, xC.y };
#pragma unroll
            for (int t = 0; t < 5; ++t) {
                const v2f* wp2 = reinterpret_cast<const v2f*>(wb + (ci * 5 + t) * 64);
                v2f va = { xv[t], xv[t] };
                v2f vc = { xv[t + 1], xv[t + 1] };
#pragma unroll
                for (int q2 = 0; q2 < 8; ++q2) {
                    v2f w = wp2[q2];
                    a0[q2] = __builtin_elementwise_fma(w, va, a0[q2]);
                    a1[q2] = __builtin_elementwise_fma(w, vc, a1[q2]);
                }
            }
        }
        __syncthreads();     // xt0/xt1 dead; U[0..3904) becomes Y[64 co][stride 61]
        if (jj < 60) {
#pragma unroll
            for (int q2 = 0; q2 < 8; ++q2) {
#pragma unroll
                for (int cpp = 0; cpp < 2; ++cpp) {
                    int qq = 2 * q2 + cpp;
                    int co = cgu * 16 + qq;
                    float m = fmaxf(a0[q2][cpp], a1[q2][cpp]) + b2[co];
                    U[co * 61 + jj] = fmaxf(m, 0.f);
                }
            }
        }
    }
    __syncthreads();
    if (tid < 128) {
        int co = tid & 63, bin = tid >> 6;
        const float* r = U + co * 61 + bin * 30;
        float s = 0.f;
#pragma unroll
        for (int k = 0; k < 30; ++k) s += r[k];
        xs[((size_t)b * 64 + (blockIdx.x * 2 + bin)) * 64 + co] = s * (1.f / 30.f);
    }
}

// ---------------- fused LSTM (2 layers) + graph/GCN/classifier, one block per batch elem.
// LSTM: 1 barrier/step via per-wave hbw copies + double-buffered gate exchange.
// Graph phase reuses the xg region; layer-1 h handed off via LDS (xb).
__global__ __launch_bounds__(256) void lstmgraph_kernel(
    const float* __restrict__ xseq,
    const float* __restrict__ wih0, const float* __restrict__ whh0,
    const float* __restrict__ bih0, const float* __restrict__ bhh0,
    const float* __restrict__ wih1, const float* __restrict__ whh1,
    const float* __restrict__ bih1, const float* __restrict__ bhh1,
    const float* __restrict__ gw0, const float* __restrict__ gb0,
    const float* __restrict__ gw1, const float* __restrict__ gb1,
    const float* __restrict__ gw2, const float* __restrict__ gb2,
    const float* __restrict__ clw, const float* __restrict__ clb,
    float* __restrict__ out)
{
    __shared__ float xb[64][64];        // lstm input -> layer h storage
    __shared__ float xg[16384];         // lstm x-gate precompute; graph-union later
    __shared__ float gbuf[2][4][64];    // double-buffered gate exchange
    __shared__ float hbw[4][64];        // per-wave h copies
    int b = blockIdx.x;
    int tid = threadIdx.x;
    int wv = tid >> 6, ln = tid & 63;
    for (int i = tid; i < 4096; i += 256) xb[i >> 6][i & 63] = xseq[(size_t)b * 4096 + i];
    __syncthreads();
    float wr[64];
    for (int layer = 0; layer < 2; ++layer) {
        const float* wih = layer ? wih1 : wih0;
        const float* whh = layer ? whh1 : whh0;
        float bias = layer ? (bih1[tid] + bhh1[tid]) : (bih0[tid] + bhh0[tid]);
        // phase A: xg[t*256+tid] = bias + x_t . wih_row(tid)
#pragma unroll
        for (int k4 = 0; k4 < 16; ++k4) {
            float4 v = reinterpret_cast<const float4*>(wih + (size_t)tid * 64)[k4];
            wr[k4 * 4 + 0] = v.x; wr[k4 * 4 + 1] = v.y;
            wr[k4 * 4 + 2] = v.z; wr[k4 * 4 + 3] = v.w;
        }
        for (int t = 0; t < 64; ++t) {
            float s0 = bias, s1 = 0.f, s2 = 0.f, s3 = 0.f;
#pragma unroll
            for (int k4 = 0; k4 < 16; ++k4) {
                float4 xv4 = *reinterpret_cast<const float4*>(&xb[t][k4 * 4]);
                s0 = fmaf(wr[k4 * 4 + 0], xv4.x, s0);
                s1 = fmaf(wr[k4 * 4 + 1], xv4.y, s1);
                s2 = fmaf(wr[k4 * 4 + 2], xv4.z, s2);
                s3 = fmaf(wr[k4 * 4 + 3], xv4.w, s3);
            }
            xg[t * 256 + tid] = (s0 + s1) + (s2 + s3);
        }
        // phase B: recurrence, 1 barrier per step
#pragma unroll
        for (int k4 = 0; k4 < 16; ++k4) {
            float4 v = reinterpret_cast<const float4*>(whh + (size_t)tid * 64)[k4];
            wr[k4 * 4 + 0] = v.x; wr[k4 * 4 + 1] = v.y;
            wr[k4 * 4 + 2] = v.z; wr[k4 * 4 + 3] = v.w;
        }
        hbw[wv][ln] = 0.f;    // each wave its own copy (wave-coherent)
        float c = 0.f;
        __syncthreads();      // xg/xb ready; hbw init visible within wave anyway
        for (int t = 0; t < 64; ++t) {
            float s0 = xg[t * 256 + tid], s1 = 0.f, s2 = 0.f, s3 = 0.f;
#pragma unroll
            for (int k4 = 0; k4 < 16; ++k4) {
                float4 hv4 = *reinterpret_cast<const float4*>(&hbw[wv][k4 * 4]);
                s0 = fmaf(wr[k4 * 4 + 0], hv4.x, s0);
                s1 = fmaf(wr[k4 * 4 + 1], hv4.y, s1);
                s2 = fmaf(wr[k4 * 4 + 2], hv4.z, s2);
                s3 = fmaf(wr[k4 * 4 + 3], hv4.w, s3);
            }
            float acc = (s0 + s1) + (s2 + s3);
            float a;
            if (wv == 2) a = tanhf(acc);
            else         a = 1.f / (1.f + __expf(-acc));
            gbuf[t & 1][wv][ln] = a;
            __syncthreads();
            float gi = gbuf[t & 1][0][ln], gf = gbuf[t & 1][1][ln],
                  gg = gbuf[t & 1][2][ln], go = gbuf[t & 1][3][ln];
            c = fmaf(gf, c, gi * gg);
            float h = go * tanhf(c);
            hbw[wv][ln] = h;                 // own copy, no barrier needed
            if (wv == 0) xb[t][ln] = h;      // layer output (consumed after barrier)
        }
        __syncthreads();      // xb (layer h) complete before next phase
    }
    // ---------------- graph phase: xb = layer-1 h in [t][ch]; arrays live in xg
    float* nf   = xg;            // 16 x 257
    float* sb   = xg + 4112;     // 16 x 257
    float* red  = xg + 8224;     // 16 x 17
    float* mean = xg + 8496;     // 16
    float* rstd = xg + 8512;     // 16
    float* C    = xg + 8528;     // 256
    float* adj  = xg + 8784;     // 256
    float* thrv = xg + 9040;     // 1
    float* bufA = xg + 9044;     // 16 x 65
    float* bufB = xg + 10084;    // 16 x 65
    float* bufC = xg + 11124;    // 16 x 65
    float* emb  = xg + 12164;    // 64
    for (int i = tid; i < 4096; i += 256) {
        int n = i >> 8, f = i & 255;
        nf[n * 257 + f] = xb[4 * n + (f >> 6)][f & 63];
    }
    __syncthreads();
    int nd = tid >> 4, sub = tid & 15;
    {
        float s = 0.f;
        for (int f = sub; f < 256; f += 16) s += nf[nd * 257 + f];
        red[nd * 17 + sub] = s;
    }
    __syncthreads();
    if (tid < 16) {
        float m = 0.f;
        for (int i = 0; i < 16; ++i) m += red[tid * 17 + i];
        mean[tid] = m * (1.f / 256.f);
    }
    __syncthreads();
    {
        float mu = mean[nd];
        float ss = 0.f;
        for (int f = sub; f < 256; f += 16) { float d = nf[nd * 257 + f] - mu; ss = fmaf(d, d, ss); }
        red[nd * 17 + sub] = ss;
    }
    __syncthreads();
    if (tid < 16) {
        float m = 0.f;
        for (int i = 0; i < 16; ++i) m += red[tid * 17 + i];
        rstd[tid] = 1.f / (sqrtf(m * (1.f / 255.f)) + 1e-8f);
    }
    __syncthreads();
    for (int i = tid; i < 4096; i += 256) {
        int n = i >> 8, f = i & 255;
        sb[n * 257 + f] = (nf[n * 257 + f] - mean[n]) * rstd[n];
    }
    __syncthreads();
    {
        int n = tid >> 4, m = tid & 15;
        float a0 = 0, a1 = 0, a2 = 0, a3 = 0;
        for (int f = 0; f < 256; f += 4) {
            a0 = fmaf(sb[n * 257 + f + 0], sb[m * 257 + f + 0], a0);
            a1 = fmaf(sb[n * 257 + f + 1], sb[m * 257 + f + 1], a1);
            a2 = fmaf(sb[n * 257 + f + 2], sb[m * 257 + f + 2], a2);
            a3 = fmaf(sb[n * 257 + f + 3], sb[m * 257 + f + 3], a3);
        }
        C[tid] = ((a0 + a1) + (a2 + a3)) * (1.f / 256.f);
    }
    __syncthreads();
    {
        float v = C[tid];
        int cnt = 0, eq = 0;
        for (int j2 = 0; j2 < 256; ++j2) {
            float vj = C[j2];
            cnt += (vj < v);
            eq  += (vj == v);
        }
        if (cnt <= 191 && 191 < cnt + eq) thrv[0] = v;
    }
    __syncthreads();
    {
        int n = tid >> 4, m = tid & 15;
        adj[tid] = (C[tid] > thrv[0] && n != m) ? 1.f : 0.f;
    }
    __syncthreads();
    for (int i = tid; i < 4096; i += 256) {
        int n = i >> 8, f = i & 255;
        float acc = nf[n * 257 + f];
#pragma unroll
        for (int m = 0; m < 16; ++m) acc = fmaf(adj[n * 16 + m], nf[m * 257 + f], acc);
        sb[n * 257 + f] = acc;
    }
    __syncthreads();
    for (int i = tid; i < 1024; i += 256) {
        int n = i >> 6, o = i & 63;
        const float4* wr4 = reinterpret_cast<const float4*>(gw0 + (size_t)o * 256);
        float acc = gb0[o];
        for (int f4 = 0; f4 < 64; ++f4) {
            float4 wv4 = wr4[f4];
            int f = f4 * 4;
            acc = fmaf(sb[n * 257 + f + 0], wv4.x, acc);
            acc = fmaf(sb[n * 257 + f + 1], wv4.y, acc);
            acc = fmaf(sb[n * 257 + f + 2], wv4.z, acc);
            acc = fmaf(sb[n * 257 + f + 3], wv4.w, acc);
        }
        bufA[n * 65 + o] = fmaxf(acc, 0.f);
    }
    __syncthreads();
    for (int i = tid; i < 1024; i += 256) {
        int n = i >> 6, f = i & 63;
        float acc = bufA[n * 65 + f];
#pragma unroll
        for (int m = 0; m < 16; ++m) acc = fmaf(adj[n * 16 + m], bufA[m * 65 + f], acc);
        bufB[n * 65 + f] = acc;
    }
    __syncthreads();
    for (int i = tid; i < 1024; i += 256) {
        int n = i >> 6, o = i & 63;
        const float4* wr4 = reinterpret_cast<const float4*>(gw1 + (size_t)o * 64);
        float acc = gb1[o];
        for (int f4 = 0; f4 < 16; ++f4) {
            float4 wv4 = wr4[f4];
            int f = f4 * 4;
            acc = fmaf(bufB[n * 65 + f + 0], wv4.x, acc);
            acc = fmaf(bufB[n * 65 + f + 1], wv4.y, acc);
            acc = fmaf(bufB[n * 65 + f + 2], wv4.z, acc);
            acc = fmaf(bufB[n * 65 + f + 3], wv4.w, acc);
        }
        bufC[n * 65 + o] = fmaxf(acc, 0.f);
    }
    __syncthreads();
    for (int i = tid; i < 1024; i += 256) {
        int n = i >> 6, f = i & 63;
        float acc = bufC[n * 65 + f];
#pragma unroll
        for (int m = 0; m < 16; ++m) acc = fmaf(adj[n * 16 + m], bufC[m * 65 + f], acc);
        bufA[n * 65 + f] = acc;
    }
    __syncthreads();
    for (int i = tid; i < 1024; i += 256) {
        int n = i >> 6, o = i & 63;
        const float4* wr4 = reinterpret_cast<const float4*>(gw2 + (size_t)o * 64);
        float acc = gb2[o];
        for (int f4 = 0; f4 < 16; ++f4) {
            float4 wv4 = wr4[f4];
            int f = f4 * 4;
            acc = fmaf(bufA[n * 65 + f + 0], wv4.x, acc);
            acc = fmaf(bufA[n * 65 + f + 1], wv4.y, acc);
            acc = fmaf(bufA[n * 65 + f + 2], wv4.z, acc);
            acc = fmaf(bufA[n * 65 + f + 3], wv4.w, acc);
        }
        bufB[n * 65 + o] = fmaxf(acc, 0.f);
    }
    __syncthreads();
    if (tid < 64) {
        float mx = bufB[0 * 65 + tid];
#pragma unroll
        for (int n = 1; n < 16; ++n) mx = fmaxf(mx, bufB[n * 65 + tid]);
        emb[tid] = mx;
    }
    __syncthreads();
    if (tid < 5) {
        float acc = clb[tid];
#pragma unroll
        for (int o = 0; o < 64; ++o) acc = fmaf(emb[o], clw[tid * 64 + o], acc);
        out[(size_t)b * 5 + tid] = acc;
    }
}

extern "C" void kernel_launch(void* const* d_in, const int* in_sizes, int n_in,
                              void* d_out, int out_size, void* d_ws, size_t ws_size,
                              hipStream_t stream)
{
    const float* x    = (const float*)d_in[0];
    const float* cw0  = (const float*)d_in[1];
    const float* cb0  = (const float*)d_in[2];
    const float* bng0 = (const float*)d_in[3];
    const float* bnb0 = (const float*)d_in[4];
    const float* bnm0 = (const float*)d_in[5];
    const float* bnv0 = (const float*)d_in[6];
    const float* cw1  = (const float*)d_in[7];
    const float* cb1  = (const float*)d_in[8];
    const float* bng1 = (const float*)d_in[9];
    const float* bnb1 = (const float*)d_in[10];
    const float* bnm1 = (const float*)d_in[11];
    const float* bnv1 = (const float*)d_in[12];
    const float* cw2  = (const float*)d_in[13];
    const float* cb2  = (const float*)d_in[14];
    const float* bng2 = (const float*)d_in[15];
    const float* bnb2 = (const float*)d_in[16];
    const float* bnm2 = (const float*)d_in[17];
    const float* bnv2 = (const float*)d_in[18];
    const float* wih0 = (const float*)d_in[19];
    const float* whh0 = (const float*)d_in[20];
    const float* bih0 = (const float*)d_in[21];
    const float* bhh0 = (const float*)d_in[22];
    const float* wih1 = (const float*)d_in[23];
    const float* whh1 = (const float*)d_in[24];
    const float* bih1 = (const float*)d_in[25];
    const float* bhh1 = (const float*)d_in[26];
    const float* gw0  = (const float*)d_in[27];
    const float* gb0  = (const float*)d_in[28];
    const float* gw1  = (const float*)d_in[29];
    const float* gb1  = (const float*)d_in[30];
    const float* gw2  = (const float*)d_in[31];
    const float* gb2  = (const float*)d_in[32];
    const float* clw  = (const float*)d_in[33];
    const float* clb  = (const float*)d_in[34];

    // ws layout (floats)
    float* xs  = (float*)d_ws;            // (B,64,64) = 1048576
    float* wt1 = xs + 1048576;            // 2560
    float* b1  = wt1 + 2560;              // 32
    float* wt2 = b1 + 32;                 // 10240
    float* b2  = wt2 + 10240;             // 64
    float* w0f = b2 + 64;                 // 80
    float* b0f = w0f + 80;                // 16

    prep_weights_kernel<<<1, 256, 0, stream>>>(
        cw0, cb0, bng0, bnb0, bnm0, bnv0,
        cw1, cb1, bng1, bnb1, bnm1, bnv1,
        cw2, cb2, bng2, bnb2, bnm2, bnv2,
        wt1, b1, wt2, b2, w0f, b0f);
    convall_kernel<<<dim3(32, 256), 256, 0, stream>>>(x, w0f, b0f, wt1, b1, wt2, b2, xs);
    lstmgraph_kernel<<<256, 256, 0, stream>>>(xs, wih0, whh0, bih0, bhh0,
                                              wih1, whh1, bih1, bhh1,
                                              gw0, gb0, gw1, gb1, gw2, gb2,
                                              clw, clb, (float*)d_out);
}

// Round 10
// 462.363 us; speedup vs baseline: 1.5375x; 1.0143x over previous
//
#include <hip/hip_runtime.h>
#include <math.h>

typedef __attribute__((ext_vector_type(2))) float v2f;

// ---------------- prep: BN-fold + transpose conv weights; transpose LSTM weights
// wXc[k4*1024 + r*4 + c] = wX[r*64 + k4*4 + c]  (coalesced per-row float4 loads)
__global__ __launch_bounds__(256) void prep_weights_kernel(
    const float* __restrict__ cw0, const float* __restrict__ cb0,
    const float* __restrict__ bng0, const float* __restrict__ bnb0,
    const float* __restrict__ bnm0, const float* __restrict__ bnv0,
    const float* __restrict__ cw1, const float* __restrict__ cb1,
    const float* __restrict__ bng1, const float* __restrict__ bnb1,
    const float* __restrict__ bnm1, const float* __restrict__ bnv1,
    const float* __restrict__ cw2, const float* __restrict__ cb2,
    const float* __restrict__ bng2, const float* __restrict__ bnb2,
    const float* __restrict__ bnm2, const float* __restrict__ bnv2,
    const float* __restrict__ wih0, const float* __restrict__ whh0,
    const float* __restrict__ wih1, const float* __restrict__ whh1,
    float* __restrict__ wt1, float* __restrict__ b1,
    float* __restrict__ wt2, float* __restrict__ b2,
    float* __restrict__ w0f, float* __restrict__ b0f,
    float* __restrict__ wih0c, float* __restrict__ whh0c,
    float* __restrict__ wih1c, float* __restrict__ whh1c)
{
    int g = blockIdx.x * 256 + threadIdx.x;
    const int GS = 64 * 256;
    for (int i = g; i < 2560; i += GS) {
        int co = i & 31, r = i >> 5, t = r % 5, ci = r / 5;
        float s = bng1[co] * rsqrtf(bnv1[co] + 1e-5f);
        wt1[i] = cw1[(co * 16 + ci) * 5 + t] * s;
    }
    if (g < 32) {
        float s = bng1[g] * rsqrtf(bnv1[g] + 1e-5f);
        b1[g] = (cb1[g] - bnm1[g]) * s + bnb1[g];
    }
    for (int i = g; i < 10240; i += GS) {
        int co = i & 63, r = i >> 6, t = r % 5, ci = r / 5;
        float s = bng2[co] * rsqrtf(bnv2[co] + 1e-5f);
        wt2[i] = cw2[(co * 32 + ci) * 5 + t] * s;
    }
    if (g < 64) {
        float s = bng2[g] * rsqrtf(bnv2[g] + 1e-5f);
        b2[g] = (cb2[g] - bnm2[g]) * s + bnb2[g];
    }
    if (g < 80) {
        int co = g / 5;
        float s = bng0[co] * rsqrtf(bnv0[co] + 1e-5f);
        w0f[g] = cw0[g] * s;
    }
    if (g < 16) {
        float s = bng0[g] * rsqrtf(bnv0[g] + 1e-5f);
        b0f[g] = (cb0[g] - bnm0[g]) * s + bnb0[g];
    }
    for (int i = g; i < 16384; i += GS) {
        int c = i & 3, r = (i >> 2) & 255, k4 = i >> 10;
        int src = r * 64 + k4 * 4 + c;
        wih0c[i] = wih0[src];
        whh0c[i] = whh0[src];
        wih1c[i] = wih1[src];
        whh1c[i] = whh1[src];
    }
}

// ---------------- fully fused CNN + LSTM layer-0 x-gates:
// x (B,1,15360) -> xg0 (B,64,256).  Conv phases identical to round 9 (bit-exact).
__global__ __launch_bounds__(256) void convall_kernel(
    const float* __restrict__ x,
    const float* __restrict__ w0f, const float* __restrict__ b0f,
    const float* __restrict__ wt1, const float* __restrict__ b1,
    const float* __restrict__ wt2, const float* __restrict__ b2,
    const float* __restrict__ wih0c,
    const float* __restrict__ bih0, const float* __restrict__ bhh0,
    float* __restrict__ xg0g)
{
    __shared__ float U[8096];
    float* raw = &U[4064];
    int b = blockIdx.y, bx = blockIdx.x, tid = threadIdx.x;
    const float* xb = x + (size_t)b * 15360;
    {
        int base = 480 * bx - 14;
        for (int i = tid; i < 508; i += 256) {
            int g = base + i;
            raw[i] = (g >= 0 && g < 15360) ? xb[g] : 0.f;
        }
    }
    __syncthreads();
    // ---- conv0 (+BN+ReLU+maxpool2)
    {
        int ci0 = tid >> 4, sub = tid & 15;
        float w0 = w0f[ci0*5+0], w1 = w0f[ci0*5+1], w2 = w0f[ci0*5+2],
              w3 = w0f[ci0*5+3], w4 = w0f[ci0*5+4];
        float bb = b0f[ci0];
        int r0g = 240 * bx - 6;
        for (int p = sub; p < 252; p += 16) {
            int r = r0g + p;
            float v = 0.f;
            if (r >= 0 && r < 7680) {
                int i0 = 2 * p;
                float c0 = raw[i0],   c1 = raw[i0+1], c2 = raw[i0+2],
                      c3 = raw[i0+3], c4 = raw[i0+4], c5 = raw[i0+5];
                float s0 = fmaf(w0,c0, fmaf(w1,c1, fmaf(w2,c2, fmaf(w3,c3, w4*c4))));
                float s1 = fmaf(w0,c1, fmaf(w1,c2, fmaf(w2,c3, fmaf(w3,c4, w4*c5))));
                v = fmaxf(fmaxf(s0, s1) + bb, 0.f);
            }
            U[ci0 * 254 + p] = v;
        }
    }
    __syncthreads();
    // ---- conv1 (+BN+ReLU+maxpool2)
    {
        int cg = tid >> 7, jj = tid & 127;
        int cgu = __builtin_amdgcn_readfirstlane(cg);
        if (tid < 64) { int co = tid >> 1, c = 124 + (tid & 1); U[4064 + co * 126 + c] = 0.f; }
        if (jj < 124) {
            const float* wb = wt1 + cgu * 16;
            v2f a0[8], a1[8];
#pragma unroll
            for (int q = 0; q < 8; ++q) { a0[q] = (v2f){0.f,0.f}; a1[q] = (v2f){0.f,0.f}; }
#pragma unroll 4
            for (int ci = 0; ci < 16; ++ci) {
                const float2* xr = reinterpret_cast<const float2*>(&U[ci * 254]);
                float2 xA = xr[jj], xB = xr[jj + 1], xC = xr[jj + 2];
                float xv[6] = { xA.x, xA.y, xB.x, xB.y, xC.x, xC.y };
#pragma unroll
                for (int t = 0; t < 5; ++t) {
                    const v2f* wp2 = reinterpret_cast<const v2f*>(wb + (ci * 5 + t) * 32);
                    v2f va = { xv[t], xv[t] };
                    v2f vc = { xv[t + 1], xv[t + 1] };
#pragma unroll
                    for (int q2 = 0; q2 < 8; ++q2) {
                        v2f w = wp2[q2];
                        a0[q2] = __builtin_elementwise_fma(w, va, a0[q2]);
                        a1[q2] = __builtin_elementwise_fma(w, vc, a1[q2]);
                    }
                }
            }
            int q = 120 * bx - 2 + jj;
            bool ok = (q >= 0 && q < 3840);
#pragma unroll
            for (int q2 = 0; q2 < 8; ++q2) {
#pragma unroll
                for (int cpp = 0; cpp < 2; ++cpp) {
                    int qq = 2 * q2 + cpp;
                    int co = cgu * 16 + qq;
                    float val = 0.f;
                    if (ok) val = fmaxf(fmaxf(a0[q2][cpp], a1[q2][cpp]) + b1[co], 0.f);
                    U[4064 + co * 126 + jj] = val;
                }
            }
        }
    }
    __syncthreads();
    // ---- conv2 (+BN+ReLU+maxpool2) + avgpool into xsl (LDS)
    {
        int cg = tid >> 6, jj = tid & 63;
        int jje = (jj < 59) ? jj : 59;
        int cgu = __builtin_amdgcn_readfirstlane(cg);
        const float* wb = wt2 + cgu * 16;
        v2f a0[8], a1[8];
#pragma unroll
        for (int q = 0; q < 8; ++q) { a0[q] = (v2f){0.f,0.f}; a1[q] = (v2f){0.f,0.f}; }
#pragma unroll 4
        for (int ci = 0; ci < 32; ++ci) {
            const float2* xr = reinterpret_cast<const float2*>(&U[4064 + ci * 126]);
            float2 xA = xr[jje], xB = xr[jje + 1], xC = xr[jje + 2];
            float xv[6] = { xA.x, xA.y, xB.x, xB.y, xC.x, xC.y };
#pragma unroll
            for (int t = 0; t < 5; ++t) {
                const v2f* wp2 = reinterpret_cast<const v2f*>(wb + (ci * 5 + t) * 64);
                v2f va = { xv[t], xv[t] };
                v2f vc = { xv[t + 1], xv[t + 1] };
#pragma unroll
                for (int q2 = 0; q2 < 8; ++q2) {
                    v2f w = wp2[q2];
                    a0[q2] = __builtin_elementwise_fma(w, va, a0[q2]);
                    a1[q2] = __builtin_elementwise_fma(w, vc, a1[q2]);
                }
            }
        }
        __syncthreads();     // xt0/xt1 dead; U[0..3904) becomes Y
        if (jj < 60) {
#pragma unroll
            for (int q2 = 0; q2 < 8; ++q2) {
#pragma unroll
                for (int cpp = 0; cpp < 2; ++cpp) {
                    int qq = 2 * q2 + cpp;
                    int co = cgu * 16 + qq;
                    float m = fmaxf(a0[q2][cpp], a1[q2][cpp]) + b2[co];
                    U[co * 61 + jj] = fmaxf(m, 0.f);
                }
            }
        }
    }
    __syncthreads();
    if (tid < 128) {
        int co = tid & 63, bin = tid >> 6;
        const float* r = U + co * 61 + bin * 30;
        float s = 0.f;
#pragma unroll
        for (int k = 0; k < 30; ++k) s += r[k];
        U[3904 + bin * 64 + co] = s * (1.f / 30.f);    // xsl[bin][co]
    }
    __syncthreads();
    // ---- LSTM layer-0 x-gates for this block's 2 timesteps (bit-exact phase A)
    {
        int r = tid;
        float bias0 = bih0[r] + bhh0[r];
        float wr0[64];
#pragma unroll
        for (int k4 = 0; k4 < 16; ++k4) {
            float4 w4 = reinterpret_cast<const float4*>(wih0c)[k4 * 256 + r];
            wr0[k4*4+0] = w4.x; wr0[k4*4+1] = w4.y;
            wr0[k4*4+2] = w4.z; wr0[k4*4+3] = w4.w;
        }
#pragma unroll
        for (int bin = 0; bin < 2; ++bin) {
            float s0 = bias0, s1 = 0.f, s2 = 0.f, s3 = 0.f;
#pragma unroll
            for (int k4 = 0; k4 < 16; ++k4) {
                float4 xv4 = *reinterpret_cast<const float4*>(&U[3904 + bin * 64 + k4 * 4]);
                s0 = fmaf(wr0[k4*4+0], xv4.x, s0);
                s1 = fmaf(wr0[k4*4+1], xv4.y, s1);
                s2 = fmaf(wr0[k4*4+2], xv4.z, s2);
                s3 = fmaf(wr0[k4*4+3], xv4.w, s3);
            }
            xg0g[((size_t)b * 64 + 2 * bx + bin) * 256 + r] = (s0 + s1) + (s2 + s3);
        }
    }
}

// ---------------- fused LSTM recurrences + graph, 512 threads, 1 block/batch.
// xg0 prefetched from global per step; xg1 computed post-layer0 into global.
__global__ __launch_bounds__(512) void lstmgraph_kernel(
    const float* __restrict__ xg0g, float* __restrict__ xg1g,
    const float* __restrict__ whh0c, const float* __restrict__ wih1c,
    const float* __restrict__ whh1c,
    const float* __restrict__ bih1, const float* __restrict__ bhh1,
    const float* __restrict__ gw0, const float* __restrict__ gb0,
    const float* __restrict__ gw1, const float* __restrict__ gb1,
    const float* __restrict__ gw2, const float* __restrict__ gb2,
    const float* __restrict__ clw, const float* __restrict__ clb,
    float* __restrict__ out)
{
    __shared__ float xb[64][64];    // h storage (h0 then h1)
    __shared__ float G[12228];      // gbuf/hbw during lstm; graph arrays after
    float* gbuf = G;                // [2][4][64]
    float* hbw  = G + 512;          // [4][64]
    int b = blockIdx.x;
    int tid = threadIdx.x;
    int wv = tid >> 6, ln = tid & 63;
    size_t base0 = (size_t)b * 16384;
    float wr[64];
    // ---- layer 0 recurrence (waves 0-3)
    if (wv < 4) {
#pragma unroll
        for (int k4 = 0; k4 < 16; ++k4) {
            float4 w4 = reinterpret_cast<const float4*>(whh0c)[k4 * 256 + tid];
            wr[k4*4+0] = w4.x; wr[k4*4+1] = w4.y;
            wr[k4*4+2] = w4.z; wr[k4*4+3] = w4.w;
        }
        hbw[wv * 64 + ln] = 0.f;
    }
    float c = 0.f;
    float xg_cur = (wv < 4) ? xg0g[base0 + tid] : 0.f;
    for (int t = 0; t < 64; ++t) {
        float xg_nxt = 0.f;
        if (wv < 4 && t < 63) xg_nxt = xg0g[base0 + (size_t)(t + 1) * 256 + tid];
        if (wv < 4) {
            float s0 = xg_cur, s1 = 0.f, s2 = 0.f, s3 = 0.f;
#pragma unroll
            for (int k4 = 0; k4 < 16; ++k4) {
                float4 hv4 = *reinterpret_cast<const float4*>(&hbw[wv * 64 + k4 * 4]);
                s0 = fmaf(wr[k4*4+0], hv4.x, s0);
                s1 = fmaf(wr[k4*4+1], hv4.y, s1);
                s2 = fmaf(wr[k4*4+2], hv4.z, s2);
                s3 = fmaf(wr[k4*4+3], hv4.w, s3);
            }
            float acc = (s0 + s1) + (s2 + s3);
            float a;
            if (wv == 2) a = tanhf(acc);
            else         a = 1.f / (1.f + __expf(-acc));
            gbuf[(t & 1) * 256 + wv * 64 + ln] = a;
        }
        __syncthreads();
        if (wv < 4) {
            float gi = gbuf[(t & 1) * 256 + 0 * 64 + ln], gf = gbuf[(t & 1) * 256 + 1 * 64 + ln],
                  gg = gbuf[(t & 1) * 256 + 2 * 64 + ln], go = gbuf[(t & 1) * 256 + 3 * 64 + ln];
            c = fmaf(gf, c, gi * gg);
            float h = go * tanhf(c);
            hbw[wv * 64 + ln] = h;
            if (wv == 0) xb[t][ln] = h;
        }
        xg_cur = xg_nxt;
    }
    __syncthreads();   // xb (h0) complete
    // ---- layer 1 phase A: all 512 threads, row r = tid&255, half the timesteps each
    {
        int r = tid & 255;
        int tb = (tid >> 8) * 32;
        float bias1 = bih1[r] + bhh1[r];
        float wr1[64];
#pragma unroll
        for (int k4 = 0; k4 < 16; ++k4) {
            float4 w4 = reinterpret_cast<const float4*>(wih1c)[k4 * 256 + r];
            wr1[k4*4+0] = w4.x; wr1[k4*4+1] = w4.y;
            wr1[k4*4+2] = w4.z; wr1[k4*4+3] = w4.w;
        }
        for (int tt = 0; tt < 32; ++tt) {
            int t = tb + tt;
            float s0 = bias1, s1 = 0.f, s2 = 0.f, s3 = 0.f;
#pragma unroll
            for (int k4 = 0; k4 < 16; ++k4) {
                float4 xv4 = *reinterpret_cast<const float4*>(&xb[t][k4 * 4]);
                s0 = fmaf(wr1[k4*4+0], xv4.x, s0);
                s1 = fmaf(wr1[k4*4+1], xv4.y, s1);
                s2 = fmaf(wr1[k4*4+2], xv4.z, s2);
                s3 = fmaf(wr1[k4*4+3], xv4.w, s3);
            }
            xg1g[base0 + (size_t)t * 256 + r] = (s0 + s1) + (s2 + s3);
        }
    }
    // ---- layer 1 recurrence
    if (wv < 4) {
#pragma unroll
        for (int k4 = 0; k4 < 16; ++k4) {
            float4 w4 = reinterpret_cast<const float4*>(whh1c)[k4 * 256 + tid];
            wr[k4*4+0] = w4.x; wr[k4*4+1] = w4.y;
            wr[k4*4+2] = w4.z; wr[k4*4+3] = w4.w;
        }
        hbw[wv * 64 + ln] = 0.f;
    }
    c = 0.f;
    __syncthreads();   // xg1g writes drained; hbw reset
    xg_cur = (wv < 4) ? xg1g[base0 + tid] : 0.f;
    for (int t = 0; t < 64; ++t) {
        float xg_nxt = 0.f;
        if (wv < 4 && t < 63) xg_nxt = xg1g[base0 + (size_t)(t + 1) * 256 + tid];
        if (wv < 4) {
            float s0 = xg_cur, s1 = 0.f, s2 = 0.f, s3 = 0.f;
#pragma unroll
            for (int k4 = 0; k4 < 16; ++k4) {
                float4 hv4 = *reinterpret_cast<const float4*>(&hbw[wv * 64 + k4 * 4]);
                s0 = fmaf(wr[k4*4+0], hv4.x, s0);
                s1 = fmaf(wr[k4*4+1], hv4.y, s1);
                s2 = fmaf(wr[k4*4+2], hv4.z, s2);
                s3 = fmaf(wr[k4*4+3], hv4.w, s3);
            }
            float acc = (s0 + s1) + (s2 + s3);
            float a;
            if (wv == 2) a = tanhf(acc);
            else         a = 1.f / (1.f + __expf(-acc));
            gbuf[(t & 1) * 256 + wv * 64 + ln] = a;
        }
        __syncthreads();
        if (wv < 4) {
            float gi = gbuf[(t & 1) * 256 + 0 * 64 + ln], gf = gbuf[(t & 1) * 256 + 1 * 64 + ln],
                  gg = gbuf[(t & 1) * 256 + 2 * 64 + ln], go = gbuf[(t & 1) * 256 + 3 * 64 + ln];
            c = fmaf(gf, c, gi * gg);
            float h = go * tanhf(c);
            hbw[wv * 64 + ln] = h;
            if (wv == 0) xb[t][ln] = h;
        }
        xg_cur = xg_nxt;
    }
    __syncthreads();   // xb (h1) complete; gbuf/hbw dead -> graph arrays may use G
    // ---------------- graph phase
    float* nf   = G;            // 16 x 257
    float* sb   = G + 4112;     // 16 x 257
    float* red  = G + 8224;     // 16 x 17
    float* mean = G + 8496;     // 16
    float* rstd = G + 8512;     // 16
    float* C    = G + 8528;     // 256
    float* adj  = G + 8784;     // 256
    float* thrv = G + 9040;     // 1 (+pad)
    float* bufA = G + 9044;     // 16 x 65
    float* bufB = G + 10084;    // 16 x 65
    float* bufC = G + 11124;    // 16 x 65
    float* emb  = G + 12164;    // 64
    for (int i = tid; i < 4096; i += 512) {
        int n = i >> 8, f = i & 255;
        nf[n * 257 + f] = xb[4 * n + (f >> 6)][f & 63];
    }
    __syncthreads();
    int nd = (tid >> 4) & 15, sub = tid & 15;
    if (tid < 256) {
        float s = 0.f;
        for (int f = sub; f < 256; f += 16) s += nf[nd * 257 + f];
        red[nd * 17 + sub] = s;
    }
    __syncthreads();
    if (tid < 16) {
        float m = 0.f;
        for (int i = 0; i < 16; ++i) m += red[tid * 17 + i];
        mean[tid] = m * (1.f / 256.f);
    }
    __syncthreads();
    if (tid < 256) {
        float mu = mean[nd];
        float ss = 0.f;
        for (int f = sub; f < 256; f += 16) { float d = nf[nd * 257 + f] - mu; ss = fmaf(d, d, ss); }
        red[nd * 17 + sub] = ss;
    }
    __syncthreads();
    if (tid < 16) {
        float m = 0.f;
        for (int i = 0; i < 16; ++i) m += red[tid * 17 + i];
        rstd[tid] = 1.f / (sqrtf(m * (1.f / 255.f)) + 1e-8f);
    }
    __syncthreads();
    for (int i = tid; i < 4096; i += 512) {
        int n = i >> 8, f = i & 255;
        sb[n * 257 + f] = (nf[n * 257 + f] - mean[n]) * rstd[n];
    }
    __syncthreads();
    if (tid < 256) {
        int n = tid >> 4, m = tid & 15;
        float a0 = 0, a1 = 0, a2 = 0, a3 = 0;
        for (int f = 0; f < 256; f += 4) {
            a0 = fmaf(sb[n * 257 + f + 0], sb[m * 257 + f + 0], a0);
            a1 = fmaf(sb[n * 257 + f + 1], sb[m * 257 + f + 1], a1);
            a2 = fmaf(sb[n * 257 + f + 2], sb[m * 257 + f + 2], a2);
            a3 = fmaf(sb[n * 257 + f + 3], sb[m * 257 + f + 3], a3);
        }
        C[tid] = ((a0 + a1) + (a2 + a3)) * (1.f / 256.f);
    }
    __syncthreads();
    if (tid < 256) {
        float v = C[tid];
        int cnt = 0, eq = 0;
        for (int j2 = 0; j2 < 256; ++j2) {
            float vj = C[j2];
            cnt += (vj < v);
            eq  += (vj == v);
        }
        if (cnt <= 191 && 191 < cnt + eq) thrv[0] = v;
    }
    __syncthreads();
    if (tid < 256) {
        int n = tid >> 4, m = tid & 15;
        adj[tid] = (C[tid] > thrv[0] && n != m) ? 1.f : 0.f;
    }
    __syncthreads();
    for (int i = tid; i < 4096; i += 512) {
        int n = i >> 8, f = i & 255;
        float acc = nf[n * 257 + f];
#pragma unroll
        for (int m = 0; m < 16; ++m) acc = fmaf(adj[n * 16 + m], nf[m * 257 + f], acc);
        sb[n * 257 + f] = acc;
    }
    __syncthreads();
    for (int i = tid; i < 1024; i += 512) {
        int n = i >> 6, o = i & 63;
        const float4* wr4 = reinterpret_cast<const float4*>(gw0 + (size_t)o * 256);
        float acc = gb0[o];
        for (int f4 = 0; f4 < 64; ++f4) {
            float4 wv4 = wr4[f4];
            int f = f4 * 4;
            acc = fmaf(sb[n * 257 + f + 0], wv4.x, acc);
            acc = fmaf(sb[n * 257 + f + 1], wv4.y, acc);
            acc = fmaf(sb[n * 257 + f + 2], wv4.z, acc);
            acc = fmaf(sb[n * 257 + f + 3], wv4.w, acc);
        }
        bufA[n * 65 + o] = fmaxf(acc, 0.f);
    }
    __syncthreads();
    for (int i = tid; i < 1024; i += 512) {
        int n = i >> 6, f = i & 63;
        float acc = bufA[n * 65 + f];
#pragma unroll
        for (int m = 0; m < 16; ++m) acc = fmaf(adj[n * 16 + m], bufA[m * 65 + f], acc);
        bufB[n * 65 + f] = acc;
    }
    __syncthreads();
    for (int i = tid; i < 1024; i += 512) {
        int n = i >> 6, o = i & 63;
        const float4* wr4 = reinterpret_cast<const float4*>(gw1 + (size_t)o * 64);
        float acc = gb1[o];
        for (int f4 = 0; f4 < 16; ++f4) {
            float4 wv4 = wr4[f4];
            int f = f4 * 4;
            acc = fmaf(bufB[n * 65 + f + 0], wv4.x, acc);
            acc = fmaf(bufB[n * 65 + f + 1], wv4.y, acc);
            acc = fmaf(bufB[n * 65 + f + 2], wv4.z, acc);
            acc = fmaf(bufB[n * 65 + f + 3], wv4.w, acc);
        }
        bufC[n * 65 + o] = fmaxf(acc, 0.f);
    }
    __syncthreads();
    for (int i = tid; i < 1024; i += 512) {
        int n = i >> 6, f = i & 63;
        float acc = bufC[n * 65 + f];
#pragma unroll
        for (int m = 0; m < 16; ++m) acc = fmaf(adj[n * 16 + m], bufC[m * 65 + f], acc);
        bufA[n * 65 + f] = acc;
    }
    __syncthreads();
    for (int i = tid; i < 1024; i += 512) {
        int n = i >> 6, o = i & 63;
        const float4* wr4 = reinterpret_cast<const float4*>(gw2 + (size_t)o * 64);
        float acc = gb2[o];
        for (int f4 = 0; f4 < 16; ++f4) {
            float4 wv4 = wr4[f4];
            int f = f4 * 4;
            acc = fmaf(bufA[n * 65 + f + 0], wv4.x, acc);
            acc = fmaf(bufA[n * 65 + f + 1], wv4.y, acc);
            acc = fmaf(bufA[n * 65 + f + 2], wv4.z, acc);
            acc = fmaf(bufA[n * 65 + f + 3], wv4.w, acc);
        }
        bufB[n * 65 + o] = fmaxf(acc, 0.f);
    }
    __syncthreads();
    if (tid < 64) {
        float mx = bufB[tid];
#pragma unroll
        for (int n = 1; n < 16; ++n) mx = fmaxf(mx, bufB[n * 65 + tid]);
        emb[tid] = mx;
    }
    __syncthreads();
    if (tid < 5) {
        float acc = clb[tid];
#pragma unroll
        for (int o = 0; o < 64; ++o) acc = fmaf(emb[o], clw[tid * 64 + o], acc);
        out[(size_t)b * 5 + tid] = acc;
    }
}

extern "C" void kernel_launch(void* const* d_in, const int* in_sizes, int n_in,
                              void* d_out, int out_size, void* d_ws, size_t ws_size,
                              hipStream_t stream)
{
    const float* x    = (const float*)d_in[0];
    const float* cw0  = (const float*)d_in[1];
    const float* cb0  = (const float*)d_in[2];
    const float* bng0 = (const float*)d_in[3];
    const float* bnb0 = (const float*)d_in[4];
    const float* bnm0 = (const float*)d_in[5];
    const float* bnv0 = (const float*)d_in[6];
    const float* cw1  = (const float*)d_in[7];
    const float* cb1  = (const float*)d_in[8];
    const float* bng1 = (const float*)d_in[9];
    const float* bnb1 = (const float*)d_in[10];
    const float* bnm1 = (const float*)d_in[11];
    const float* bnv1 = (const float*)d_in[12];
    const float* cw2  = (const float*)d_in[13];
    const float* cb2  = (const float*)d_in[14];
    const float* bng2 = (const float*)d_in[15];
    const float* bnb2 = (const float*)d_in[16];
    const float* bnm2 = (const float*)d_in[17];
    const float* bnv2 = (const float*)d_in[18];
    const float* wih0 = (const float*)d_in[19];
    const float* whh0 = (const float*)d_in[20];
    const float* bih0 = (const float*)d_in[21];
    const float* bhh0 = (const float*)d_in[22];
    const float* wih1 = (const float*)d_in[23];
    const float* whh1 = (const float*)d_in[24];
    const float* bih1 = (const float*)d_in[25];
    const float* bhh1 = (const float*)d_in[26];
    const float* gw0  = (const float*)d_in[27];
    const float* gb0  = (const float*)d_in[28];
    const float* gw1  = (const float*)d_in[29];
    const float* gb1  = (const float*)d_in[30];
    const float* gw2  = (const float*)d_in[31];
    const float* gb2  = (const float*)d_in[32];
    const float* clw  = (const float*)d_in[33];
    const float* clb  = (const float*)d_in[34];

    // ws layout (floats)
    float* xg0   = (float*)d_ws;            // (B,64,256) = 4194304
    float* xg1   = xg0 + 4194304;           // (B,64,256) = 4194304
    float* wt1   = xg1 + 4194304;           // 2560
    float* b1    = wt1 + 2560;              // 32
    float* wt2   = b1 + 32;                 // 10240
    float* b2    = wt2 + 10240;             // 64
    float* w0f   = b2 + 64;                 // 80
    float* b0f   = w0f + 80;                // 16
    float* wih0c = b0f + 16;                // 16384
    float* whh0c = wih0c + 16384;           // 16384
    float* wih1c = whh0c + 16384;           // 16384
    float* whh1c = wih1c + 16384;           // 16384

    prep_weights_kernel<<<64, 256, 0, stream>>>(
        cw0, cb0, bng0, bnb0, bnm0, bnv0,
        cw1, cb1, bng1, bnb1, bnm1, bnv1,
        cw2, cb2, bng2, bnb2, bnm2, bnv2,
        wih0, whh0, wih1, whh1,
        wt1, b1, wt2, b2, w0f, b0f,
        wih0c, whh0c, wih1c, whh1c);
    convall_kernel<<<dim3(32, 256), 256, 0, stream>>>(
        x, w0f, b0f, wt1, b1, wt2, b2, wih0c, bih0, bhh0, xg0);
    lstmgraph_kernel<<<256, 512, 0, stream>>>(
        xg0, xg1, whh0c, wih1c, whh1c, bih1, bhh1,
        gw0, gb0, gw1, gb1, gw2, gb2, clw, clb, (float*)d_out);
}

// Round 11
// 406.870 us; speedup vs baseline: 1.7472x; 1.1364x over previous
//
#include <hip/hip_runtime.h>
#include <math.h>

typedef __attribute__((ext_vector_type(2))) float v2f;

// ---------------- prep: BN-fold + transpose conv weights; transpose LSTM weights
// wXc[k4*1024 + r*4 + c] = wX[r*64 + k4*4 + c]  (coalesced per-row float4 loads)
__global__ __launch_bounds__(256) void prep_weights_kernel(
    const float* __restrict__ cw0, const float* __restrict__ cb0,
    const float* __restrict__ bng0, const float* __restrict__ bnb0,
    const float* __restrict__ bnm0, const float* __restrict__ bnv0,
    const float* __restrict__ cw1, const float* __restrict__ cb1,
    const float* __restrict__ bng1, const float* __restrict__ bnb1,
    const float* __restrict__ bnm1, const float* __restrict__ bnv1,
    const float* __restrict__ cw2, const float* __restrict__ cb2,
    const float* __restrict__ bng2, const float* __restrict__ bnb2,
    const float* __restrict__ bnm2, const float* __restrict__ bnv2,
    const float* __restrict__ wih0, const float* __restrict__ whh0,
    const float* __restrict__ wih1, const float* __restrict__ whh1,
    float* __restrict__ wt1, float* __restrict__ b1,
    float* __restrict__ wt2, float* __restrict__ b2,
    float* __restrict__ w0f, float* __restrict__ b0f,
    float* __restrict__ wih0c, float* __restrict__ whh0c,
    float* __restrict__ wih1c, float* __restrict__ whh1c)
{
    int g = blockIdx.x * 256 + threadIdx.x;
    const int GS = 64 * 256;
    for (int i = g; i < 2560; i += GS) {
        int co = i & 31, r = i >> 5, t = r % 5, ci = r / 5;
        float s = bng1[co] * rsqrtf(bnv1[co] + 1e-5f);
        wt1[i] = cw1[(co * 16 + ci) * 5 + t] * s;
    }
    if (g < 32) {
        float s = bng1[g] * rsqrtf(bnv1[g] + 1e-5f);
        b1[g] = (cb1[g] - bnm1[g]) * s + bnb1[g];
    }
    for (int i = g; i < 10240; i += GS) {
        int co = i & 63, r = i >> 6, t = r % 5, ci = r / 5;
        float s = bng2[co] * rsqrtf(bnv2[co] + 1e-5f);
        wt2[i] = cw2[(co * 32 + ci) * 5 + t] * s;
    }
    if (g < 64) {
        float s = bng2[g] * rsqrtf(bnv2[g] + 1e-5f);
        b2[g] = (cb2[g] - bnm2[g]) * s + bnb2[g];
    }
    if (g < 80) {
        int co = g / 5;
        float s = bng0[co] * rsqrtf(bnv0[co] + 1e-5f);
        w0f[g] = cw0[g] * s;
    }
    if (g < 16) {
        float s = bng0[g] * rsqrtf(bnv0[g] + 1e-5f);
        b0f[g] = (cb0[g] - bnm0[g]) * s + bnb0[g];
    }
    for (int i = g; i < 16384; i += GS) {
        int c = i & 3, r = (i >> 2) & 255, k4 = i >> 10;
        int src = r * 64 + k4 * 4 + c;
        wih0c[i] = wih0[src];
        whh0c[i] = whh0[src];
        wih1c[i] = wih1[src];
        whh1c[i] = whh1[src];
    }
}

// ---------------- fully fused CNN + LSTM layer-0 x-gates:
// x (B,1,15360) -> xg0 (B,64,256).  Identical to round 10 (bit-exact).
__global__ __launch_bounds__(256) void convall_kernel(
    const float* __restrict__ x,
    const float* __restrict__ w0f, const float* __restrict__ b0f,
    const float* __restrict__ wt1, const float* __restrict__ b1,
    const float* __restrict__ wt2, const float* __restrict__ b2,
    const float* __restrict__ wih0c,
    const float* __restrict__ bih0, const float* __restrict__ bhh0,
    float* __restrict__ xg0g)
{
    __shared__ float U[8096];
    float* raw = &U[4064];
    int b = blockIdx.y, bx = blockIdx.x, tid = threadIdx.x;
    const float* xb = x + (size_t)b * 15360;
    {
        int base = 480 * bx - 14;
        for (int i = tid; i < 508; i += 256) {
            int g = base + i;
            raw[i] = (g >= 0 && g < 15360) ? xb[g] : 0.f;
        }
    }
    __syncthreads();
    // ---- conv0 (+BN+ReLU+maxpool2)
    {
        int ci0 = tid >> 4, sub = tid & 15;
        float w0 = w0f[ci0*5+0], w1 = w0f[ci0*5+1], w2 = w0f[ci0*5+2],
              w3 = w0f[ci0*5+3], w4 = w0f[ci0*5+4];
        float bb = b0f[ci0];
        int r0g = 240 * bx - 6;
        for (int p = sub; p < 252; p += 16) {
            int r = r0g + p;
            float v = 0.f;
            if (r >= 0 && r < 7680) {
                int i0 = 2 * p;
                float c0 = raw[i0],   c1 = raw[i0+1], c2 = raw[i0+2],
                      c3 = raw[i0+3], c4 = raw[i0+4], c5 = raw[i0+5];
                float s0 = fmaf(w0,c0, fmaf(w1,c1, fmaf(w2,c2, fmaf(w3,c3, w4*c4))));
                float s1 = fmaf(w0,c1, fmaf(w1,c2, fmaf(w2,c3, fmaf(w3,c4, w4*c5))));
                v = fmaxf(fmaxf(s0, s1) + bb, 0.f);
            }
            U[ci0 * 254 + p] = v;
        }
    }
    __syncthreads();
    // ---- conv1 (+BN+ReLU+maxpool2)
    {
        int cg = tid >> 7, jj = tid & 127;
        int cgu = __builtin_amdgcn_readfirstlane(cg);
        if (tid < 64) { int co = tid >> 1, c = 124 + (tid & 1); U[4064 + co * 126 + c] = 0.f; }
        if (jj < 124) {
            const float* wb = wt1 + cgu * 16;
            v2f a0[8], a1[8];
#pragma unroll
            for (int q = 0; q < 8; ++q) { a0[q] = (v2f){0.f,0.f}; a1[q] = (v2f){0.f,0.f}; }
#pragma unroll 4
            for (int ci = 0; ci < 16; ++ci) {
                const float2* xr = reinterpret_cast<const float2*>(&U[ci * 254]);
                float2 xA = xr[jj], xB = xr[jj + 1], xC = xr[jj + 2];
                float xv[6] = { xA.x, xA.y, xB.x, xB.y, xC.x, xC.y };
#pragma unroll
                for (int t = 0; t < 5; ++t) {
                    const v2f* wp2 = reinterpret_cast<const v2f*>(wb + (ci * 5 + t) * 32);
                    v2f va = { xv[t], xv[t] };
                    v2f vc = { xv[t + 1], xv[t + 1] };
#pragma unroll
                    for (int q2 = 0; q2 < 8; ++q2) {
                        v2f w = wp2[q2];
                        a0[q2] = __builtin_elementwise_fma(w, va, a0[q2]);
                        a1[q2] = __builtin_elementwise_fma(w, vc, a1[q2]);
                    }
                }
            }
            int q = 120 * bx - 2 + jj;
            bool ok = (q >= 0 && q < 3840);
#pragma unroll
            for (int q2 = 0; q2 < 8; ++q2) {
#pragma unroll
                for (int cpp = 0; cpp < 2; ++cpp) {
                    int qq = 2 * q2 + cpp;
                    int co = cgu * 16 + qq;
                    float val = 0.f;
                    if (ok) val = fmaxf(fmaxf(a0[q2][cpp], a1[q2][cpp]) + b1[co], 0.f);
                    U[4064 + co * 126 + jj] = val;
                }
            }
        }
    }
    __syncthreads();
    // ---- conv2 (+BN+ReLU+maxpool2) + avgpool into xsl (LDS)
    {
        int cg = tid >> 6, jj = tid & 63;
        int jje = (jj < 59) ? jj : 59;
        int cgu = __builtin_amdgcn_readfirstlane(cg);
        const float* wb = wt2 + cgu * 16;
        v2f a0[8], a1[8];
#pragma unroll
        for (int q = 0; q < 8; ++q) { a0[q] = (v2f){0.f,0.f}; a1[q] = (v2f){0.f,0.f}; }
#pragma unroll 4
        for (int ci = 0; ci < 32; ++ci) {
            const float2* xr = reinterpret_cast<const float2*>(&U[4064 + ci * 126]);
            float2 xA = xr[jje], xB = xr[jje + 1], xC = xr[jje + 2];
            float xv[6] = { xA.x, xA.y, xB.x, xB.y, xC.x, xC.y };
#pragma unroll
            for (int t = 0; t < 5; ++t) {
                const v2f* wp2 = reinterpret_cast<const v2f*>(wb + (ci * 5 + t) * 64);
                v2f va = { xv[t], xv[t] };
                v2f vc = { xv[t + 1], xv[t + 1] };
#pragma unroll
                for (int q2 = 0; q2 < 8; ++q2) {
                    v2f w = wp2[q2];
                    a0[q2] = __builtin_elementwise_fma(w, va, a0[q2]);
                    a1[q2] = __builtin_elementwise_fma(w, vc, a1[q2]);
                }
            }
        }
        __syncthreads();     // xt0/xt1 dead; U[0..3904) becomes Y
        if (jj < 60) {
#pragma unroll
            for (int q2 = 0; q2 < 8; ++q2) {
#pragma unroll
                for (int cpp = 0; cpp < 2; ++cpp) {
                    int qq = 2 * q2 + cpp;
                    int co = cgu * 16 + qq;
                    float m = fmaxf(a0[q2][cpp], a1[q2][cpp]) + b2[co];
                    U[co * 61 + jj] = fmaxf(m, 0.f);
                }
            }
        }
    }
    __syncthreads();
    if (tid < 128) {
        int co = tid & 63, bin = tid >> 6;
        const float* r = U + co * 61 + bin * 30;
        float s = 0.f;
#pragma unroll
        for (int k = 0; k < 30; ++k) s += r[k];
        U[3904 + bin * 64 + co] = s * (1.f / 30.f);    // xsl[bin][co]
    }
    __syncthreads();
    // ---- LSTM layer-0 x-gates for this block's 2 timesteps (bit-exact phase A)
    {
        int r = tid;
        float bias0 = bih0[r] + bhh0[r];
        float wr0[64];
#pragma unroll
        for (int k4 = 0; k4 < 16; ++k4) {
            float4 w4 = reinterpret_cast<const float4*>(wih0c)[k4 * 256 + r];
            wr0[k4*4+0] = w4.x; wr0[k4*4+1] = w4.y;
            wr0[k4*4+2] = w4.z; wr0[k4*4+3] = w4.w;
        }
#pragma unroll
        for (int bin = 0; bin < 2; ++bin) {
            float s0 = bias0, s1 = 0.f, s2 = 0.f, s3 = 0.f;
#pragma unroll
            for (int k4 = 0; k4 < 16; ++k4) {
                float4 xv4 = *reinterpret_cast<const float4*>(&U[3904 + bin * 64 + k4 * 4]);
                s0 = fmaf(wr0[k4*4+0], xv4.x, s0);
                s1 = fmaf(wr0[k4*4+1], xv4.y, s1);
                s2 = fmaf(wr0[k4*4+2], xv4.z, s2);
                s3 = fmaf(wr0[k4*4+3], xv4.w, s3);
            }
            xg0g[((size_t)b * 64 + 2 * bx + bin) * 256 + r] = (s0 + s1) + (s2 + s3);
        }
    }
}

// ---------------- fused LSTM (layer-pipelined) + graph, 512 threads, 1 block/batch.
// Waves 0-3 (A): layer-0 recurrence.  Waves 4-7 (B): layer-1, lagging one step;
// xg1 computed in-register from xb (bit-identical to store/reload).
__global__ __launch_bounds__(512) void lstmgraph_kernel(
    const float* __restrict__ xg0g,
    const float* __restrict__ whh0c, const float* __restrict__ wih1c,
    const float* __restrict__ whh1c,
    const float* __restrict__ bih1, const float* __restrict__ bhh1,
    const float* __restrict__ gw0, const float* __restrict__ gb0,
    const float* __restrict__ gw1, const float* __restrict__ gb1,
    const float* __restrict__ gw2, const float* __restrict__ gb2,
    const float* __restrict__ clw, const float* __restrict__ clb,
    float* __restrict__ out)
{
    __shared__ float S[16384];
    float* H1   = S;                              // [64][64] layer-1 h (graph input)
    float (*xb)[64] = (float(*)[64])(S + 4096);   // [64][64] layer-0 h
    float* gbufA = S + 8192;                      // 256
    float* gbufB = S + 8448;                      // 256
    float* hbwA  = S + 8704;                      // [4][64]
    float* hbwB  = S + 8960;                      // [4][64]
    int b = blockIdx.x;
    int tid = threadIdx.x;
    int ln = tid & 63;
    int gate = (tid >> 6) & 3;        // gate type for both groups
    bool inA = (tid < 256);
    size_t base0 = (size_t)b * 16384;
    float wr[64];                     // whh row (own layer)
    float wi[64];                     // wih1 row (B only)
    float bias1 = 0.f;
    if (inA) {
#pragma unroll
        for (int k4 = 0; k4 < 16; ++k4) {
            float4 w4 = reinterpret_cast<const float4*>(whh0c)[k4 * 256 + tid];
            wr[k4*4+0] = w4.x; wr[k4*4+1] = w4.y;
            wr[k4*4+2] = w4.z; wr[k4*4+3] = w4.w;
        }
        hbwA[tid] = 0.f;
    } else {
        int r = tid - 256;
#pragma unroll
        for (int k4 = 0; k4 < 16; ++k4) {
            float4 w4 = reinterpret_cast<const float4*>(whh1c)[k4 * 256 + r];
            wr[k4*4+0] = w4.x; wr[k4*4+1] = w4.y;
            wr[k4*4+2] = w4.z; wr[k4*4+3] = w4.w;
            float4 v4 = reinterpret_cast<const float4*>(wih1c)[k4 * 256 + r];
            wi[k4*4+0] = v4.x; wi[k4*4+1] = v4.y;
            wi[k4*4+2] = v4.z; wi[k4*4+3] = v4.w;
        }
        bias1 = bih1[r] + bhh1[r];
        hbwB[r] = 0.f;
    }
    float c = 0.f;
    float xgA = 0.f, xgN = 0.f;
    if (inA) {
        xgA = xg0g[base0 + tid];
        xgN = xg0g[base0 + 256 + tid];
    }
    for (int s = 0; s <= 64; ++s) {
        float xgP = 0.f;
        float a = 0.f;
        if (inA) {
            if (s + 2 < 64) xgP = xg0g[base0 + (size_t)(s + 2) * 256 + tid];
            if (s < 64) {
                float s0 = xgA, s1 = 0.f, s2 = 0.f, s3 = 0.f;
#pragma unroll
                for (int k4 = 0; k4 < 16; ++k4) {
                    float4 hv4 = *reinterpret_cast<const float4*>(&hbwA[gate * 0 + (tid >> 6) * 64 + k4 * 4]);
                    s0 = fmaf(wr[k4*4+0], hv4.x, s0);
                    s1 = fmaf(wr[k4*4+1], hv4.y, s1);
                    s2 = fmaf(wr[k4*4+2], hv4.z, s2);
                    s3 = fmaf(wr[k4*4+3], hv4.w, s3);
                }
                float acc = (s0 + s1) + (s2 + s3);
                if (gate == 2) a = tanhf(acc);
                else           a = 1.f / (1.f + __expf(-acc));
                gbufA[tid] = a;
            }
        } else {
            if (s >= 1) {
                int t = s - 1;
                // xg1(t) in-register (bit-identical to old phase-A + reload)
                float s0 = bias1, s1 = 0.f, s2 = 0.f, s3 = 0.f;
#pragma unroll
                for (int k4 = 0; k4 < 16; ++k4) {
                    float4 xv4 = *reinterpret_cast<const float4*>(&xb[t][k4 * 4]);
                    s0 = fmaf(wi[k4*4+0], xv4.x, s0);
                    s1 = fmaf(wi[k4*4+1], xv4.y, s1);
                    s2 = fmaf(wi[k4*4+2], xv4.z, s2);
                    s3 = fmaf(wi[k4*4+3], xv4.w, s3);
                }
                float xg1 = (s0 + s1) + (s2 + s3);
                // layer-1 gate dot
                s0 = xg1; s1 = 0.f; s2 = 0.f; s3 = 0.f;
#pragma unroll
                for (int k4 = 0; k4 < 16; ++k4) {
                    float4 hv4 = *reinterpret_cast<const float4*>(&hbwB[gate * 64 + k4 * 4]);
                    s0 = fmaf(wr[k4*4+0], hv4.x, s0);
                    s1 = fmaf(wr[k4*4+1], hv4.y, s1);
                    s2 = fmaf(wr[k4*4+2], hv4.z, s2);
                    s3 = fmaf(wr[k4*4+3], hv4.w, s3);
                }
                float acc = (s0 + s1) + (s2 + s3);
                if (gate == 2) a = tanhf(acc);
                else           a = 1.f / (1.f + __expf(-acc));
                gbufB[tid - 256] = a;
            }
        }
        __syncthreads();   // barrier 1: gbuf writes -> reads
        if (inA) {
            if (s < 64) {
                float gi = gbufA[ln], gf = gbufA[64 + ln],
                      gg = gbufA[128 + ln], go = gbufA[192 + ln];
                c = fmaf(gf, c, gi * gg);
                float h = go * tanhf(c);
                hbwA[(tid >> 6) * 64 + ln] = h;
                if (tid < 64) xb[s][ln] = h;
            }
        } else {
            if (s >= 1) {
                int t = s - 1;
                float gi = gbufB[ln], gf = gbufB[64 + ln],
                      gg = gbufB[128 + ln], go = gbufB[192 + ln];
                c = fmaf(gf, c, gi * gg);
                float h = go * tanhf(c);
                hbwB[gate * 64 + ln] = h;
                if (tid < 320) H1[t * 64 + ln] = h;   // wave 4 writes layer-1 h
            }
        }
        __syncthreads();   // barrier 2: xb[s]/gbuf reuse safe for next iter
        xgA = xgN; xgN = xgP;
    }
    // ---------------- graph phase (xb/gbuf/hbw dead; G overlays S+4096)
    float* G    = S + 4096;
    float* nf   = G;            // 16 x 257
    float* sb   = G + 4112;     // 16 x 257
    float* red  = G + 8224;     // 16 x 17
    float* mean = G + 8496;     // 16
    float* rstd = G + 8512;     // 16
    float* C    = G + 8528;     // 256
    float* adj  = G + 8784;     // 256
    float* thrv = G + 9040;     // 1 (+pad)
    float* bufA = G + 9044;     // 16 x 65
    float* bufB = G + 10084;    // 16 x 65
    float* bufC = G + 11124;    // 16 x 65
    float* emb  = G + 12164;    // 64
    for (int i = tid; i < 4096; i += 512) {
        int n = i >> 8, f = i & 255;
        nf[n * 257 + f] = H1[(4 * n + (f >> 6)) * 64 + (f & 63)];
    }
    __syncthreads();
    int nd = (tid >> 4) & 15, sub = tid & 15;
    if (tid < 256) {
        float s = 0.f;
        for (int f = sub; f < 256; f += 16) s += nf[nd * 257 + f];
        red[nd * 17 + sub] = s;
    }
    __syncthreads();
    if (tid < 16) {
        float m = 0.f;
        for (int i = 0; i < 16; ++i) m += red[tid * 17 + i];
        mean[tid] = m * (1.f / 256.f);
    }
    __syncthreads();
    if (tid < 256) {
        float mu = mean[nd];
        float ss = 0.f;
        for (int f = sub; f < 256; f += 16) { float d = nf[nd * 257 + f] - mu; ss = fmaf(d, d, ss); }
        red[nd * 17 + sub] = ss;
    }
    __syncthreads();
    if (tid < 16) {
        float m = 0.f;
        for (int i = 0; i < 16; ++i) m += red[tid * 17 + i];
        rstd[tid] = 1.f / (sqrtf(m * (1.f / 255.f)) + 1e-8f);
    }
    __syncthreads();
    for (int i = tid; i < 4096; i += 512) {
        int n = i >> 8, f = i & 255;
        sb[n * 257 + f] = (nf[n * 257 + f] - mean[n]) * rstd[n];
    }
    __syncthreads();
    if (tid < 256) {
        int n = tid >> 4, m = tid & 15;
        float a0 = 0, a1 = 0, a2 = 0, a3 = 0;
        for (int f = 0; f < 256; f += 4) {
            a0 = fmaf(sb[n * 257 + f + 0], sb[m * 257 + f + 0], a0);
            a1 = fmaf(sb[n * 257 + f + 1], sb[m * 257 + f + 1], a1);
            a2 = fmaf(sb[n * 257 + f + 2], sb[m * 257 + f + 2], a2);
            a3 = fmaf(sb[n * 257 + f + 3], sb[m * 257 + f + 3], a3);
        }
        C[tid] = ((a0 + a1) + (a2 + a3)) * (1.f / 256.f);
    }
    __syncthreads();
    if (tid < 256) {
        float v = C[tid];
        int cnt = 0, eq = 0;
        for (int j2 = 0; j2 < 256; ++j2) {
            float vj = C[j2];
            cnt += (vj < v);
            eq  += (vj == v);
        }
        if (cnt <= 191 && 191 < cnt + eq) thrv[0] = v;
    }
    __syncthreads();
    if (tid < 256) {
        int n = tid >> 4, m = tid & 15;
        adj[tid] = (C[tid] > thrv[0] && n != m) ? 1.f : 0.f;
    }
    __syncthreads();
    for (int i = tid; i < 4096; i += 512) {
        int n = i >> 8, f = i & 255;
        float acc = nf[n * 257 + f];
#pragma unroll
        for (int m = 0; m < 16; ++m) acc = fmaf(adj[n * 16 + m], nf[m * 257 + f], acc);
        sb[n * 257 + f] = acc;
    }
    __syncthreads();
    for (int i = tid; i < 1024; i += 512) {
        int n = i >> 6, o = i & 63;
        const float4* wr4 = reinterpret_cast<const float4*>(gw0 + (size_t)o * 256);
        float acc = gb0[o];
        for (int f4 = 0; f4 < 64; ++f4) {
            float4 wv4 = wr4[f4];
            int f = f4 * 4;
            acc = fmaf(sb[n * 257 + f + 0], wv4.x, acc);
            acc = fmaf(sb[n * 257 + f + 1], wv4.y, acc);
            acc = fmaf(sb[n * 257 + f + 2], wv4.z, acc);
            acc = fmaf(sb[n * 257 + f + 3], wv4.w, acc);
        }
        bufA[n * 65 + o] = fmaxf(acc, 0.f);
    }
    __syncthreads();
    for (int i = tid; i < 1024; i += 512) {
        int n = i >> 6, f = i & 63;
        float acc = bufA[n * 65 + f];
#pragma unroll
        for (int m = 0; m < 16; ++m) acc = fmaf(adj[n * 16 + m], bufA[m * 65 + f], acc);
        bufB[n * 65 + f] = acc;
    }
    __syncthreads();
    for (int i = tid; i < 1024; i += 512) {
        int n = i >> 6, o = i & 63;
        const float4* wr4 = reinterpret_cast<const float4*>(gw1 + (size_t)o * 64);
        float acc = gb1[o];
        for (int f4 = 0; f4 < 16; ++f4) {
            float4 wv4 = wr4[f4];
            int f = f4 * 4;
            acc = fmaf(bufB[n * 65 + f + 0], wv4.x, acc);
            acc = fmaf(bufB[n * 65 + f + 1], wv4.y, acc);
            acc = fmaf(bufB[n * 65 + f + 2], wv4.z, acc);
            acc = fmaf(bufB[n * 65 + f + 3], wv4.w, acc);
        }
        bufC[n * 65 + o] = fmaxf(acc, 0.f);
    }
    __syncthreads();
    for (int i = tid; i < 1024; i += 512) {
        int n = i >> 6, f = i & 63;
        float acc = bufC[n * 65 + f];
#pragma unroll
        for (int m = 0; m < 16; ++m) acc = fmaf(adj[n * 16 + m], bufC[m * 65 + f], acc);
        bufA[n * 65 + f] = acc;
    }
    __syncthreads();
    for (int i = tid; i < 1024; i += 512) {
        int n = i >> 6, o = i & 63;
        const float4* wr4 = reinterpret_cast<const float4*>(gw2 + (size_t)o * 64);
        float acc = gb2[o];
        for (int f4 = 0; f4 < 16; ++f4) {
            float4 wv4 = wr4[f4];
            int f = f4 * 4;
            acc = fmaf(bufA[n * 65 + f + 0], wv4.x, acc);
            acc = fmaf(bufA[n * 65 + f + 1], wv4.y, acc);
            acc = fmaf(bufA[n * 65 + f + 2], wv4.z, acc);
            acc = fmaf(bufA[n * 65 + f + 3], wv4.w, acc);
        }
        bufB[n * 65 + o] = fmaxf(acc, 0.f);
    }
    __syncthreads();
    if (tid < 64) {
        float mx = bufB[tid];
#pragma unroll
        for (int n = 1; n < 16; ++n) mx = fmaxf(mx, bufB[n * 65 + tid]);
        emb[tid] = mx;
    }
    __syncthreads();
    if (tid < 5) {
        float acc = clb[tid];
#pragma unroll
        for (int o = 0; o < 64; ++o) acc = fmaf(emb[o], clw[tid * 64 + o], acc);
        out[(size_t)b * 5 + tid] = acc;
    }
}

extern "C" void kernel_launch(void* const* d_in, const int* in_sizes, int n_in,
                              void* d_out, int out_size, void* d_ws, size_t ws_size,
                              hipStream_t stream)
{
    const float* x    = (const float*)d_in[0];
    const float* cw0  = (const float*)d_in[1];
    const float* cb0  = (const float*)d_in[2];
    const float* bng0 = (const float*)d_in[3];
    const float* bnb0 = (const float*)d_in[4];
    const float* bnm0 = (const float*)d_in[5];
    const float* bnv0 = (const float*)d_in[6];
    const float* cw1  = (const float*)d_in[7];
    const float* cb1  = (const float*)d_in[8];
    const float* bng1 = (const float*)d_in[9];
    const float* bnb1 = (const float*)d_in[10];
    const float* bnm1 = (const float*)d_in[11];
    const float* bnv1 = (const float*)d_in[12];
    const float* cw2  = (const float*)d_in[13];
    const float* cb2  = (const float*)d_in[14];
    const float* bng2 = (const float*)d_in[15];
    const float* bnb2 = (const float*)d_in[16];
    const float* bnm2 = (const float*)d_in[17];
    const float* bnv2 = (const float*)d_in[18];
    const float* wih0 = (const float*)d_in[19];
    const float* whh0 = (const float*)d_in[20];
    const float* bih0 = (const float*)d_in[21];
    const float* bhh0 = (const float*)d_in[22];
    const float* wih1 = (const float*)d_in[23];
    const float* whh1 = (const float*)d_in[24];
    const float* bih1 = (const float*)d_in[25];
    const float* bhh1 = (const float*)d_in[26];
    const float* gw0  = (const float*)d_in[27];
    const float* gb0  = (const float*)d_in[28];
    const float* gw1  = (const float*)d_in[29];
    const float* gb1  = (const float*)d_in[30];
    const float* gw2  = (const float*)d_in[31];
    const float* gb2  = (const float*)d_in[32];
    const float* clw  = (const float*)d_in[33];
    const float* clb  = (const float*)d_in[34];

    // ws layout (floats)
    float* xg0   = (float*)d_ws;            // (B,64,256) = 4194304
    float* wt1   = xg0 + 4194304;           // 2560
    float* b1    = wt1 + 2560;              // 32
    float* wt2   = b1 + 32;                 // 10240
    float* b2    = wt2 + 10240;             // 64
    float* w0f   = b2 + 64;                 // 80
    float* b0f   = w0f + 80;                // 16
    float* wih0c = b0f + 16;                // 16384
    float* whh0c = wih0c + 16384;           // 16384
    float* wih1c = whh0c + 16384;           // 16384
    float* whh1c = wih1c + 16384;           // 16384

    prep_weights_kernel<<<64, 256, 0, stream>>>(
        cw0, cb0, bng0, bnb0, bnm0, bnv0,
        cw1, cb1, bng1, bnb1, bnm1, bnv1,
        cw2, cb2, bng2, bnb2, bnm2, bnv2,
        wih0, whh0, wih1, whh1,
        wt1, b1, wt2, b2, w0f, b0f,
        wih0c, whh0c, wih1c, whh1c);
    convall_kernel<<<dim3(32, 256), 256, 0, stream>>>(
        x, w0f, b0f, wt1, b1, wt2, b2, wih0c, bih0, bhh0, xg0);
    lstmgraph_kernel<<<256, 512, 0, stream>>>(
        xg0, whh0c, wih1c, whh1c, bih1, bhh1,
        gw0, gb0, gw1, gb1, gw2, gb2, clw, clb, (float*)d_out);
}

// Round 12
// 401.909 us; speedup vs baseline: 1.7688x; 1.0123x over previous
//
#include <hip/hip_runtime.h>
#include <math.h>

typedef __attribute__((ext_vector_type(2))) float v2f;

// ---------------- prep: BN-fold + transpose conv weights; transpose LSTM weights
__global__ __launch_bounds__(256) void prep_weights_kernel(
    const float* __restrict__ cw0, const float* __restrict__ cb0,
    const float* __restrict__ bng0, const float* __restrict__ bnb0,
    const float* __restrict__ bnm0, const float* __restrict__ bnv0,
    const float* __restrict__ cw1, const float* __restrict__ cb1,
    const float* __restrict__ bng1, const float* __restrict__ bnb1,
    const float* __restrict__ bnm1, const float* __restrict__ bnv1,
    const float* __restrict__ cw2, const float* __restrict__ cb2,
    const float* __restrict__ bng2, const float* __restrict__ bnb2,
    const float* __restrict__ bnm2, const float* __restrict__ bnv2,
    const float* __restrict__ wih0, const float* __restrict__ whh0,
    const float* __restrict__ wih1, const float* __restrict__ whh1,
    float* __restrict__ wt1, float* __restrict__ b1,
    float* __restrict__ wt2, float* __restrict__ b2,
    float* __restrict__ w0f, float* __restrict__ b0f,
    float* __restrict__ wih0c, float* __restrict__ whh0c,
    float* __restrict__ wih1c, float* __restrict__ whh1c)
{
    int g = blockIdx.x * 256 + threadIdx.x;
    const int GS = 64 * 256;
    for (int i = g; i < 2560; i += GS) {
        int co = i & 31, r = i >> 5, t = r % 5, ci = r / 5;
        float s = bng1[co] * rsqrtf(bnv1[co] + 1e-5f);
        wt1[i] = cw1[(co * 16 + ci) * 5 + t] * s;
    }
    if (g < 32) {
        float s = bng1[g] * rsqrtf(bnv1[g] + 1e-5f);
        b1[g] = (cb1[g] - bnm1[g]) * s + bnb1[g];
    }
    for (int i = g; i < 10240; i += GS) {
        int co = i & 63, r = i >> 6, t = r % 5, ci = r / 5;
        float s = bng2[co] * rsqrtf(bnv2[co] + 1e-5f);
        wt2[i] = cw2[(co * 32 + ci) * 5 + t] * s;
    }
    if (g < 64) {
        float s = bng2[g] * rsqrtf(bnv2[g] + 1e-5f);
        b2[g] = (cb2[g] - bnm2[g]) * s + bnb2[g];
    }
    if (g < 80) {
        int co = g / 5;
        float s = bng0[co] * rsqrtf(bnv0[co] + 1e-5f);
        w0f[g] = cw0[g] * s;
    }
    if (g < 16) {
        float s = bng0[g] * rsqrtf(bnv0[g] + 1e-5f);
        b0f[g] = (cb0[g] - bnm0[g]) * s + bnb0[g];
    }
    for (int i = g; i < 16384; i += GS) {
        int c = i & 3, r = (i >> 2) & 255, k4 = i >> 10;
        int src = r * 64 + k4 * 4 + c;
        wih0c[i] = wih0[src];
        whh0c[i] = whh0[src];
        wih1c[i] = wih1[src];
        whh1c[i] = whh1[src];
    }
}

// ---------------- fully fused CNN + LSTM layer-0 x-gates: x -> xg0 (B,64,256)
// LDS = 8000 floats = 32000 B (<= 32 KiB granule) -> 5 blocks/CU.
//   xt0: U[ci0*252], 16 rows (writes/reads 0..251)
//   xt1: U[4032 + ci*124], 32 rows (writes 0..123, reads <= 123)
//   raw: U[4032..4540) overlay (dead before conv1 writes xt1)
//   Y  : U[co*61] (xt0 region); xsl: U[3904..4032)
// All accumulation chains identical to round 11 -> bit-identical.
__global__ __launch_bounds__(256) void convall_kernel(
    const float* __restrict__ x,
    const float* __restrict__ w0f, const float* __restrict__ b0f,
    const float* __restrict__ wt1, const float* __restrict__ b1,
    const float* __restrict__ wt2, const float* __restrict__ b2,
    const float* __restrict__ wih0c,
    const float* __restrict__ bih0, const float* __restrict__ bhh0,
    float* __restrict__ xg0g)
{
    __shared__ float U[8000];
    float* raw = &U[4032];
    int b = blockIdx.y, bx = blockIdx.x, tid = threadIdx.x;
    const float* xb = x + (size_t)b * 15360;
    {
        int base = 480 * bx - 14;
        for (int i = tid; i < 508; i += 256) {
            int g = base + i;
            raw[i] = (g >= 0 && g < 15360) ? xb[g] : 0.f;
        }
    }
    __syncthreads();
    // ---- conv0 (+BN+ReLU+maxpool2)
    {
        int ci0 = tid >> 4, sub = tid & 15;
        float w0 = w0f[ci0*5+0], w1 = w0f[ci0*5+1], w2 = w0f[ci0*5+2],
              w3 = w0f[ci0*5+3], w4 = w0f[ci0*5+4];
        float bb = b0f[ci0];
        int r0g = 240 * bx - 6;
        for (int p = sub; p < 252; p += 16) {
            int r = r0g + p;
            float v = 0.f;
            if (r >= 0 && r < 7680) {
                int i0 = 2 * p;
                float c0 = raw[i0],   c1 = raw[i0+1], c2 = raw[i0+2],
                      c3 = raw[i0+3], c4 = raw[i0+4], c5 = raw[i0+5];
                float s0 = fmaf(w0,c0, fmaf(w1,c1, fmaf(w2,c2, fmaf(w3,c3, w4*c4))));
                float s1 = fmaf(w0,c1, fmaf(w1,c2, fmaf(w2,c3, fmaf(w3,c4, w4*c5))));
                v = fmaxf(fmaxf(s0, s1) + bb, 0.f);
            }
            U[ci0 * 252 + p] = v;
        }
    }
    __syncthreads();
    // ---- conv1 (+BN+ReLU+maxpool2): 124 pooled values per co (raw now dead)
    {
        int cg = tid >> 7, jj = tid & 127;
        int cgu = __builtin_amdgcn_readfirstlane(cg);
        if (jj < 124) {
            const float* wb = wt1 + cgu * 16;
            v2f a0[8], a1[8];
#pragma unroll
            for (int q = 0; q < 8; ++q) { a0[q] = (v2f){0.f,0.f}; a1[q] = (v2f){0.f,0.f}; }
#pragma unroll 4
            for (int ci = 0; ci < 16; ++ci) {
                const float2* xr = reinterpret_cast<const float2*>(&U[ci * 252]);
                float2 xA = xr[jj], xB = xr[jj + 1], xC = xr[jj + 2];
                float xv[6] = { xA.x, xA.y, xB.x, xB.y, xC.x, xC.y };
#pragma unroll
                for (int t = 0; t < 5; ++t) {
                    const v2f* wp2 = reinterpret_cast<const v2f*>(wb + (ci * 5 + t) * 32);
                    v2f va = { xv[t], xv[t] };
                    v2f vc = { xv[t + 1], xv[t + 1] };
#pragma unroll
                    for (int q2 = 0; q2 < 8; ++q2) {
                        v2f w = wp2[q2];
                        a0[q2] = __builtin_elementwise_fma(w, va, a0[q2]);
                        a1[q2] = __builtin_elementwise_fma(w, vc, a1[q2]);
                    }
                }
            }
            int q = 120 * bx - 2 + jj;
            bool ok = (q >= 0 && q < 3840);
#pragma unroll
            for (int q2 = 0; q2 < 8; ++q2) {
#pragma unroll
                for (int cpp = 0; cpp < 2; ++cpp) {
                    int qq = 2 * q2 + cpp;
                    int co = cgu * 16 + qq;
                    float val = 0.f;
                    if (ok) val = fmaxf(fmaxf(a0[q2][cpp], a1[q2][cpp]) + b1[co], 0.f);
                    U[4032 + co * 124 + jj] = val;
                }
            }
        }
    }
    __syncthreads();
    // ---- conv2 (+BN+ReLU+maxpool2) + avgpool into xsl (LDS)
    {
        int cg = tid >> 6, jj = tid & 63;
        int jje = (jj < 59) ? jj : 59;
        int cgu = __builtin_amdgcn_readfirstlane(cg);
        const float* wb = wt2 + cgu * 16;
        v2f a0[8], a1[8];
#pragma unroll
        for (int q = 0; q < 8; ++q) { a0[q] = (v2f){0.f,0.f}; a1[q] = (v2f){0.f,0.f}; }
#pragma unroll 4
        for (int ci = 0; ci < 32; ++ci) {
            const float2* xr = reinterpret_cast<const float2*>(&U[4032 + ci * 124]);
            float2 xA = xr[jje], xB = xr[jje + 1], xC = xr[jje + 2];
            float xv[6] = { xA.x, xA.y, xB.x, xB.y, xC.x, xC.y };
#pragma unroll
            for (int t = 0; t < 5; ++t) {
                const v2f* wp2 = reinterpret_cast<const v2f*>(wb + (ci * 5 + t) * 64);
                v2f va = { xv[t], xv[t] };
                v2f vc = { xv[t + 1], xv[t + 1] };
#pragma unroll
                for (int q2 = 0; q2 < 8; ++q2) {
                    v2f w = wp2[q2];
                    a0[q2] = __builtin_elementwise_fma(w, va, a0[q2]);
                    a1[q2] = __builtin_elementwise_fma(w, vc, a1[q2]);
                }
            }
        }
        __syncthreads();     // xt0/xt1 dead; U[0..3904) becomes Y
        if (jj < 60) {
#pragma unroll
            for (int q2 = 0; q2 < 8; ++q2) {
#pragma unroll
                for (int cpp = 0; cpp < 2; ++cpp) {
                    int qq = 2 * q2 + cpp;
                    int co = cgu * 16 + qq;
                    float m = fmaxf(a0[q2][cpp], a1[q2][cpp]) + b2[co];
                    U[co * 61 + jj] = fmaxf(m, 0.f);
                }
            }
        }
    }
    __syncthreads();
    if (tid < 128) {
        int co = tid & 63, bin = tid >> 6;
        const float* r = U + co * 61 + bin * 30;
        float s = 0.f;
#pragma unroll
        for (int k = 0; k < 30; ++k) s += r[k];
        U[3904 + bin * 64 + co] = s * (1.f / 30.f);    // xsl[bin][co]
    }
    __syncthreads();
    // ---- LSTM layer-0 x-gates for this block's 2 timesteps (bit-exact phase A)
    {
        int r = tid;
        float bias0 = bih0[r] + bhh0[r];
        float wr0[64];
#pragma unroll
        for (int k4 = 0; k4 < 16; ++k4) {
            float4 w4 = reinterpret_cast<const float4*>(wih0c)[k4 * 256 + r];
            wr0[k4*4+0] = w4.x; wr0[k4*4+1] = w4.y;
            wr0[k4*4+2] = w4.z; wr0[k4*4+3] = w4.w;
        }
#pragma unroll
        for (int bin = 0; bin < 2; ++bin) {
            float s0 = bias0, s1 = 0.f, s2 = 0.f, s3 = 0.f;
#pragma unroll
            for (int k4 = 0; k4 < 16; ++k4) {
                float4 xv4 = *reinterpret_cast<const float4*>(&U[3904 + bin * 64 + k4 * 4]);
                s0 = fmaf(wr0[k4*4+0], xv4.x, s0);
                s1 = fmaf(wr0[k4*4+1], xv4.y, s1);
                s2 = fmaf(wr0[k4*4+2], xv4.z, s2);
                s3 = fmaf(wr0[k4*4+3], xv4.w, s3);
            }
            xg0g[((size_t)b * 64 + 2 * bx + bin) * 256 + r] = (s0 + s1) + (s2 + s3);
        }
    }
}

// ---------------- fused LSTM (lag-2 layer pipeline, 1 barrier/iter) + graph.
// Waves 0-3 (A): layer-0 step s.  Waves 4-7 (B): layer-1 step t = s-2.
// xb[t] write (post-bar, iter t) -> B read (pre-bar, iter t+2): separated by
// barrier of iter t+1.  Gate buffers parity-indexed (s&1): reuse separated by
// one barrier.  h-copies are wave-private.  All dot orders = round 11.
__global__ __launch_bounds__(512) void lstmgraph_kernel(
    const float* __restrict__ xg0g,
    const float* __restrict__ whh0c, const float* __restrict__ wih1c,
    const float* __restrict__ whh1c,
    const float* __restrict__ bih1, const float* __restrict__ bhh1,
    const float* __restrict__ gw0, const float* __restrict__ gb0,
    const float* __restrict__ gw1, const float* __restrict__ gb1,
    const float* __restrict__ gw2, const float* __restrict__ gb2,
    const float* __restrict__ clw, const float* __restrict__ clb,
    float* __restrict__ out)
{
    __shared__ float S[16384];
    float* H1    = S;                              // [64][64] layer-1 h
    float (*xb)[64] = (float(*)[64])(S + 4096);    // [64][64] layer-0 h
    float* gbufA = S + 8192;                       // [2][256]
    float* gbufB = S + 8704;                       // [2][256]
    float* hbwA  = S + 9216;                       // [4][64]
    float* hbwB  = S + 9472;                       // [4][64]
    int b = blockIdx.x;
    int tid = threadIdx.x;
    int ln = tid & 63;
    int gate = (tid >> 6) & 3;
    bool inA = (tid < 256);
    size_t base0 = (size_t)b * 16384;
    float wr[64];
    float wi[64];
    float bias1 = 0.f;
    if (inA) {
#pragma unroll
        for (int k4 = 0; k4 < 16; ++k4) {
            float4 w4 = reinterpret_cast<const float4*>(whh0c)[k4 * 256 + tid];
            wr[k4*4+0] = w4.x; wr[k4*4+1] = w4.y;
            wr[k4*4+2] = w4.z; wr[k4*4+3] = w4.w;
        }
        hbwA[tid] = 0.f;
    } else {
        int r = tid - 256;
#pragma unroll
        for (int k4 = 0; k4 < 16; ++k4) {
            float4 w4 = reinterpret_cast<const float4*>(whh1c)[k4 * 256 + r];
            wr[k4*4+0] = w4.x; wr[k4*4+1] = w4.y;
            wr[k4*4+2] = w4.z; wr[k4*4+3] = w4.w;
            float4 v4 = reinterpret_cast<const float4*>(wih1c)[k4 * 256 + r];
            wi[k4*4+0] = v4.x; wi[k4*4+1] = v4.y;
            wi[k4*4+2] = v4.z; wi[k4*4+3] = v4.w;
        }
        bias1 = bih1[r] + bhh1[r];
        hbwB[r] = 0.f;
    }
    float c = 0.f;
    float xgA = 0.f, xgN = 0.f;
    if (inA) {
        xgA = xg0g[base0 + tid];
        xgN = xg0g[base0 + 256 + tid];
    }
    for (int s = 0; s <= 65; ++s) {
        float xgP = 0.f;
        if (inA) {
            if (s + 2 < 64) xgP = xg0g[base0 + (size_t)(s + 2) * 256 + tid];
            if (s < 64) {
                float s0 = xgA, s1 = 0.f, s2 = 0.f, s3 = 0.f;
#pragma unroll
                for (int k4 = 0; k4 < 16; ++k4) {
                    float4 hv4 = *reinterpret_cast<const float4*>(&hbwA[(tid >> 6) * 64 + k4 * 4]);
                    s0 = fmaf(wr[k4*4+0], hv4.x, s0);
                    s1 = fmaf(wr[k4*4+1], hv4.y, s1);
                    s2 = fmaf(wr[k4*4+2], hv4.z, s2);
                    s3 = fmaf(wr[k4*4+3], hv4.w, s3);
                }
                float acc = (s0 + s1) + (s2 + s3);
                float a;
                if (gate == 2) a = tanhf(acc);
                else           a = 1.f / (1.f + __expf(-acc));
                gbufA[(s & 1) * 256 + tid] = a;
            }
        } else {
            if (s >= 2) {
                int t = s - 2;
                float s0 = bias1, s1 = 0.f, s2 = 0.f, s3 = 0.f;
#pragma unroll
                for (int k4 = 0; k4 < 16; ++k4) {
                    float4 xv4 = *reinterpret_cast<const float4*>(&xb[t][k4 * 4]);
                    s0 = fmaf(wi[k4*4+0], xv4.x, s0);
                    s1 = fmaf(wi[k4*4+1], xv4.y, s1);
                    s2 = fmaf(wi[k4*4+2], xv4.z, s2);
                    s3 = fmaf(wi[k4*4+3], xv4.w, s3);
                }
                float xg1 = (s0 + s1) + (s2 + s3);
                s0 = xg1; s1 = 0.f; s2 = 0.f; s3 = 0.f;
#pragma unroll
                for (int k4 = 0; k4 < 16; ++k4) {
                    float4 hv4 = *reinterpret_cast<const float4*>(&hbwB[gate * 64 + k4 * 4]);
                    s0 = fmaf(wr[k4*4+0], hv4.x, s0);
                    s1 = fmaf(wr[k4*4+1], hv4.y, s1);
                    s2 = fmaf(wr[k4*4+2], hv4.z, s2);
                    s3 = fmaf(wr[k4*4+3], hv4.w, s3);
                }
                float acc = (s0 + s1) + (s2 + s3);
                float a;
                if (gate == 2) a = tanhf(acc);
                else           a = 1.f / (1.f + __expf(-acc));
                gbufB[(s & 1) * 256 + (tid - 256)] = a;
            }
        }
        __syncthreads();   // the single barrier per iteration
        if (inA) {
            if (s < 64) {
                int par = (s & 1) * 256;
                float gi = gbufA[par + ln], gf = gbufA[par + 64 + ln],
                      gg = gbufA[par + 128 + ln], go = gbufA[par + 192 + ln];
                c = fmaf(gf, c, gi * gg);
                float h = go * tanhf(c);
                hbwA[(tid >> 6) * 64 + ln] = h;
                if (tid < 64) xb[s][ln] = h;
            }
        } else {
            if (s >= 2) {
                int t = s - 2;
                int par = (s & 1) * 256;
                float gi = gbufB[par + ln], gf = gbufB[par + 64 + ln],
                      gg = gbufB[par + 128 + ln], go = gbufB[par + 192 + ln];
                c = fmaf(gf, c, gi * gg);
                float h = go * tanhf(c);
                hbwB[gate * 64 + ln] = h;
                if (tid < 320) H1[t * 64 + ln] = h;
            }
        }
        xgA = xgN; xgN = xgP;
    }
    __syncthreads();
    // ---------------- graph phase (xb/gbuf/hbw dead; G overlays S+4096)
    float* G    = S + 4096;
    float* nf   = G;            // 16 x 257
    float* sb   = G + 4112;     // 16 x 257
    float* red  = G + 8224;     // 16 x 17
    float* mean = G + 8496;     // 16
    float* rstd = G + 8512;     // 16
    float* C    = G + 8528;     // 256
    float* adj  = G + 8784;     // 256
    float* thrv = G + 9040;     // 1 (+pad)
    float* bufA = G + 9044;     // 16 x 65
    float* bufB = G + 10084;    // 16 x 65
    float* bufC = G + 11124;    // 16 x 65
    float* emb  = G + 12164;    // 64
    for (int i = tid; i < 4096; i += 512) {
        int n = i >> 8, f = i & 255;
        nf[n * 257 + f] = H1[(4 * n + (f >> 6)) * 64 + (f & 63)];
    }
    __syncthreads();
    int nd = (tid >> 4) & 15, sub = tid & 15;
    if (tid < 256) {
        float s = 0.f;
        for (int f = sub; f < 256; f += 16) s += nf[nd * 257 + f];
        red[nd * 17 + sub] = s;
    }
    __syncthreads();
    if (tid < 16) {
        float m = 0.f;
        for (int i = 0; i < 16; ++i) m += red[tid * 17 + i];
        mean[tid] = m * (1.f / 256.f);
    }
    __syncthreads();
    if (tid < 256) {
        float mu = mean[nd];
        float ss = 0.f;
        for (int f = sub; f < 256; f += 16) { float d = nf[nd * 257 + f] - mu; ss = fmaf(d, d, ss); }
        red[nd * 17 + sub] = ss;
    }
    __syncthreads();
    if (tid < 16) {
        float m = 0.f;
        for (int i = 0; i < 16; ++i) m += red[tid * 17 + i];
        rstd[tid] = 1.f / (sqrtf(m * (1.f / 255.f)) + 1e-8f);
    }
    __syncthreads();
    for (int i = tid; i < 4096; i += 512) {
        int n = i >> 8, f = i & 255;
        sb[n * 257 + f] = (nf[n * 257 + f] - mean[n]) * rstd[n];
    }
    __syncthreads();
    if (tid < 256) {
        int n = tid >> 4, m = tid & 15;
        float a0 = 0, a1 = 0, a2 = 0, a3 = 0;
        for (int f = 0; f < 256; f += 4) {
            a0 = fmaf(sb[n * 257 + f + 0], sb[m * 257 + f + 0], a0);
            a1 = fmaf(sb[n * 257 + f + 1], sb[m * 257 + f + 1], a1);
            a2 = fmaf(sb[n * 257 + f + 2], sb[m * 257 + f + 2], a2);
            a3 = fmaf(sb[n * 257 + f + 3], sb[m * 257 + f + 3], a3);
        }
        C[tid] = ((a0 + a1) + (a2 + a3)) * (1.f / 256.f);
    }
    __syncthreads();
    if (tid < 256) {
        float v = C[tid];
        int cnt = 0, eq = 0;
        for (int j2 = 0; j2 < 256; ++j2) {
            float vj = C[j2];
            cnt += (vj < v);
            eq  += (vj == v);
        }
        if (cnt <= 191 && 191 < cnt + eq) thrv[0] = v;
    }
    __syncthreads();
    if (tid < 256) {
        int n = tid >> 4, m = tid & 15;
        adj[tid] = (C[tid] > thrv[0] && n != m) ? 1.f : 0.f;
    }
    __syncthreads();
    for (int i = tid; i < 4096; i += 512) {
        int n = i >> 8, f = i & 255;
        float acc = nf[n * 257 + f];
#pragma unroll
        for (int m = 0; m < 16; ++m) acc = fmaf(adj[n * 16 + m], nf[m * 257 + f], acc);
        sb[n * 257 + f] = acc;
    }
    __syncthreads();
    for (int i = tid; i < 1024; i += 512) {
        int n = i >> 6, o = i & 63;
        const float4* wr4 = reinterpret_cast<const float4*>(gw0 + (size_t)o * 256);
        float acc = gb0[o];
        for (int f4 = 0; f4 < 64; ++f4) {
            float4 wv4 = wr4[f4];
            int f = f4 * 4;
            acc = fmaf(sb[n * 257 + f + 0], wv4.x, acc);
            acc = fmaf(sb[n * 257 + f + 1], wv4.y, acc);
            acc = fmaf(sb[n * 257 + f + 2], wv4.z, acc);
            acc = fmaf(sb[n * 257 + f + 3], wv4.w, acc);
        }
        bufA[n * 65 + o] = fmaxf(acc, 0.f);
    }
    __syncthreads();
    for (int i = tid; i < 1024; i += 512) {
        int n = i >> 6, f = i & 63;
        float acc = bufA[n * 65 + f];
#pragma unroll
        for (int m = 0; m < 16; ++m) acc = fmaf(adj[n * 16 + m], bufA[m * 65 + f], acc);
        bufB[n * 65 + f] = acc;
    }
    __syncthreads();
    for (int i = tid; i < 1024; i += 512) {
        int n = i >> 6, o = i & 63;
        const float4* wr4 = reinterpret_cast<const float4*>(gw1 + (size_t)o * 64);
        float acc = gb1[o];
        for (int f4 = 0; f4 < 16; ++f4) {
            float4 wv4 = wr4[f4];
            int f = f4 * 4;
            acc = fmaf(bufB[n * 65 + f + 0], wv4.x, acc);
            acc = fmaf(bufB[n * 65 + f + 1], wv4.y, acc);
            acc = fmaf(bufB[n * 65 + f + 2], wv4.z, acc);
            acc = fmaf(bufB[n * 65 + f + 3], wv4.w, acc);
        }
        bufC[n * 65 + o] = fmaxf(acc, 0.f);
    }
    __syncthreads();
    for (int i = tid; i < 1024; i += 512) {
        int n = i >> 6, f = i & 63;
        float acc = bufC[n * 65 + f];
#pragma unroll
        for (int m = 0; m < 16; ++m) acc = fmaf(adj[n * 16 + m], bufC[m * 65 + f], acc);
        bufA[n * 65 + f] = acc;
    }
    __syncthreads();
    for (int i = tid; i < 1024; i += 512) {
        int n = i >> 6, o = i & 63;
        const float4* wr4 = reinterpret_cast<const float4*>(gw2 + (size_t)o * 64);
        float acc = gb2[o];
        for (int f4 = 0; f4 < 16; ++f4) {
            float4 wv4 = wr4[f4];
            int f = f4 * 4;
            acc = fmaf(bufA[n * 65 + f + 0], wv4.x, acc);
            acc = fmaf(bufA[n * 65 + f + 1], wv4.y, acc);
            acc = fmaf(bufA[n * 65 + f + 2], wv4.z, acc);
            acc = fmaf(bufA[n * 65 + f + 3], wv4.w, acc);
        }
        bufB[n * 65 + o] = fmaxf(acc, 0.f);
    }
    __syncthreads();
    if (tid < 64) {
        float mx = bufB[tid];
#pragma unroll
        for (int n = 1; n < 16; ++n) mx = fmaxf(mx, bufB[n * 65 + tid]);
        emb[tid] = mx;
    }
    __syncthreads();
    if (tid < 5) {
        float acc = clb[tid];
#pragma unroll
        for (int o = 0; o < 64; ++o) acc = fmaf(emb[o], clw[tid * 64 + o], acc);
        out[(size_t)b * 5 + tid] = acc;
    }
}

extern "C" void kernel_launch(void* const* d_in, const int* in_sizes, int n_in,
                              void* d_out, int out_size, void* d_ws, size_t ws_size,
                              hipStream_t stream)
{
    const float* x    = (const float*)d_in[0];
    const float* cw0  = (const float*)d_in[1];
    const float* cb0  = (const float*)d_in[2];
    const float* bng0 = (const float*)d_in[3];
    const float* bnb0 = (const float*)d_in[4];
    const float* bnm0 = (const float*)d_in[5];
    const float* bnv0 = (const float*)d_in[6];
    const float* cw1  = (const float*)d_in[7];
    const float* cb1  = (const float*)d_in[8];
    const float* bng1 = (const float*)d_in[9];
    const float* bnb1 = (const float*)d_in[10];
    const float* bnm1 = (const float*)d_in[11];
    const float* bnv1 = (const float*)d_in[12];
    const float* cw2  = (const float*)d_in[13];
    const float* cb2  = (const float*)d_in[14];
    const float* bng2 = (const float*)d_in[15];
    const float* bnb2 = (const float*)d_in[16];
    const float* bnm2 = (const float*)d_in[17];
    const float* bnv2 = (const float*)d_in[18];
    const float* wih0 = (const float*)d_in[19];
    const float* whh0 = (const float*)d_in[20];
    const float* bih0 = (const float*)d_in[21];
    const float* bhh0 = (const float*)d_in[22];
    const float* wih1 = (const float*)d_in[23];
    const float* whh1 = (const float*)d_in[24];
    const float* bih1 = (const float*)d_in[25];
    const float* bhh1 = (const float*)d_in[26];
    const float* gw0  = (const float*)d_in[27];
    const float* gb0  = (const float*)d_in[28];
    const float* gw1  = (const float*)d_in[29];
    const float* gb1  = (const float*)d_in[30];
    const float* gw2  = (const float*)d_in[31];
    const float* gb2  = (const float*)d_in[32];
    const float* clw  = (const float*)d_in[33];
    const float* clb  = (const float*)d_in[34];

    // ws layout (floats)
    float* xg0   = (float*)d_ws;            // (B,64,256) = 4194304
    float* wt1   = xg0 + 4194304;           // 2560
    float* b1    = wt1 + 2560;              // 32
    float* wt2   = b1 + 32;                 // 10240
    float* b2    = wt2 + 10240;             // 64
    float* w0f   = b2 + 64;                 // 80
    float* b0f   = w0f + 80;                // 16
    float* wih0c = b0f + 16;                // 16384
    float* whh0c = wih0c + 16384;           // 16384
    float* wih1c = whh0c + 16384;           // 16384
    float* whh1c = wih1c + 16384;           // 16384

    prep_weights_kernel<<<64, 256, 0, stream>>>(
        cw0, cb0, bng0, bnb0, bnm0, bnv0,
        cw1, cb1, bng1, bnb1, bnm1, bnv1,
        cw2, cb2, bng2, bnb2, bnm2, bnv2,
        wih0, whh0, wih1, whh1,
        wt1, b1, wt2, b2, w0f, b0f,
        wih0c, whh0c, wih1c, whh1c);
    convall_kernel<<<dim3(32, 256), 256, 0, stream>>>(
        x, w0f, b0f, wt1, b1, wt2, b2, wih0c, bih0, bhh0, xg0);
    lstmgraph_kernel<<<256, 512, 0, stream>>>(
        xg0, whh0c, wih1c, whh1c, bih1, bhh1,
        gw0, gb0, gw1, gb1, gw2, gb2, clw, clb, (float*)d_out);
}